// Round 1
// baseline (1812.733 us; speedup 1.0000x reference)
//
#include <hip/hip_runtime.h>

constexpr int kB   = 8;
constexpr int kN   = 64;
constexpr int kE   = 192;
constexpr int kDin = 1024;
constexpr int kDp  = 256;
constexpr int kNN  = 4096;
constexpr float kTauInv = 20.0f;
constexpr int GRID = 512;

// ---------------------------------------------------------------------------
// LDS phase union — max member (csr) = 38,400 B -> 2 blocks/CU easily fits
// ---------------------------------------------------------------------------
struct SmemGemm { float As[2][16][68]; float Ws[2][16][68]; };
struct SmemBN   { float wsum[4]; };
struct SmemSim  { float Xs[32][36]; float Ys[32][36]; };
struct SmemCsr  {
    int km1[4096], km2[4096];
    short es1[kE], es2[kE], rp1[kE], rp2[kE];
    int cnt1[64], cnt2[64], pos1[64], pos2[64];
    int ccnt1[kE], ccnt2[kE], cpos1[kE], cpos2[kE];
};
struct SmemPd   {
    short rs1[kE], rd1[kE], rs2[kE], rd2[kE], rp1[kE], rp2[kE];
    int co1[kE + 1], co2[kE + 1];
    short cl1[kE], cl2[kE];
};
struct SmemLayer {
    float WL[17 * 16]; float bL[16], SL[16]; float c0v;
    int jd2[kE]; int il[kE]; float msgT[64][18];
};
struct SmemSink {
    float mat[65][68]; float fL[65], gL[65];
    float WcL[17]; float bcv, binvv; float wred[4];
};
union __align__(16) SmemU {
    SmemGemm g; SmemBN bn; SmemSim sim; SmemCsr csr; SmemPd pd; SmemLayer ly; SmemSink sk;
};
static_assert(sizeof(SmemU) <= 49152, "LDS budget");

// ---------------------------------------------------------------------------
// Software grid barrier. Slots zeroed by hipMemsetAsync before launch.
// Co-residency of all 512 blocks guaranteed by __launch_bounds__(256,2)
// (2 blocks/CU min) + 38.4 KB LDS (<80 KB/block at 2/CU).
// ---------------------------------------------------------------------------
__device__ __forceinline__ void gsync(int* bars, int slot)
{
    __syncthreads();
    if (threadIdx.x == 0) {
        __threadfence();
        __hip_atomic_fetch_add(&bars[slot], 1, __ATOMIC_RELEASE, __HIP_MEMORY_SCOPE_AGENT);
        while (__hip_atomic_load(&bars[slot], __ATOMIC_ACQUIRE, __HIP_MEMORY_SCOPE_AGENT) < GRID)
            __builtin_amdgcn_s_sleep(2);
        __threadfence();
    }
    __syncthreads();
}

// ---------------------------------------------------------------------------
// Fused gather + layer MLP phase (transplanted from verified layer_k)
// ---------------------------------------------------------------------------
template <int C>
__device__ void layer_phase(int bid, int t, SmemLayer& L,
    const int* off1, const int* lst1, const int* off2, const int* lst2,
    const int* d1, const int* d2,
    const float* Ke, const float* x, const float* Kp, const int* degcnt,
    const float* W, const float* bb, const float* S, const float* c0,
    float* xn, float* vbuf)
{
    const int r2 = bid & 63, b = bid >> 6;
    for (int k = t; k < C * 16; k += 256) L.WL[k] = W[k];
    if (t < 16) { L.bL[t] = bb[t]; L.SL[t] = S[t]; }
    if (t == 0) L.c0v = c0[0];
    const int j0 = off2[b * 65 + r2];
    const int n2 = off2[b * 65 + r2 + 1] - j0;
    for (int k = t; k < n2; k += 256) {
        int j = lst2[b * kE + j0 + k];
        L.jd2[k] = (j << 8) | d2[b * kE + j];
    }
    for (int k = t; k < kE; k += 256) {
        int i = lst1[b * kE + k];
        L.il[k] = (i << 8) | d1[b * kE + i];
    }
    __syncthreads();

    const int r1 = t >> 2, lane = t & 3;
    const int i0 = off1[b * 65 + r1], i1 = off1[b * 65 + r1 + 1];
    const float* Keb = Ke + (size_t)b * kE * kE;
    const float* KpB = Kp + (size_t)b * kNN;

    if (C == 1) {
        float acc = 0.f;
        for (int k = 0; k < n2; ++k) {
            int pk = L.jd2[k], j = pk >> 8, dd2 = pk & 255;
            for (int m = i0 + lane; m < i1; m += 4) {
                int pi = L.il[m], i = pi >> 8, dd1 = pi & 255;
                if (dd2 == r2 && dd1 == r1) continue;
                acc += Keb[(size_t)i * kE + j] * KpB[dd1 * 64 + dd2];
            }
        }
        acc += __shfl_xor(acc, 1);
        acc += __shfl_xor(acc, 2);
        if (lane == 0) L.msgT[r1][0] = acc;
    } else {
        const float* xb = x + (size_t)b * kNN * C;
        constexpr int NCH = (C + 3) / 4;
        float acc[NCH];
#pragma unroll
        for (int cc = 0; cc < NCH; ++cc) acc[cc] = 0.f;
        for (int k = 0; k < n2; ++k) {
            int pk = L.jd2[k], j = pk >> 8, dd2 = pk & 255;
            const float* xrow = xb + (size_t)(dd2 * 64) * C;
            for (int m = i0; m < i1; ++m) {
                int pi = L.il[m], i = pi >> 8, dd1 = pi & 255;
                if (dd2 == r2 && dd1 == r1) continue;
                float kv = Keb[(size_t)i * kE + j];
                const float* xc = xrow + dd1 * C;
#pragma unroll
                for (int cc = 0; cc < NCH; ++cc) {
                    int c = lane + cc * 4;
                    if (c < C) acc[cc] += kv * xc[c];
                }
            }
        }
#pragma unroll
        for (int cc = 0; cc < NCH; ++cc) {
            int c = lane + cc * 4;
            if (c < C) L.msgT[r1][c] = acc[cc];
        }
    }
    __syncthreads();

    const int row = r2 * 64 + r1;
    const int idx = b * kNN + row;
    const float kd = KpB[r1 * 64 + r2];
    const float dg = fmaxf((float)(degcnt[idx] + (kd > 0.f ? 1 : 0)), 1.f);
    float m[C];
    if (C == 1) {
        m[0] = (L.msgT[r1][0] + kd * kd) / dg;
    } else {
        const float* xr = x + (size_t)idx * C;
#pragma unroll
        for (int c = 0; c < C; ++c)
            m[c] = (L.msgT[r1][c] + kd * xr[c]) / dg;
    }
    float vpart = 0.f;
#pragma unroll
    for (int ff = 0; ff < 4; ++ff) {
        int f = lane * 4 + ff;
        float a = L.bL[f];
#pragma unroll
        for (int c = 0; c < C; ++c) a += m[c] * L.WL[c * 16 + f];
        float h = fmaxf(a, 0.f);
        xn[(size_t)idx * 17 + f] = h;
        vpart += h * L.SL[f];
    }
    vpart += __shfl_xor(vpart, 1);
    vpart += __shfl_xor(vpart, 2);
    if (lane == 0) vbuf[idx] = vpart + L.c0v;
}

// ---------------------------------------------------------------------------
// Mid sinkhorn (64x64, dual potentials) — 256 threads, 4 lanes/row, cnt=16
// ---------------------------------------------------------------------------
__device__ void sink64_phase(int b, int t, SmemSink& S,
                             const float* vin, float* xout)
{
    for (int idx = t; idx < kNN; idx += 256) {
        int q = idx >> 6, p = idx & 63;
        S.mat[p][q] = vin[b * kNN + idx] * kTauInv;
    }
    if (t < 64) { S.fL[t] = 0.f; S.gL[t] = 0.f; }
    __syncthreads();
    const int r = t >> 2, s = t & 3;
    float tv[16];
    for (int it = 0; it < 10; ++it) {
        float mx = -1e30f;
#pragma unroll
        for (int k = 0; k < 16; ++k) {
            float v = S.mat[r][s + 4 * k] + S.gL[s + 4 * k];
            tv[k] = v; mx = fmaxf(mx, v);
        }
        mx = fmaxf(mx, __shfl_xor(mx, 1));
        mx = fmaxf(mx, __shfl_xor(mx, 2));
        float sum = 0.f;
#pragma unroll
        for (int k = 0; k < 16; ++k) sum += __expf(tv[k] - mx);
        sum += __shfl_xor(sum, 1);
        sum += __shfl_xor(sum, 2);
        if (s == 0) S.fL[r] = -(mx + __logf(sum));
        __syncthreads();
        mx = -1e30f;
#pragma unroll
        for (int k = 0; k < 16; ++k) {
            float v = S.mat[s + 4 * k][r] + S.fL[s + 4 * k];
            tv[k] = v; mx = fmaxf(mx, v);
        }
        mx = fmaxf(mx, __shfl_xor(mx, 1));
        mx = fmaxf(mx, __shfl_xor(mx, 2));
        sum = 0.f;
#pragma unroll
        for (int k = 0; k < 16; ++k) sum += __expf(tv[k] - mx);
        sum += __shfl_xor(sum, 1);
        sum += __shfl_xor(sum, 2);
        if (s == 0) S.gL[r] = -(mx + __logf(sum));
        __syncthreads();
    }
    const float fr = S.fL[r];
#pragma unroll
    for (int k = 0; k < 16; ++k) {
        int q = s + 4 * k;
        float e = __expf(S.mat[r][q] + fr + S.gL[q]);
        xout[(size_t)(b * kNN + q * 64 + r) * 17 + 16] = e;
    }
}

// ---------------------------------------------------------------------------
// Final bin-augmented sinkhorn (65x65) + per-batch max -> atomicMax(gmax)
// Fixed-trip guarded loops (no runtime-indexed arrays -> stays in VGPRs).
// ---------------------------------------------------------------------------
__device__ void sink65_phase(int b, int t, SmemSink& S,
                             const float* xA, float* outp,
                             const float* Wc, const float* bc,
                             const float* binvp, int* gmax)
{
    if (t < 17) S.WcL[t] = Wc[t];
    if (t == 17) S.bcv = bc[0];
    if (t == 18) S.binvv = binvp[0];
    if (t < 65) { S.fL[t] = 0.f; S.gL[t] = 0.f; }
    __syncthreads();
    for (int idx = t; idx < 65 * 65; idx += 256) {
        int q = idx / 65, p = idx - q * 65;
        float v;
        if (p < 64 && q < 64) {
            const float* xr = xA + (size_t)(b * kNN + q * 64 + p) * 17;
            v = S.bcv;
#pragma unroll
            for (int c = 0; c < 17; ++c) v += xr[c] * S.WcL[c];
        } else v = S.binvv;
        S.mat[p][q] = v;
    }
    __syncthreads();
    const int r = t >> 2, s = t & 3;
    for (int it = 0; it < 10; ++it) {
        for (int rr = r; rr < 65; rr += 64) {
            float tv[17];
            float mx = -1e30f;
#pragma unroll
            for (int k = 0; k < 17; ++k) {
                int q = s + 4 * k;
                float v = (q < 65) ? S.mat[rr][q] + S.gL[q] : -1e30f;
                tv[k] = v; mx = fmaxf(mx, v);
            }
            mx = fmaxf(mx, __shfl_xor(mx, 1));
            mx = fmaxf(mx, __shfl_xor(mx, 2));
            float sum = 0.f;
#pragma unroll
            for (int k = 0; k < 17; ++k) sum += __expf(tv[k] - mx);
            sum += __shfl_xor(sum, 1);
            sum += __shfl_xor(sum, 2);
            if (s == 0) S.fL[rr] = -(mx + __logf(sum));
        }
        __syncthreads();
        for (int rr = r; rr < 65; rr += 64) {
            float tv[17];
            float mx = -1e30f;
#pragma unroll
            for (int k = 0; k < 17; ++k) {
                int p = s + 4 * k;
                float v = (p < 65) ? S.mat[p][rr] + S.fL[p] : -1e30f;
                tv[k] = v; mx = fmaxf(mx, v);
            }
            mx = fmaxf(mx, __shfl_xor(mx, 1));
            mx = fmaxf(mx, __shfl_xor(mx, 2));
            float sum = 0.f;
#pragma unroll
            for (int k = 0; k < 17; ++k) sum += __expf(tv[k] - mx);
            sum += __shfl_xor(sum, 1);
            sum += __shfl_xor(sum, 2);
            if (s == 0) S.gL[rr] = -(mx + __logf(sum));
        }
        __syncthreads();
    }
    float lmax = 0.f;
    {
        const float fr = S.fL[r];
#pragma unroll
        for (int k = 0; k < 16; ++k) {
            int q = s + 4 * k;
            if (q < 64) {
                float e = __expf(S.mat[r][q] + fr + S.gL[q]);
                outp[((size_t)b * kN + r) * kN + q] = e;
                lmax = fmaxf(lmax, e);
            }
        }
    }
#pragma unroll
    for (int o = 32; o >= 1; o >>= 1) lmax = fmaxf(lmax, __shfl_xor(lmax, o));
    if ((t & 63) == 0) S.wred[t >> 6] = lmax;
    __syncthreads();
    if (t == 0) {
        float m = fmaxf(fmaxf(S.wred[0], S.wred[1]), fmaxf(S.wred[2], S.wred[3]));
        atomicMax(gmax, __float_as_int(m));   // all values > 0: int order == float order
    }
}

// ---------------------------------------------------------------------------
// The whole pipeline as one persistent kernel. 512 blocks x 256 threads,
// 12 software grid barriers. bars[0..30] = barrier slots, bars[31] = gmax.
// ---------------------------------------------------------------------------
__global__ __launch_bounds__(256, 2) void mega(
    const float* __restrict__ x1, const float* __restrict__ x2,
    const float* __restrict__ e1, const float* __restrict__ e2,
    const float* __restrict__ Wp, const float* __restrict__ bp,
    const float* __restrict__ gamma, const float* __restrict__ beta,
    const float* __restrict__ W0, const float* __restrict__ b0,
    const float* __restrict__ S0, const float* __restrict__ c0,
    const float* __restrict__ W1, const float* __restrict__ b1,
    const float* __restrict__ S1, const float* __restrict__ c1,
    const float* __restrict__ W2, const float* __restrict__ b2,
    const float* __restrict__ S2, const float* __restrict__ c2,
    const float* __restrict__ Wc, const float* __restrict__ bc,
    const float* __restrict__ binv,
    const int* __restrict__ src1, const int* __restrict__ dst1,
    const int* __restrict__ src2, const int* __restrict__ dst2,
    float* __restrict__ P, float* __restrict__ hbuf, float* __restrict__ stats,
    float* __restrict__ Kp, float* __restrict__ Ke, float* __restrict__ vbuf,
    float* __restrict__ xA, float* __restrict__ xB,
    int* __restrict__ degcnt,
    int* __restrict__ off1, int* __restrict__ off2,
    int* __restrict__ lst1, int* __restrict__ lst2,
    int* __restrict__ rep1g, int* __restrict__ rep2g,
    int* __restrict__ coff1, int* __restrict__ coff2,
    int* __restrict__ clst1, int* __restrict__ clst2,
    int* __restrict__ bars, float* __restrict__ out)
{
    const int bid = blockIdx.x;
    const int t = threadIdx.x;
    __shared__ SmemU u;

    // ================= phase 0: projection GEMM (z-split 2) ================
    {
        if (bid == 0) for (int i = t; i < 2048; i += 256) stats[i] = 0.f;
        const int ct = bid & 3, rt = (bid >> 2) & 63, z = bid >> 8;
        const int tx = t & 15, ty = t >> 4;
        const int grow0 = rt * 64, col0 = ct * 64;
        const float* src; int lrow0;
        if (rt < 8)       { src = x1; lrow0 = grow0; }
        else if (rt < 16) { src = x2; lrow0 = grow0 - 512; }
        else if (rt < 40) { src = e1; lrow0 = grow0 - 1024; }
        else              { src = e2; lrow0 = grow0 - 2560; }

        const int arow = t >> 2, acol = (t & 3) * 4;
        const int wrow = t >> 4, wcol = (t & 15) * 4;
        const float* Abase = src + (size_t)(lrow0 + arow) * kDin + z * 512 + acol;
        const float* Wbase = Wp + (size_t)(z * 512 + wrow) * kDp + col0 + wcol;

        float4 a4 = *(const float4*)Abase;
        float4 w4 = *(const float4*)Wbase;
        float acc[4][4] = {};

        for (int c = 0; c < 32; ++c) {
            const int cur = c & 1;
            u.g.As[cur][acol + 0][arow] = a4.x;
            u.g.As[cur][acol + 1][arow] = a4.y;
            u.g.As[cur][acol + 2][arow] = a4.z;
            u.g.As[cur][acol + 3][arow] = a4.w;
            *(float4*)&u.g.Ws[cur][wrow][wcol] = w4;
            __syncthreads();
            if (c < 31) {
                a4 = *(const float4*)(Abase + (c + 1) * 16);
                w4 = *(const float4*)(Wbase + (size_t)(c + 1) * 16 * kDp);
            }
#pragma unroll
            for (int kk = 0; kk < 16; ++kk) {
                float4 av = *(const float4*)&u.g.As[cur][kk][ty * 4];
                float4 wv = *(const float4*)&u.g.Ws[cur][kk][tx * 4];
                float a[4] = {av.x, av.y, av.z, av.w};
                float w[4] = {wv.x, wv.y, wv.z, wv.w};
#pragma unroll
                for (int i = 0; i < 4; ++i)
#pragma unroll
                    for (int j = 0; j < 4; ++j)
                        acc[i][j] += a[i] * w[j];
            }
        }
        float* Pz = P + (size_t)z * 1048576;
#pragma unroll
        for (int i = 0; i < 4; ++i)
#pragma unroll
            for (int j = 0; j < 4; ++j)
                Pz[(size_t)(grow0 + ty * 4 + i) * kDp + col0 + tx * 4 + j] = acc[i][j];
    }
    gsync(bars, 0);

    // ========= phase 1: reduce split-K + bias + BN-stat accumulation =======
    {
        const int r0 = bid * 8;
        const int seg = (r0 < 512) ? 0 : (r0 < 1024 ? 1 : (r0 < 2560 ? 2 : 3));
        const float bb = bp[t];
        float s = 0.f, s2 = 0.f;
#pragma unroll
        for (int rr = 0; rr < 8; ++rr) {
            size_t o = (size_t)(r0 + rr) * kDp + t;
            float v = P[o] + P[o + 1048576] + bb;
            hbuf[o] = v;
            s += v; s2 += v * v;
        }
        atomicAdd(&stats[seg * 512 + t], s);
        atomicAdd(&stats[seg * 512 + 256 + t], s2);
    }
    gsync(bars, 1);

    // ===== phase 2: BN+ReLU+L2norm (bid<504)  ||  build_csr (bid>=504) =====
    if (bid < 504) {
        const float ga = gamma[t], be = beta[t];
        for (int r = bid; r < 4096; r += 504) {
            const int seg = (r < 512) ? 0 : (r < 1024 ? 1 : (r < 2560 ? 2 : 3));
            const float n = (seg < 2) ? 512.f : 1536.f;
            const float mu = stats[seg * 512 + t] / n;
            const float var = stats[seg * 512 + 256 + t] / n - mu * mu;
            const float istd = rsqrtf(var + 1e-5f);
            float v = hbuf[(size_t)r * kDp + t];
            float p = fmaxf((v - mu) * istd * ga + be, 0.f);
            float ss = p * p;
#pragma unroll
            for (int o = 32; o >= 1; o >>= 1) ss += __shfl_xor(ss, o);
            if ((t & 63) == 0) u.bn.wsum[t >> 6] = ss;
            __syncthreads();
            const float tot = u.bn.wsum[0] + u.bn.wsum[1] + u.bn.wsum[2] + u.bn.wsum[3];
            const float scale = 1.f / fmaxf(sqrtf(tot), 1e-12f);
            hbuf[(size_t)r * kDp + t] = p * scale;
            __syncthreads();
        }
    } else {
        const int b = bid - 504;
        auto& C = u.csr;
        for (int i = t; i < 4096; i += 256) {
            C.km1[i] = 0x7fffffff; C.km2[i] = 0x7fffffff;
            degcnt[b * kNN + i] = 0;
        }
        if (t < 64) { C.cnt1[t] = 0; C.cnt2[t] = 0; }
        for (int i = t; i < kE; i += 256) { C.ccnt1[i] = 0; C.ccnt2[i] = 0; }
        __syncthreads();
        if (t < kE) {
            int v1 = src1[b * kE + t], v2 = src2[b * kE + t];
            C.es1[t] = (short)v1; C.es2[t] = (short)v2;
            atomicAdd(&C.cnt1[v1], 1);
            atomicAdd(&C.cnt2[v2], 1);
            atomicMin(&C.km1[v1 * 64 + dst1[b * kE + t]], t);
            atomicMin(&C.km2[v2 * 64 + dst2[b * kE + t]], t);
        }
        __syncthreads();
        if (t < kE) {
            int r1 = C.km1[C.es1[t] * 64 + dst1[b * kE + t]];
            int r2 = C.km2[C.es2[t] * 64 + dst2[b * kE + t]];
            C.rp1[t] = (short)r1; C.rp2[t] = (short)r2;
            rep1g[b * kE + t] = r1; rep2g[b * kE + t] = r2;
            atomicAdd(&C.ccnt1[r1], 1);
            atomicAdd(&C.ccnt2[r2], 1);
        }
        __syncthreads();
        if (t == 0) {
            int a = 0, c = 0;
            for (int v = 0; v < 64; ++v) { C.pos1[v] = a; a += C.cnt1[v]; C.pos2[v] = c; c += C.cnt2[v]; }
            a = 0; c = 0;
            for (int v = 0; v < kE; ++v) { C.cpos1[v] = a; a += C.ccnt1[v]; C.cpos2[v] = c; c += C.ccnt2[v]; }
        }
        __syncthreads();
        if (t < 64) { off1[b * 65 + t] = C.pos1[t]; off2[b * 65 + t] = C.pos2[t]; }
        if (t == 0) { off1[b * 65 + 64] = kE; off2[b * 65 + 64] = kE; }
        if (t < kE) { coff1[b * 193 + t] = C.cpos1[t]; coff2[b * 193 + t] = C.cpos2[t]; }
        if (t == 0) { coff1[b * 193 + kE] = kE; coff2[b * 193 + kE] = kE; }
        __syncthreads();
        if (t < kE) {
            int p = atomicAdd(&C.pos1[C.es1[t]], 1); lst1[b * kE + p] = t;
            int q = atomicAdd(&C.pos2[C.es2[t]], 1); lst2[b * kE + q] = t;
            int cp = atomicAdd(&C.cpos1[C.rp1[t]], 1); clst1[b * kE + cp] = t;
            int cq = atomicAdd(&C.cpos2[C.rp2[t]], 1); clst2[b * kE + cq] = t;
        }
    }
    gsync(bars, 2);

    // ==================== phase 3: similarity GEMMs ========================
    if (bid < 320) {
        const int id = bid % 40, b = bid / 40;
        int mt, nt, ldo; const float *X, *Y; float* outp; float scale;
        if (id < 4) {
            mt = (id >> 1) * 32; nt = (id & 1) * 32; ldo = 64;
            X = hbuf + (size_t)b * 64 * kDp;
            Y = hbuf + (512 + (size_t)b * 64) * kDp;
            outp = Kp + (size_t)b * 4096; scale = 1.0f;
        } else {
            int e = id - 4;
            mt = (e / 6) * 32; nt = (e % 6) * 32; ldo = 192;
            X = hbuf + (1024 + (size_t)b * 192) * kDp;
            Y = hbuf + (2560 + (size_t)b * 192) * kDp;
            outp = Ke + (size_t)b * 36864; scale = 0.5f;
        }
        const int row = t >> 3, kq = t & 7;
        const int ty = t >> 4, tx = t & 15;
        float acc[2][2] = {};
        for (int k0 = 0; k0 < kDp; k0 += 32) {
            float4 xa = *(const float4*)(X + (size_t)(mt + row) * kDp + k0 + kq * 4);
            float4 ya = *(const float4*)(Y + (size_t)(nt + row) * kDp + k0 + kq * 4);
            u.sim.Xs[kq * 4 + 0][row] = xa.x; u.sim.Xs[kq * 4 + 1][row] = xa.y;
            u.sim.Xs[kq * 4 + 2][row] = xa.z; u.sim.Xs[kq * 4 + 3][row] = xa.w;
            u.sim.Ys[kq * 4 + 0][row] = ya.x; u.sim.Ys[kq * 4 + 1][row] = ya.y;
            u.sim.Ys[kq * 4 + 2][row] = ya.z; u.sim.Ys[kq * 4 + 3][row] = ya.w;
            __syncthreads();
#pragma unroll
            for (int kk = 0; kk < 32; ++kk) {
                float2 xv = *(const float2*)&u.sim.Xs[kk][ty * 2];
                float2 yv = *(const float2*)&u.sim.Ys[kk][tx * 2];
                acc[0][0] += xv.x * yv.x; acc[0][1] += xv.x * yv.y;
                acc[1][0] += xv.y * yv.x; acc[1][1] += xv.y * yv.y;
            }
            __syncthreads();
        }
#pragma unroll
        for (int i = 0; i < 2; ++i)
#pragma unroll
            for (int j = 0; j < 2; ++j)
                outp[(size_t)(mt + ty * 2 + i) * ldo + nt + tx * 2 + j] = scale * acc[i][j];
    }
    gsync(bars, 3);

    // ======================= phase 4: pairdeg ==============================
    {
        const int b = bid >> 6, ch0 = bid & 63;
        auto& D = u.pd;
        for (int i = t; i < kE; i += 256) {
            D.rs1[i] = (short)src1[b * kE + i]; D.rd1[i] = (short)dst1[b * kE + i];
            D.rs2[i] = (short)src2[b * kE + i]; D.rd2[i] = (short)dst2[b * kE + i];
            D.rp1[i] = (short)rep1g[b * kE + i]; D.rp2[i] = (short)rep2g[b * kE + i];
            D.cl1[i] = (short)clst1[b * kE + i]; D.cl2[i] = (short)clst2[b * kE + i];
        }
        for (int i = t; i < kE + 1; i += 256) {
            D.co1[i] = coff1[b * 193 + i]; D.co2[i] = coff2[b * 193 + i];
        }
        __syncthreads();
        const float* Keb = Ke + (size_t)b * kE * kE;
        for (int chunk = ch0; chunk < 144; chunk += 64) {
            int idx = chunk * 256 + t;
            if (idx < kE * kE) {
                int i = idx / kE, j = idx - i * kE;
                if (D.rp1[i] == i && D.rp2[j] == j) {
                    float sum = 0.f;
                    for (int m = D.co1[i]; m < D.co1[i + 1]; ++m) {
                        int ii = D.cl1[m];
                        const float* kr = Keb + (size_t)ii * kE;
                        for (int n = D.co2[j]; n < D.co2[j + 1]; ++n) sum += kr[D.cl2[n]];
                    }
                    int rr = D.rs2[j] * 64 + D.rs1[i];
                    int cc = D.rd2[j] * 64 + D.rd1[i];
                    if (rr != cc && sum > 0.0f) atomicAdd(&degcnt[b * kNN + rr], 1);
                }
            }
        }
    }
    gsync(bars, 4);

    // ================= GNN layers + sinkhorns + final ======================
    layer_phase<1>(bid, t, u.ly, off1, lst1, off2, lst2, dst1, dst2,
                   Ke, nullptr, Kp, degcnt, W0, b0, S0, c0, xA, vbuf);
    gsync(bars, 5);
    if ((bid & 63) == 0) sink64_phase(bid >> 6, t, u.sk, vbuf, xA);
    gsync(bars, 6);
    layer_phase<17>(bid, t, u.ly, off1, lst1, off2, lst2, dst1, dst2,
                    Ke, xA, Kp, degcnt, W1, b1, S1, c1, xB, vbuf);
    gsync(bars, 7);
    if ((bid & 63) == 0) sink64_phase(bid >> 6, t, u.sk, vbuf, xB);
    gsync(bars, 8);
    layer_phase<17>(bid, t, u.ly, off1, lst1, off2, lst2, dst1, dst2,
                    Ke, xB, Kp, degcnt, W2, b2, S2, c2, xA, vbuf);
    gsync(bars, 9);
    if ((bid & 63) == 0) sink64_phase(bid >> 6, t, u.sk, vbuf, xA);
    gsync(bars, 10);
    if ((bid & 63) == 0) sink65_phase(bid >> 6, t, u.sk, xA, out, Wc, bc, binv, bars + 31);
    gsync(bars, 11);

    // ====================== final: global normalize ========================
    {
        const float gm = __int_as_float(
            __hip_atomic_load(bars + 31, __ATOMIC_RELAXED, __HIP_MEMORY_SCOPE_AGENT));
        if (t < 64) {
            const float inv = 1.f / gm;
            out[bid * 64 + t] *= inv;
        }
    }
}

// ---------------------------------------------------------------------------
extern "C" void kernel_launch(void* const* d_in, const int* in_sizes, int n_in,
                              void* d_out, int out_size, void* d_ws, size_t ws_size,
                              hipStream_t stream)
{
    (void)in_sizes; (void)n_in; (void)out_size; (void)ws_size;

    const float* x1    = (const float*)d_in[0];
    const float* x2    = (const float*)d_in[1];
    const float* e1    = (const float*)d_in[2];
    const float* e2    = (const float*)d_in[3];
    const float* Wp    = (const float*)d_in[4];
    const float* bp    = (const float*)d_in[5];
    const float* gamma = (const float*)d_in[6];
    const float* beta  = (const float*)d_in[7];
    const float* W0 = (const float*)d_in[8];
    const float* b0 = (const float*)d_in[9];
    const float* S0 = (const float*)d_in[10];
    const float* c0 = (const float*)d_in[11];
    const float* W1 = (const float*)d_in[12];
    const float* b1 = (const float*)d_in[13];
    const float* S1 = (const float*)d_in[14];
    const float* c1 = (const float*)d_in[15];
    const float* W2 = (const float*)d_in[16];
    const float* b2 = (const float*)d_in[17];
    const float* S2 = (const float*)d_in[18];
    const float* c2 = (const float*)d_in[19];
    const float* Wc = (const float*)d_in[20];
    const float* bc = (const float*)d_in[21];
    const float* binv = (const float*)d_in[22];
    const int* src1 = (const int*)d_in[23];
    const int* dst1 = (const int*)d_in[24];
    const int* src2 = (const int*)d_in[25];
    const int* dst2 = (const int*)d_in[26];

    float* out = (float*)d_out;
    float* wsf = (float*)d_ws;

    float* hbuf  = wsf;                    // 1,048,576
    float* P     = hbuf + 1048576;         // 4,194,304 (z=2 uses 2,097,152)
    float* Kp    = P + 4194304;            // 32768
    float* Ke    = Kp + 32768;             // 294912
    float* vbuf  = Ke + 294912;            // 32768
    float* xA    = vbuf + 32768;           // 557056
    float* xB    = xA + 557056;            // 557056
    float* stats = xB + 557056;            // 2048
    int*   degcnt = (int*)(stats + 2048);  // 32768
    int*   off1 = degcnt + 32768;          // 520
    int*   off2 = off1 + 520;              // 520
    int*   lst1 = off2 + 520;              // 1536
    int*   lst2 = lst1 + 1536;             // 1536
    int*   rep1g = lst2 + 1536;            // 1536
    int*   rep2g = rep1g + 1536;           // 1536
    int*   coff1 = rep2g + 1536;           // 1544
    int*   coff2 = coff1 + 1544;           // 1544
    int*   clst1 = coff2 + 1544;           // 1536
    int*   clst2 = clst1 + 1536;           // 1536
    int*   bars  = clst2 + 1536;           // 32 (barrier slots + gmax bits)

    hipMemsetAsync(bars, 0, 32 * sizeof(int), stream);
    mega<<<dim3(GRID), dim3(256), 0, stream>>>(
        x1, x2, e1, e2, Wp, bp, gamma, beta,
        W0, b0, S0, c0, W1, b1, S1, c1, W2, b2, S2, c2,
        Wc, bc, binv, src1, dst1, src2, dst2,
        P, hbuf, stats, Kp, Ke, vbuf, xA, xB,
        degcnt, off1, off2, lst1, lst2, rep1g, rep2g,
        coff1, coff2, clst1, clst2, bars, out);
}

// Round 2
// 744.192 us; speedup vs baseline: 2.4358x; 2.4358x over previous
//
#include <hip/hip_runtime.h>

constexpr int kB   = 8;
constexpr int kN   = 64;
constexpr int kE   = 192;
constexpr int kDin = 1024;
constexpr int kDp  = 256;
constexpr int kNN  = 4096;
constexpr float kTauInv = 20.0f;
constexpr int GRID = 512;

// ---------------------------------------------------------------------------
// LDS phase union — max member (csr) = 38,400 B -> 2 blocks/CU easily fits
// ---------------------------------------------------------------------------
struct SmemGemm { float As[2][16][68]; float Ws[2][16][68]; };
struct SmemBN   { float wsum[4]; };
struct SmemSim  { float Xs[32][36]; float Ys[32][36]; };
struct SmemCsr  {
    int km1[4096], km2[4096];
    short es1[kE], es2[kE], rp1[kE], rp2[kE];
    int cnt1[64], cnt2[64], pos1[64], pos2[64];
    int ccnt1[kE], ccnt2[kE], cpos1[kE], cpos2[kE];
};
struct SmemPd   {
    short rs1[kE], rd1[kE], rs2[kE], rd2[kE], rp1[kE], rp2[kE];
    int co1[kE + 1], co2[kE + 1];
    short cl1[kE], cl2[kE];
};
struct SmemLayer {
    float WL[17 * 16]; float bL[16], SL[16]; float c0v;
    int jd2[kE]; int il[kE]; float msgT[64][18];
};
struct SmemSink {
    float mat[65][68]; float fL[65], gL[65];
    float WcL[17]; float bcv, binvv; float wred[4];
};
union __align__(16) SmemU {
    SmemGemm g; SmemBN bn; SmemSim sim; SmemCsr csr; SmemPd pd; SmemLayer ly; SmemSink sk;
};
static_assert(sizeof(SmemU) <= 49152, "LDS budget");

// ---------------------------------------------------------------------------
// Software grid barrier — RELAXED polls (no per-iteration buffer_inv!),
// cache maintenance exactly once per barrier via explicit fences.
// R1 lesson: acquire-loads in the spin loop emit buffer_inv each iteration,
// trashing all XCD L2s continuously (57 GB/s, 1.8 ms). Slots zeroed by
// hipMemsetAsync before launch. Co-residency: __launch_bounds__(256,2).
// ---------------------------------------------------------------------------
__device__ __forceinline__ void gsync(int* bars, int slot)
{
    __syncthreads();
    if (threadIdx.x == 0) {
        __builtin_amdgcn_fence(__ATOMIC_RELEASE, "agent");   // writeback once
        __hip_atomic_fetch_add(&bars[slot], 1, __ATOMIC_RELAXED,
                               __HIP_MEMORY_SCOPE_AGENT);
        while (__hip_atomic_load(&bars[slot], __ATOMIC_RELAXED,
                                 __HIP_MEMORY_SCOPE_AGENT) < GRID)
            __builtin_amdgcn_s_sleep(8);
        __builtin_amdgcn_fence(__ATOMIC_ACQUIRE, "agent");   // invalidate once
    }
    __syncthreads();
}

// ---------------------------------------------------------------------------
// Fused gather + layer MLP phase (transplanted from verified layer_k)
// ---------------------------------------------------------------------------
template <int C>
__device__ void layer_phase(int bid, int t, SmemLayer& L,
    const int* off1, const int* lst1, const int* off2, const int* lst2,
    const int* d1, const int* d2,
    const float* Ke, const float* x, const float* Kp, const int* degcnt,
    const float* W, const float* bb, const float* S, const float* c0,
    float* xn, float* vbuf)
{
    const int r2 = bid & 63, b = bid >> 6;
    for (int k = t; k < C * 16; k += 256) L.WL[k] = W[k];
    if (t < 16) { L.bL[t] = bb[t]; L.SL[t] = S[t]; }
    if (t == 0) L.c0v = c0[0];
    const int j0 = off2[b * 65 + r2];
    const int n2 = off2[b * 65 + r2 + 1] - j0;
    for (int k = t; k < n2; k += 256) {
        int j = lst2[b * kE + j0 + k];
        L.jd2[k] = (j << 8) | d2[b * kE + j];
    }
    for (int k = t; k < kE; k += 256) {
        int i = lst1[b * kE + k];
        L.il[k] = (i << 8) | d1[b * kE + i];
    }
    __syncthreads();

    const int r1 = t >> 2, lane = t & 3;
    const int i0 = off1[b * 65 + r1], i1 = off1[b * 65 + r1 + 1];
    const float* Keb = Ke + (size_t)b * kE * kE;
    const float* KpB = Kp + (size_t)b * kNN;

    if (C == 1) {
        float acc = 0.f;
        for (int k = 0; k < n2; ++k) {
            int pk = L.jd2[k], j = pk >> 8, dd2 = pk & 255;
            for (int m = i0 + lane; m < i1; m += 4) {
                int pi = L.il[m], i = pi >> 8, dd1 = pi & 255;
                if (dd2 == r2 && dd1 == r1) continue;
                acc += Keb[(size_t)i * kE + j] * KpB[dd1 * 64 + dd2];
            }
        }
        acc += __shfl_xor(acc, 1);
        acc += __shfl_xor(acc, 2);
        if (lane == 0) L.msgT[r1][0] = acc;
    } else {
        const float* xb = x + (size_t)b * kNN * C;
        constexpr int NCH = (C + 3) / 4;
        float acc[NCH];
#pragma unroll
        for (int cc = 0; cc < NCH; ++cc) acc[cc] = 0.f;
        for (int k = 0; k < n2; ++k) {
            int pk = L.jd2[k], j = pk >> 8, dd2 = pk & 255;
            const float* xrow = xb + (size_t)(dd2 * 64) * C;
            for (int m = i0; m < i1; ++m) {
                int pi = L.il[m], i = pi >> 8, dd1 = pi & 255;
                if (dd2 == r2 && dd1 == r1) continue;
                float kv = Keb[(size_t)i * kE + j];
                const float* xc = xrow + dd1 * C;
#pragma unroll
                for (int cc = 0; cc < NCH; ++cc) {
                    int c = lane + cc * 4;
                    if (c < C) acc[cc] += kv * xc[c];
                }
            }
        }
#pragma unroll
        for (int cc = 0; cc < NCH; ++cc) {
            int c = lane + cc * 4;
            if (c < C) L.msgT[r1][c] = acc[cc];
        }
    }
    __syncthreads();

    const int row = r2 * 64 + r1;
    const int idx = b * kNN + row;
    const float kd = KpB[r1 * 64 + r2];
    const float dg = fmaxf((float)(degcnt[idx] + (kd > 0.f ? 1 : 0)), 1.f);
    float m[C];
    if (C == 1) {
        m[0] = (L.msgT[r1][0] + kd * kd) / dg;
    } else {
        const float* xr = x + (size_t)idx * C;
#pragma unroll
        for (int c = 0; c < C; ++c)
            m[c] = (L.msgT[r1][c] + kd * xr[c]) / dg;
    }
    float vpart = 0.f;
#pragma unroll
    for (int ff = 0; ff < 4; ++ff) {
        int f = lane * 4 + ff;
        float a = L.bL[f];
#pragma unroll
        for (int c = 0; c < C; ++c) a += m[c] * L.WL[c * 16 + f];
        float h = fmaxf(a, 0.f);
        xn[(size_t)idx * 17 + f] = h;
        vpart += h * L.SL[f];
    }
    vpart += __shfl_xor(vpart, 1);
    vpart += __shfl_xor(vpart, 2);
    if (lane == 0) vbuf[idx] = vpart + L.c0v;
}

// ---------------------------------------------------------------------------
// Mid sinkhorn (64x64, dual potentials) — 256 threads, 4 lanes/row, cnt=16
// ---------------------------------------------------------------------------
__device__ void sink64_phase(int b, int t, SmemSink& S,
                             const float* vin, float* xout)
{
    for (int idx = t; idx < kNN; idx += 256) {
        int q = idx >> 6, p = idx & 63;
        S.mat[p][q] = vin[b * kNN + idx] * kTauInv;
    }
    if (t < 64) { S.fL[t] = 0.f; S.gL[t] = 0.f; }
    __syncthreads();
    const int r = t >> 2, s = t & 3;
    float tv[16];
    for (int it = 0; it < 10; ++it) {
        float mx = -1e30f;
#pragma unroll
        for (int k = 0; k < 16; ++k) {
            float v = S.mat[r][s + 4 * k] + S.gL[s + 4 * k];
            tv[k] = v; mx = fmaxf(mx, v);
        }
        mx = fmaxf(mx, __shfl_xor(mx, 1));
        mx = fmaxf(mx, __shfl_xor(mx, 2));
        float sum = 0.f;
#pragma unroll
        for (int k = 0; k < 16; ++k) sum += __expf(tv[k] - mx);
        sum += __shfl_xor(sum, 1);
        sum += __shfl_xor(sum, 2);
        if (s == 0) S.fL[r] = -(mx + __logf(sum));
        __syncthreads();
        mx = -1e30f;
#pragma unroll
        for (int k = 0; k < 16; ++k) {
            float v = S.mat[s + 4 * k][r] + S.fL[s + 4 * k];
            tv[k] = v; mx = fmaxf(mx, v);
        }
        mx = fmaxf(mx, __shfl_xor(mx, 1));
        mx = fmaxf(mx, __shfl_xor(mx, 2));
        sum = 0.f;
#pragma unroll
        for (int k = 0; k < 16; ++k) sum += __expf(tv[k] - mx);
        sum += __shfl_xor(sum, 1);
        sum += __shfl_xor(sum, 2);
        if (s == 0) S.gL[r] = -(mx + __logf(sum));
        __syncthreads();
    }
    const float fr = S.fL[r];
#pragma unroll
    for (int k = 0; k < 16; ++k) {
        int q = s + 4 * k;
        float e = __expf(S.mat[r][q] + fr + S.gL[q]);
        xout[(size_t)(b * kNN + q * 64 + r) * 17 + 16] = e;
    }
}

// ---------------------------------------------------------------------------
// Final bin-augmented sinkhorn (65x65) + per-batch max -> atomicMax(gmax)
// ---------------------------------------------------------------------------
__device__ void sink65_phase(int b, int t, SmemSink& S,
                             const float* xA, float* outp,
                             const float* Wc, const float* bc,
                             const float* binvp, int* gmax)
{
    if (t < 17) S.WcL[t] = Wc[t];
    if (t == 17) S.bcv = bc[0];
    if (t == 18) S.binvv = binvp[0];
    if (t < 65) { S.fL[t] = 0.f; S.gL[t] = 0.f; }
    __syncthreads();
    for (int idx = t; idx < 65 * 65; idx += 256) {
        int q = idx / 65, p = idx - q * 65;
        float v;
        if (p < 64 && q < 64) {
            const float* xr = xA + (size_t)(b * kNN + q * 64 + p) * 17;
            v = S.bcv;
#pragma unroll
            for (int c = 0; c < 17; ++c) v += xr[c] * S.WcL[c];
        } else v = S.binvv;
        S.mat[p][q] = v;
    }
    __syncthreads();
    const int r = t >> 2, s = t & 3;
    for (int it = 0; it < 10; ++it) {
        for (int rr = r; rr < 65; rr += 64) {
            float tv[17];
            float mx = -1e30f;
#pragma unroll
            for (int k = 0; k < 17; ++k) {
                int q = s + 4 * k;
                float v = (q < 65) ? S.mat[rr][q] + S.gL[q] : -1e30f;
                tv[k] = v; mx = fmaxf(mx, v);
            }
            mx = fmaxf(mx, __shfl_xor(mx, 1));
            mx = fmaxf(mx, __shfl_xor(mx, 2));
            float sum = 0.f;
#pragma unroll
            for (int k = 0; k < 17; ++k) sum += __expf(tv[k] - mx);
            sum += __shfl_xor(sum, 1);
            sum += __shfl_xor(sum, 2);
            if (s == 0) S.fL[rr] = -(mx + __logf(sum));
        }
        __syncthreads();
        for (int rr = r; rr < 65; rr += 64) {
            float tv[17];
            float mx = -1e30f;
#pragma unroll
            for (int k = 0; k < 17; ++k) {
                int p = s + 4 * k;
                float v = (p < 65) ? S.mat[p][rr] + S.fL[p] : -1e30f;
                tv[k] = v; mx = fmaxf(mx, v);
            }
            mx = fmaxf(mx, __shfl_xor(mx, 1));
            mx = fmaxf(mx, __shfl_xor(mx, 2));
            float sum = 0.f;
#pragma unroll
            for (int k = 0; k < 17; ++k) sum += __expf(tv[k] - mx);
            sum += __shfl_xor(sum, 1);
            sum += __shfl_xor(sum, 2);
            if (s == 0) S.gL[rr] = -(mx + __logf(sum));
        }
        __syncthreads();
    }
    float lmax = 0.f;
    {
        const float fr = S.fL[r];
#pragma unroll
        for (int k = 0; k < 16; ++k) {
            int q = s + 4 * k;
            if (q < 64) {
                float e = __expf(S.mat[r][q] + fr + S.gL[q]);
                outp[((size_t)b * kN + r) * kN + q] = e;
                lmax = fmaxf(lmax, e);
            }
        }
    }
#pragma unroll
    for (int o = 32; o >= 1; o >>= 1) lmax = fmaxf(lmax, __shfl_xor(lmax, o));
    if ((t & 63) == 0) S.wred[t >> 6] = lmax;
    __syncthreads();
    if (t == 0) {
        float m = fmaxf(fmaxf(S.wred[0], S.wred[1]), fmaxf(S.wred[2], S.wred[3]));
        atomicMax(gmax, __float_as_int(m));   // all values > 0: int order == float order
    }
}

// ---------------------------------------------------------------------------
// The whole pipeline as one persistent kernel. 512 blocks x 256 threads,
// 12 software grid barriers. bars[0..30] = barrier slots, bars[31] = gmax.
// ---------------------------------------------------------------------------
__global__ __launch_bounds__(256, 2) void mega(
    const float* __restrict__ x1, const float* __restrict__ x2,
    const float* __restrict__ e1, const float* __restrict__ e2,
    const float* __restrict__ Wp, const float* __restrict__ bp,
    const float* __restrict__ gamma, const float* __restrict__ beta,
    const float* __restrict__ W0, const float* __restrict__ b0,
    const float* __restrict__ S0, const float* __restrict__ c0,
    const float* __restrict__ W1, const float* __restrict__ b1,
    const float* __restrict__ S1, const float* __restrict__ c1,
    const float* __restrict__ W2, const float* __restrict__ b2,
    const float* __restrict__ S2, const float* __restrict__ c2,
    const float* __restrict__ Wc, const float* __restrict__ bc,
    const float* __restrict__ binv,
    const int* __restrict__ src1, const int* __restrict__ dst1,
    const int* __restrict__ src2, const int* __restrict__ dst2,
    float* __restrict__ P, float* __restrict__ hbuf, float* __restrict__ stats,
    float* __restrict__ Kp, float* __restrict__ Ke, float* __restrict__ vbuf,
    float* __restrict__ xA, float* __restrict__ xB,
    int* __restrict__ degcnt,
    int* __restrict__ off1, int* __restrict__ off2,
    int* __restrict__ lst1, int* __restrict__ lst2,
    int* __restrict__ rep1g, int* __restrict__ rep2g,
    int* __restrict__ coff1, int* __restrict__ coff2,
    int* __restrict__ clst1, int* __restrict__ clst2,
    int* __restrict__ bars, float* __restrict__ out)
{
    const int bid = blockIdx.x;
    const int t = threadIdx.x;
    __shared__ SmemU u;

    // ================= phase 0: projection GEMM (z-split 2) ================
    {
        if (bid == 0) for (int i = t; i < 2048; i += 256) stats[i] = 0.f;
        const int ct = bid & 3, rt = (bid >> 2) & 63, z = bid >> 8;
        const int tx = t & 15, ty = t >> 4;
        const int grow0 = rt * 64, col0 = ct * 64;
        const float* src; int lrow0;
        if (rt < 8)       { src = x1; lrow0 = grow0; }
        else if (rt < 16) { src = x2; lrow0 = grow0 - 512; }
        else if (rt < 40) { src = e1; lrow0 = grow0 - 1024; }
        else              { src = e2; lrow0 = grow0 - 2560; }

        const int arow = t >> 2, acol = (t & 3) * 4;
        const int wrow = t >> 4, wcol = (t & 15) * 4;
        const float* Abase = src + (size_t)(lrow0 + arow) * kDin + z * 512 + acol;
        const float* Wbase = Wp + (size_t)(z * 512 + wrow) * kDp + col0 + wcol;

        float4 a4 = *(const float4*)Abase;
        float4 w4 = *(const float4*)Wbase;
        float acc[4][4] = {};

        for (int c = 0; c < 32; ++c) {
            const int cur = c & 1;
            u.g.As[cur][acol + 0][arow] = a4.x;
            u.g.As[cur][acol + 1][arow] = a4.y;
            u.g.As[cur][acol + 2][arow] = a4.z;
            u.g.As[cur][acol + 3][arow] = a4.w;
            *(float4*)&u.g.Ws[cur][wrow][wcol] = w4;
            __syncthreads();
            if (c < 31) {
                a4 = *(const float4*)(Abase + (c + 1) * 16);
                w4 = *(const float4*)(Wbase + (size_t)(c + 1) * 16 * kDp);
            }
#pragma unroll
            for (int kk = 0; kk < 16; ++kk) {
                float4 av = *(const float4*)&u.g.As[cur][kk][ty * 4];
                float4 wv = *(const float4*)&u.g.Ws[cur][kk][tx * 4];
                float a[4] = {av.x, av.y, av.z, av.w};
                float w[4] = {wv.x, wv.y, wv.z, wv.w};
#pragma unroll
                for (int i = 0; i < 4; ++i)
#pragma unroll
                    for (int j = 0; j < 4; ++j)
                        acc[i][j] += a[i] * w[j];
            }
        }
        float* Pz = P + (size_t)z * 1048576;
#pragma unroll
        for (int i = 0; i < 4; ++i)
#pragma unroll
            for (int j = 0; j < 4; ++j)
                Pz[(size_t)(grow0 + ty * 4 + i) * kDp + col0 + tx * 4 + j] = acc[i][j];
    }
    gsync(bars, 0);

    // ========= phase 1: reduce split-K + bias + BN-stat accumulation =======
    {
        const int r0 = bid * 8;
        const int seg = (r0 < 512) ? 0 : (r0 < 1024 ? 1 : (r0 < 2560 ? 2 : 3));
        const float bb = bp[t];
        float s = 0.f, s2 = 0.f;
#pragma unroll
        for (int rr = 0; rr < 8; ++rr) {
            size_t o = (size_t)(r0 + rr) * kDp + t;
            float v = P[o] + P[o + 1048576] + bb;
            hbuf[o] = v;
            s += v; s2 += v * v;
        }
        atomicAdd(&stats[seg * 512 + t], s);
        atomicAdd(&stats[seg * 512 + 256 + t], s2);
    }
    gsync(bars, 1);

    // ===== phase 2: BN+ReLU+L2norm (bid<504)  ||  build_csr (bid>=504) =====
    if (bid < 504) {
        const float ga = gamma[t], be = beta[t];
        for (int r = bid; r < 4096; r += 504) {
            const int seg = (r < 512) ? 0 : (r < 1024 ? 1 : (r < 2560 ? 2 : 3));
            const float n = (seg < 2) ? 512.f : 1536.f;
            const float mu = stats[seg * 512 + t] / n;
            const float var = stats[seg * 512 + 256 + t] / n - mu * mu;
            const float istd = rsqrtf(var + 1e-5f);
            float v = hbuf[(size_t)r * kDp + t];
            float p = fmaxf((v - mu) * istd * ga + be, 0.f);
            float ss = p * p;
#pragma unroll
            for (int o = 32; o >= 1; o >>= 1) ss += __shfl_xor(ss, o);
            if ((t & 63) == 0) u.bn.wsum[t >> 6] = ss;
            __syncthreads();
            const float tot = u.bn.wsum[0] + u.bn.wsum[1] + u.bn.wsum[2] + u.bn.wsum[3];
            const float scale = 1.f / fmaxf(sqrtf(tot), 1e-12f);
            hbuf[(size_t)r * kDp + t] = p * scale;
            __syncthreads();
        }
    } else {
        const int b = bid - 504;
        auto& C = u.csr;
        for (int i = t; i < 4096; i += 256) {
            C.km1[i] = 0x7fffffff; C.km2[i] = 0x7fffffff;
            degcnt[b * kNN + i] = 0;
        }
        if (t < 64) { C.cnt1[t] = 0; C.cnt2[t] = 0; }
        for (int i = t; i < kE; i += 256) { C.ccnt1[i] = 0; C.ccnt2[i] = 0; }
        __syncthreads();
        if (t < kE) {
            int v1 = src1[b * kE + t], v2 = src2[b * kE + t];
            C.es1[t] = (short)v1; C.es2[t] = (short)v2;
            atomicAdd(&C.cnt1[v1], 1);
            atomicAdd(&C.cnt2[v2], 1);
            atomicMin(&C.km1[v1 * 64 + dst1[b * kE + t]], t);
            atomicMin(&C.km2[v2 * 64 + dst2[b * kE + t]], t);
        }
        __syncthreads();
        if (t < kE) {
            int r1 = C.km1[C.es1[t] * 64 + dst1[b * kE + t]];
            int r2 = C.km2[C.es2[t] * 64 + dst2[b * kE + t]];
            C.rp1[t] = (short)r1; C.rp2[t] = (short)r2;
            rep1g[b * kE + t] = r1; rep2g[b * kE + t] = r2;
            atomicAdd(&C.ccnt1[r1], 1);
            atomicAdd(&C.ccnt2[r2], 1);
        }
        __syncthreads();
        if (t == 0) {
            int a = 0, c = 0;
            for (int v = 0; v < 64; ++v) { C.pos1[v] = a; a += C.cnt1[v]; C.pos2[v] = c; c += C.cnt2[v]; }
            a = 0; c = 0;
            for (int v = 0; v < kE; ++v) { C.cpos1[v] = a; a += C.ccnt1[v]; C.cpos2[v] = c; c += C.ccnt2[v]; }
        }
        __syncthreads();
        if (t < 64) { off1[b * 65 + t] = C.pos1[t]; off2[b * 65 + t] = C.pos2[t]; }
        if (t == 0) { off1[b * 65 + 64] = kE; off2[b * 65 + 64] = kE; }
        if (t < kE) { coff1[b * 193 + t] = C.cpos1[t]; coff2[b * 193 + t] = C.cpos2[t]; }
        if (t == 0) { coff1[b * 193 + kE] = kE; coff2[b * 193 + kE] = kE; }
        __syncthreads();
        if (t < kE) {
            int p = atomicAdd(&C.pos1[C.es1[t]], 1); lst1[b * kE + p] = t;
            int q = atomicAdd(&C.pos2[C.es2[t]], 1); lst2[b * kE + q] = t;
            int cp = atomicAdd(&C.cpos1[C.rp1[t]], 1); clst1[b * kE + cp] = t;
            int cq = atomicAdd(&C.cpos2[C.rp2[t]], 1); clst2[b * kE + cq] = t;
        }
    }
    gsync(bars, 2);

    // ==================== phase 3: similarity GEMMs ========================
    if (bid < 320) {
        const int id = bid % 40, b = bid / 40;
        int mt, nt, ldo; const float *X, *Y; float* outp; float scale;
        if (id < 4) {
            mt = (id >> 1) * 32; nt = (id & 1) * 32; ldo = 64;
            X = hbuf + (size_t)b * 64 * kDp;
            Y = hbuf + (512 + (size_t)b * 64) * kDp;
            outp = Kp + (size_t)b * 4096; scale = 1.0f;
        } else {
            int e = id - 4;
            mt = (e / 6) * 32; nt = (e % 6) * 32; ldo = 192;
            X = hbuf + (1024 + (size_t)b * 192) * kDp;
            Y = hbuf + (2560 + (size_t)b * 192) * kDp;
            outp = Ke + (size_t)b * 36864; scale = 0.5f;
        }
        const int row = t >> 3, kq = t & 7;
        const int ty = t >> 4, tx = t & 15;
        float acc[2][2] = {};
        for (int k0 = 0; k0 < kDp; k0 += 32) {
            float4 xa = *(const float4*)(X + (size_t)(mt + row) * kDp + k0 + kq * 4);
            float4 ya = *(const float4*)(Y + (size_t)(nt + row) * kDp + k0 + kq * 4);
            u.sim.Xs[kq * 4 + 0][row] = xa.x; u.sim.Xs[kq * 4 + 1][row] = xa.y;
            u.sim.Xs[kq * 4 + 2][row] = xa.z; u.sim.Xs[kq * 4 + 3][row] = xa.w;
            u.sim.Ys[kq * 4 + 0][row] = ya.x; u.sim.Ys[kq * 4 + 1][row] = ya.y;
            u.sim.Ys[kq * 4 + 2][row] = ya.z; u.sim.Ys[kq * 4 + 3][row] = ya.w;
            __syncthreads();
#pragma unroll
            for (int kk = 0; kk < 32; ++kk) {
                float2 xv = *(const float2*)&u.sim.Xs[kk][ty * 2];
                float2 yv = *(const float2*)&u.sim.Ys[kk][tx * 2];
                acc[0][0] += xv.x * yv.x; acc[0][1] += xv.x * yv.y;
                acc[1][0] += xv.y * yv.x; acc[1][1] += xv.y * yv.y;
            }
            __syncthreads();
        }
#pragma unroll
        for (int i = 0; i < 2; ++i)
#pragma unroll
            for (int j = 0; j < 2; ++j)
                outp[(size_t)(mt + ty * 2 + i) * ldo + nt + tx * 2 + j] = scale * acc[i][j];
    }
    gsync(bars, 3);

    // ======================= phase 4: pairdeg ==============================
    {
        const int b = bid >> 6, ch0 = bid & 63;
        auto& D = u.pd;
        for (int i = t; i < kE; i += 256) {
            D.rs1[i] = (short)src1[b * kE + i]; D.rd1[i] = (short)dst1[b * kE + i];
            D.rs2[i] = (short)src2[b * kE + i]; D.rd2[i] = (short)dst2[b * kE + i];
            D.rp1[i] = (short)rep1g[b * kE + i]; D.rp2[i] = (short)rep2g[b * kE + i];
            D.cl1[i] = (short)clst1[b * kE + i]; D.cl2[i] = (short)clst2[b * kE + i];
        }
        for (int i = t; i < kE + 1; i += 256) {
            D.co1[i] = coff1[b * 193 + i]; D.co2[i] = coff2[b * 193 + i];
        }
        __syncthreads();
        const float* Keb = Ke + (size_t)b * kE * kE;
        for (int chunk = ch0; chunk < 144; chunk += 64) {
            int idx = chunk * 256 + t;
            if (idx < kE * kE) {
                int i = idx / kE, j = idx - i * kE;
                if (D.rp1[i] == i && D.rp2[j] == j) {
                    float sum = 0.f;
                    for (int m = D.co1[i]; m < D.co1[i + 1]; ++m) {
                        int ii = D.cl1[m];
                        const float* kr = Keb + (size_t)ii * kE;
                        for (int n = D.co2[j]; n < D.co2[j + 1]; ++n) sum += kr[D.cl2[n]];
                    }
                    int rr = D.rs2[j] * 64 + D.rs1[i];
                    int cc = D.rd2[j] * 64 + D.rd1[i];
                    if (rr != cc && sum > 0.0f) atomicAdd(&degcnt[b * kNN + rr], 1);
                }
            }
        }
    }
    gsync(bars, 4);

    // ================= GNN layers + sinkhorns + final ======================
    layer_phase<1>(bid, t, u.ly, off1, lst1, off2, lst2, dst1, dst2,
                   Ke, nullptr, Kp, degcnt, W0, b0, S0, c0, xA, vbuf);
    gsync(bars, 5);
    if ((bid & 63) == 0) sink64_phase(bid >> 6, t, u.sk, vbuf, xA);
    gsync(bars, 6);
    layer_phase<17>(bid, t, u.ly, off1, lst1, off2, lst2, dst1, dst2,
                    Ke, xA, Kp, degcnt, W1, b1, S1, c1, xB, vbuf);
    gsync(bars, 7);
    if ((bid & 63) == 0) sink64_phase(bid >> 6, t, u.sk, vbuf, xB);
    gsync(bars, 8);
    layer_phase<17>(bid, t, u.ly, off1, lst1, off2, lst2, dst1, dst2,
                    Ke, xB, Kp, degcnt, W2, b2, S2, c2, xA, vbuf);
    gsync(bars, 9);
    if ((bid & 63) == 0) sink64_phase(bid >> 6, t, u.sk, vbuf, xA);
    gsync(bars, 10);
    if ((bid & 63) == 0) sink65_phase(bid >> 6, t, u.sk, xA, out, Wc, bc, binv, bars + 31);
    gsync(bars, 11);

    // ====================== final: global normalize ========================
    {
        const float gm = __int_as_float(
            __hip_atomic_load(bars + 31, __ATOMIC_RELAXED, __HIP_MEMORY_SCOPE_AGENT));
        if (t < 64) {
            const float inv = 1.f / gm;
            out[bid * 64 + t] *= inv;
        }
    }
}

// ---------------------------------------------------------------------------
extern "C" void kernel_launch(void* const* d_in, const int* in_sizes, int n_in,
                              void* d_out, int out_size, void* d_ws, size_t ws_size,
                              hipStream_t stream)
{
    (void)in_sizes; (void)n_in; (void)out_size; (void)ws_size;

    const float* x1    = (const float*)d_in[0];
    const float* x2    = (const float*)d_in[1];
    const float* e1    = (const float*)d_in[2];
    const float* e2    = (const float*)d_in[3];
    const float* Wp    = (const float*)d_in[4];
    const float* bp    = (const float*)d_in[5];
    const float* gamma = (const float*)d_in[6];
    const float* beta  = (const float*)d_in[7];
    const float* W0 = (const float*)d_in[8];
    const float* b0 = (const float*)d_in[9];
    const float* S0 = (const float*)d_in[10];
    const float* c0 = (const float*)d_in[11];
    const float* W1 = (const float*)d_in[12];
    const float* b1 = (const float*)d_in[13];
    const float* S1 = (const float*)d_in[14];
    const float* c1 = (const float*)d_in[15];
    const float* W2 = (const float*)d_in[16];
    const float* b2 = (const float*)d_in[17];
    const float* S2 = (const float*)d_in[18];
    const float* c2 = (const float*)d_in[19];
    const float* Wc = (const float*)d_in[20];
    const float* bc = (const float*)d_in[21];
    const float* binv = (const float*)d_in[22];
    const int* src1 = (const int*)d_in[23];
    const int* dst1 = (const int*)d_in[24];
    const int* src2 = (const int*)d_in[25];
    const int* dst2 = (const int*)d_in[26];

    float* out = (float*)d_out;
    float* wsf = (float*)d_ws;

    float* hbuf  = wsf;                    // 1,048,576
    float* P     = hbuf + 1048576;         // 4,194,304 (z=2 uses 2,097,152)
    float* Kp    = P + 4194304;            // 32768
    float* Ke    = Kp + 32768;             // 294912
    float* vbuf  = Ke + 294912;            // 32768
    float* xA    = vbuf + 32768;           // 557056
    float* xB    = xA + 557056;            // 557056
    float* stats = xB + 557056;            // 2048
    int*   degcnt = (int*)(stats + 2048);  // 32768
    int*   off1 = degcnt + 32768;          // 520
    int*   off2 = off1 + 520;              // 520
    int*   lst1 = off2 + 520;              // 1536
    int*   lst2 = lst1 + 1536;             // 1536
    int*   rep1g = lst2 + 1536;            // 1536
    int*   rep2g = rep1g + 1536;           // 1536
    int*   coff1 = rep2g + 1536;           // 1544
    int*   coff2 = coff1 + 1544;           // 1544
    int*   clst1 = coff2 + 1544;           // 1536
    int*   clst2 = clst1 + 1536;           // 1536
    int*   bars  = clst2 + 1536;           // 32 (barrier slots + gmax bits)

    hipMemsetAsync(bars, 0, 32 * sizeof(int), stream);
    mega<<<dim3(GRID), dim3(256), 0, stream>>>(
        x1, x2, e1, e2, Wp, bp, gamma, beta,
        W0, b0, S0, c0, W1, b1, S1, c1, W2, b2, S2, c2,
        Wc, bc, binv, src1, dst1, src2, dst2,
        P, hbuf, stats, Kp, Ke, vbuf, xA, xB,
        degcnt, off1, off2, lst1, lst2, rep1g, rep2g,
        coff1, coff2, clst1, clst2, bars, out);
}

// Round 3
// 425.522 us; speedup vs baseline: 4.2600x; 1.7489x over previous
//
#include <hip/hip_runtime.h>

constexpr int kB   = 8;
constexpr int kN   = 64;
constexpr int kE   = 192;
constexpr int kDin = 1024;
constexpr int kDp  = 256;
constexpr int kNN  = 4096;
constexpr float kTauInv = 20.0f;
constexpr int GRID = 512;

// ---------------------------------------------------------------------------
// LDS phase union — max member (csr) = 38,400 B -> 2 blocks/CU fits
// ---------------------------------------------------------------------------
struct SmemGemm {
    float As[2][16][36]; float Ws[2][16][68];
    float colS[64], colS2[64];
};
struct SmemBN   { float wsum[4]; };
struct SmemSim  { float Xs[32][36]; float Ys[32][36]; };
struct SmemCsr  {
    int km1[4096], km2[4096];
    short es1[kE], es2[kE], rp1[kE], rp2[kE];
    int cnt1[64], cnt2[64], pos1[64], pos2[64];
    int ccnt1[kE], ccnt2[kE], cpos1[kE], cpos2[kE];
};
struct SmemPd   {
    short rs1[kE], rd1[kE], rs2[kE], rd2[kE], rp1[kE], rp2[kE];
    int co1[kE + 1], co2[kE + 1];
    short cl1[kE], cl2[kE];
};
struct SmemLayer {
    float mat[64][68]; float fL[64], gL[64];     // local sinkhorn (C=17 only)
    float WL[17 * 16]; float bL[16], SL[16]; float c0v;
    int jd2[kE]; int il[kE]; float msgT[64][18];
};
struct SmemSink {
    float mat[65][68]; float fL[65], gL[65];
    float WcL[17]; float bcv, binvv; float wred[4];
};
union __align__(16) SmemU {
    SmemGemm g; SmemBN bn; SmemSim sim; SmemCsr csr; SmemPd pd; SmemLayer ly; SmemSink sk;
};
static_assert(sizeof(SmemU) <= 49152, "LDS budget");

// ---------------------------------------------------------------------------
// Two-level grid barrier. R2 lesson: 512 pollers on ONE line queue the
// arrival RMWs behind a poll backlog (~40us/barrier + 30ms collapse outlier).
// Here: 8 group-counter lines (64 arrivals each) -> root line -> 8 flag
// lines; waiters poll only their group flag (64 pollers/line). Relaxed
// atomics everywhere; cache maintenance once per barrier via fences.
// Slot stride 512 ints; slots memset-zeroed before launch.
// ---------------------------------------------------------------------------
__device__ __forceinline__ void gsync(int* bars, int slot)
{
    __syncthreads();
    if (threadIdx.x == 0) {
        int* base = bars + slot * 512;
        const int g = (int)blockIdx.x >> 6;
        __builtin_amdgcn_fence(__ATOMIC_RELEASE, "agent");   // writeback once
        int prev = __hip_atomic_fetch_add(&base[g * 16], 1, __ATOMIC_RELAXED,
                                          __HIP_MEMORY_SCOPE_AGENT);
        if (prev == 63) {
            int r = __hip_atomic_fetch_add(&base[128], 1, __ATOMIC_RELAXED,
                                           __HIP_MEMORY_SCOPE_AGENT);
            if (r == 7) {
#pragma unroll
                for (int gg = 0; gg < 8; ++gg)
                    __hip_atomic_store(&base[256 + gg * 16], 1, __ATOMIC_RELAXED,
                                       __HIP_MEMORY_SCOPE_AGENT);
            }
        }
        while (__hip_atomic_load(&base[256 + g * 16], __ATOMIC_RELAXED,
                                 __HIP_MEMORY_SCOPE_AGENT) == 0)
            __builtin_amdgcn_s_sleep(16);
        __builtin_amdgcn_fence(__ATOMIC_ACQUIRE, "agent");   // invalidate once
    }
    __syncthreads();
}

// ---------------------------------------------------------------------------
// Local (redundant, per-block) 64x64 sinkhorn from vbuf into LDS.
// On return mat[p][q] = exp-probability; row q*64+p of the batch maps to
// mat[p][q]. Identical op order to the verified 8-block sink64_phase.
// ---------------------------------------------------------------------------
__device__ void sink64_local(int b, int t, float (*mat)[68], float* fL, float* gL,
                             const float* __restrict__ vin)
{
    for (int idx = t; idx < kNN; idx += 256) {
        int q = idx >> 6, p = idx & 63;
        mat[p][q] = vin[b * kNN + idx] * kTauInv;
    }
    if (t < 64) { fL[t] = 0.f; gL[t] = 0.f; }
    __syncthreads();
    const int r = t >> 2, s = t & 3;
    float tv[16];
    for (int it = 0; it < 10; ++it) {
        float mx = -1e30f;
#pragma unroll
        for (int k = 0; k < 16; ++k) {
            float v = mat[r][s + 4 * k] + gL[s + 4 * k];
            tv[k] = v; mx = fmaxf(mx, v);
        }
        mx = fmaxf(mx, __shfl_xor(mx, 1));
        mx = fmaxf(mx, __shfl_xor(mx, 2));
        float sum = 0.f;
#pragma unroll
        for (int k = 0; k < 16; ++k) sum += __expf(tv[k] - mx);
        sum += __shfl_xor(sum, 1);
        sum += __shfl_xor(sum, 2);
        if (s == 0) fL[r] = -(mx + __logf(sum));
        __syncthreads();
        mx = -1e30f;
#pragma unroll
        for (int k = 0; k < 16; ++k) {
            float v = mat[s + 4 * k][r] + fL[s + 4 * k];
            tv[k] = v; mx = fmaxf(mx, v);
        }
        mx = fmaxf(mx, __shfl_xor(mx, 1));
        mx = fmaxf(mx, __shfl_xor(mx, 2));
        sum = 0.f;
#pragma unroll
        for (int k = 0; k < 16; ++k) sum += __expf(tv[k] - mx);
        sum += __shfl_xor(sum, 1);
        sum += __shfl_xor(sum, 2);
        if (s == 0) gL[r] = -(mx + __logf(sum));
        __syncthreads();
    }
    const float fr = fL[r];
#pragma unroll
    for (int k = 0; k < 16; ++k) {
        int q = s + 4 * k;
        mat[r][q] = __expf(mat[r][q] + fr + gL[q]);
    }
    __syncthreads();
}

// ---------------------------------------------------------------------------
// Fused gather + layer MLP. For C==17 the ss channel comes from the local
// sinkhorn in L.mat (computed here from vprev) instead of global memory.
// ---------------------------------------------------------------------------
template <int C>
__device__ void layer_phase(int bid, int t, SmemLayer& L,
    const int* off1, const int* lst1, const int* off2, const int* lst2,
    const int* d1, const int* d2,
    const float* Ke, const float* x, const float* Kp, const int* degcnt,
    const float* W, const float* bb, const float* S, const float* c0,
    const float* vprev, float* xn, float* vout)
{
    const int r2 = bid & 63, b = bid >> 6;
    for (int k = t; k < C * 16; k += 256) L.WL[k] = W[k];
    if (t < 16) { L.bL[t] = bb[t]; L.SL[t] = S[t]; }
    if (t == 0) L.c0v = c0[0];
    const int j0 = off2[b * 65 + r2];
    const int n2 = off2[b * 65 + r2 + 1] - j0;
    for (int k = t; k < n2; k += 256) {
        int j = lst2[b * kE + j0 + k];
        L.jd2[k] = (j << 8) | d2[b * kE + j];
    }
    for (int k = t; k < kE; k += 256) {
        int i = lst1[b * kE + k];
        L.il[k] = (i << 8) | d1[b * kE + i];
    }
    if (C == 17) {
        sink64_local(b, t, L.mat, L.fL, L.gL, vprev);  // includes syncthreads
    } else {
        __syncthreads();
    }

    const int r1 = t >> 2, lane = t & 3;
    const int i0 = off1[b * 65 + r1], i1 = off1[b * 65 + r1 + 1];
    const float* Keb = Ke + (size_t)b * kE * kE;
    const float* KpB = Kp + (size_t)b * kNN;

    if (C == 1) {
        float acc = 0.f;
        for (int k = 0; k < n2; ++k) {
            int pk = L.jd2[k], j = pk >> 8, dd2 = pk & 255;
            for (int m = i0 + lane; m < i1; m += 4) {
                int pi = L.il[m], i = pi >> 8, dd1 = pi & 255;
                if (dd2 == r2 && dd1 == r1) continue;
                acc += Keb[(size_t)i * kE + j] * KpB[dd1 * 64 + dd2];
            }
        }
        acc += __shfl_xor(acc, 1);
        acc += __shfl_xor(acc, 2);
        if (lane == 0) L.msgT[r1][0] = acc;
    } else {
        const float* xb = x + (size_t)b * kNN * C;
        float acc[5];
#pragma unroll
        for (int cc = 0; cc < 5; ++cc) acc[cc] = 0.f;
        for (int k = 0; k < n2; ++k) {
            int pk = L.jd2[k], j = pk >> 8, dd2 = pk & 255;
            const float* xrow = xb + (size_t)(dd2 * 64) * C;
            for (int m = i0; m < i1; ++m) {
                int pi = L.il[m], i = pi >> 8, dd1 = pi & 255;
                if (dd2 == r2 && dd1 == r1) continue;
                float kv = Keb[(size_t)i * kE + j];
                const float* xc = xrow + dd1 * C;
#pragma unroll
                for (int cc = 0; cc < 4; ++cc)
                    acc[cc] += kv * xc[lane + cc * 4];
                if (lane == 0) acc[4] += kv * L.mat[dd1][dd2];   // ss from LDS
            }
        }
#pragma unroll
        for (int cc = 0; cc < 5; ++cc) {
            int c = lane + cc * 4;
            if (c < C) L.msgT[r1][c] = acc[cc];
        }
    }
    __syncthreads();

    const int row = r2 * 64 + r1;
    const int idx = b * kNN + row;
    const float kd = KpB[r1 * 64 + r2];
    const float dg = fmaxf((float)(degcnt[idx] + (kd > 0.f ? 1 : 0)), 1.f);
    float m[C];
    if (C == 1) {
        m[0] = (L.msgT[r1][0] + kd * kd) / dg;
    } else {
        const float* xr = x + (size_t)idx * C;
#pragma unroll
        for (int c = 0; c < 16; ++c)
            m[c] = (L.msgT[r1][c] + kd * xr[c]) / dg;
        m[16] = (L.msgT[r1][16] + kd * L.mat[r1][r2]) / dg;   // own ss from LDS
    }
    float vpart = 0.f;
#pragma unroll
    for (int ff = 0; ff < 4; ++ff) {
        int f = lane * 4 + ff;
        float a = L.bL[f];
#pragma unroll
        for (int c = 0; c < C; ++c) a += m[c] * L.WL[c * 16 + f];
        float h = fmaxf(a, 0.f);
        xn[(size_t)idx * 17 + f] = h;
        vpart += h * L.SL[f];
    }
    vpart += __shfl_xor(vpart, 1);
    vpart += __shfl_xor(vpart, 2);
    if (lane == 0) vout[idx] = vpart + L.c0v;
}

// ---------------------------------------------------------------------------
// Persistent megakernel: 512 blocks x 256 threads, 7 grid barriers.
// ---------------------------------------------------------------------------
__global__ __launch_bounds__(256, 2) void mega(
    const float* __restrict__ x1, const float* __restrict__ x2,
    const float* __restrict__ e1, const float* __restrict__ e2,
    const float* __restrict__ Wp, const float* __restrict__ bp,
    const float* __restrict__ gamma, const float* __restrict__ beta,
    const float* __restrict__ W0, const float* __restrict__ b0,
    const float* __restrict__ S0, const float* __restrict__ c0,
    const float* __restrict__ W1, const float* __restrict__ b1,
    const float* __restrict__ S1, const float* __restrict__ c1,
    const float* __restrict__ W2, const float* __restrict__ b2,
    const float* __restrict__ S2, const float* __restrict__ c2,
    const float* __restrict__ Wc, const float* __restrict__ bc,
    const float* __restrict__ binv,
    const int* __restrict__ src1, const int* __restrict__ dst1,
    const int* __restrict__ src2, const int* __restrict__ dst2,
    float* __restrict__ hbuf, float* __restrict__ stats,
    float* __restrict__ Kp, float* __restrict__ Ke,
    float* __restrict__ vA, float* __restrict__ vB,
    float* __restrict__ xA, float* __restrict__ xB,
    int* __restrict__ degcnt,
    int* __restrict__ off1, int* __restrict__ off2,
    int* __restrict__ lst1, int* __restrict__ lst2,
    int* __restrict__ rep1g, int* __restrict__ rep2g,
    int* __restrict__ coff1, int* __restrict__ coff2,
    int* __restrict__ clst1, int* __restrict__ clst2,
    int* __restrict__ bars, float* __restrict__ out)
{
    const int bid = blockIdx.x;
    const int t = threadIdx.x;
    __shared__ SmemU u;

    // ====== phase 0: projection GEMM, full K, + bias + BN-stats ===========
    // 32x64 tiles: 128 rt x 4 ct = 512 blocks. W-tile re-reads hit L2
    // (Wp = 1 MB, L2-resident per XCD); no split-K, no P round-trip.
    {
        const int rt = bid >> 2, ct = bid & 3;
        const int grow0 = rt * 32, col0 = ct * 64;
        const int seg = (rt < 16) ? 0 : (rt < 32 ? 1 : (rt < 80 ? 2 : 3));
        const float* src; int lrow0;
        if (rt < 16)      { src = x1; lrow0 = grow0; }
        else if (rt < 32) { src = x2; lrow0 = grow0 - 512; }
        else if (rt < 80) { src = e1; lrow0 = grow0 - 1024; }
        else              { src = e2; lrow0 = grow0 - 2560; }

        const int tx = t & 15, ty = t >> 4;
        const int arow = t >> 3, acol = (t & 7) * 2;
        const int wrow = t >> 4, wcol = (t & 15) * 4;
        if (t < 64) { u.g.colS[t] = 0.f; u.g.colS2[t] = 0.f; }

        const float* Abase = src + (size_t)(lrow0 + arow) * kDin + acol;
        const float* Wbase = Wp + (size_t)wrow * kDp + col0 + wcol;

        float2 a2 = *(const float2*)Abase;
        float4 w4 = *(const float4*)Wbase;
        float acc[2][4] = {};

        for (int c = 0; c < 64; ++c) {
            const int cur = c & 1;
            u.g.As[cur][acol + 0][arow] = a2.x;
            u.g.As[cur][acol + 1][arow] = a2.y;
            *(float4*)&u.g.Ws[cur][wrow][wcol] = w4;
            __syncthreads();
            if (c < 63) {
                a2 = *(const float2*)(Abase + (c + 1) * 16);
                w4 = *(const float4*)(Wbase + (size_t)(c + 1) * 16 * kDp);
            }
#pragma unroll
            for (int kk = 0; kk < 16; ++kk) {
                float2 av = *(const float2*)&u.g.As[cur][kk][ty * 2];
                float4 wv = *(const float4*)&u.g.Ws[cur][kk][tx * 4];
                acc[0][0] += av.x * wv.x; acc[0][1] += av.x * wv.y;
                acc[0][2] += av.x * wv.z; acc[0][3] += av.x * wv.w;
                acc[1][0] += av.y * wv.x; acc[1][1] += av.y * wv.y;
                acc[1][2] += av.y * wv.z; acc[1][3] += av.y * wv.w;
            }
        }
        const float4 bb4 = *(const float4*)&bp[col0 + tx * 4];
        float sC[4] = {0.f, 0.f, 0.f, 0.f}, qC[4] = {0.f, 0.f, 0.f, 0.f};
#pragma unroll
        for (int i = 0; i < 2; ++i) {
            const int row = grow0 + ty * 2 + i;
            float4 v;
            v.x = acc[i][0] + bb4.x; v.y = acc[i][1] + bb4.y;
            v.z = acc[i][2] + bb4.z; v.w = acc[i][3] + bb4.w;
            *(float4*)&hbuf[(size_t)row * kDp + col0 + tx * 4] = v;
            sC[0] += v.x; sC[1] += v.y; sC[2] += v.z; sC[3] += v.w;
            qC[0] += v.x * v.x; qC[1] += v.y * v.y;
            qC[2] += v.z * v.z; qC[3] += v.w * v.w;
        }
#pragma unroll
        for (int j = 0; j < 4; ++j) {
            atomicAdd(&u.g.colS[tx * 4 + j], sC[j]);
            atomicAdd(&u.g.colS2[tx * 4 + j], qC[j]);
        }
        __syncthreads();
        if (t < 64) {
            atomicAdd(&stats[seg * 512 + col0 + t], u.g.colS[t]);
            atomicAdd(&stats[seg * 512 + 256 + col0 + t], u.g.colS2[t]);
        }
    }
    gsync(bars, 0);

    // ===== phase 1: BN+ReLU+L2norm (bid<504)  ||  build_csr (bid>=504) =====
    if (bid < 504) {
        const float ga = gamma[t], be = beta[t];
        for (int r = bid; r < 4096; r += 504) {
            const int seg = (r < 512) ? 0 : (r < 1024 ? 1 : (r < 2560 ? 2 : 3));
            const float n = (seg < 2) ? 512.f : 1536.f;
            const float mu = stats[seg * 512 + t] / n;
            const float var = stats[seg * 512 + 256 + t] / n - mu * mu;
            const float istd = rsqrtf(var + 1e-5f);
            float v = hbuf[(size_t)r * kDp + t];
            float p = fmaxf((v - mu) * istd * ga + be, 0.f);
            float ss = p * p;
#pragma unroll
            for (int o = 32; o >= 1; o >>= 1) ss += __shfl_xor(ss, o);
            if ((t & 63) == 0) u.bn.wsum[t >> 6] = ss;
            __syncthreads();
            const float tot = u.bn.wsum[0] + u.bn.wsum[1] + u.bn.wsum[2] + u.bn.wsum[3];
            const float scale = 1.f / fmaxf(sqrtf(tot), 1e-12f);
            hbuf[(size_t)r * kDp + t] = p * scale;
            __syncthreads();
        }
    } else {
        const int b = bid - 504;
        auto& C = u.csr;
        for (int i = t; i < 4096; i += 256) {
            C.km1[i] = 0x7fffffff; C.km2[i] = 0x7fffffff;
            degcnt[b * kNN + i] = 0;
        }
        if (t < 64) { C.cnt1[t] = 0; C.cnt2[t] = 0; }
        for (int i = t; i < kE; i += 256) { C.ccnt1[i] = 0; C.ccnt2[i] = 0; }
        __syncthreads();
        if (t < kE) {
            int v1 = src1[b * kE + t], v2 = src2[b * kE + t];
            C.es1[t] = (short)v1; C.es2[t] = (short)v2;
            atomicAdd(&C.cnt1[v1], 1);
            atomicAdd(&C.cnt2[v2], 1);
            atomicMin(&C.km1[v1 * 64 + dst1[b * kE + t]], t);
            atomicMin(&C.km2[v2 * 64 + dst2[b * kE + t]], t);
        }
        __syncthreads();
        if (t < kE) {
            int r1 = C.km1[C.es1[t] * 64 + dst1[b * kE + t]];
            int r2 = C.km2[C.es2[t] * 64 + dst2[b * kE + t]];
            C.rp1[t] = (short)r1; C.rp2[t] = (short)r2;
            rep1g[b * kE + t] = r1; rep2g[b * kE + t] = r2;
            atomicAdd(&C.ccnt1[r1], 1);
            atomicAdd(&C.ccnt2[r2], 1);
        }
        __syncthreads();
        if (t == 0) {
            int a = 0, c = 0;
            for (int v = 0; v < 64; ++v) { C.pos1[v] = a; a += C.cnt1[v]; C.pos2[v] = c; c += C.cnt2[v]; }
            a = 0; c = 0;
            for (int v = 0; v < kE; ++v) { C.cpos1[v] = a; a += C.ccnt1[v]; C.cpos2[v] = c; c += C.ccnt2[v]; }
        }
        __syncthreads();
        if (t < 64) { off1[b * 65 + t] = C.pos1[t]; off2[b * 65 + t] = C.pos2[t]; }
        if (t == 0) { off1[b * 65 + 64] = kE; off2[b * 65 + 64] = kE; }
        if (t < kE) { coff1[b * 193 + t] = C.cpos1[t]; coff2[b * 193 + t] = C.cpos2[t]; }
        if (t == 0) { coff1[b * 193 + kE] = kE; coff2[b * 193 + kE] = kE; }
        __syncthreads();
        if (t < kE) {
            int p = atomicAdd(&C.pos1[C.es1[t]], 1); lst1[b * kE + p] = t;
            int q = atomicAdd(&C.pos2[C.es2[t]], 1); lst2[b * kE + q] = t;
            int cp = atomicAdd(&C.cpos1[C.rp1[t]], 1); clst1[b * kE + cp] = t;
            int cq = atomicAdd(&C.cpos2[C.rp2[t]], 1); clst2[b * kE + cq] = t;
        }
    }
    gsync(bars, 1);

    // ==================== phase 2: similarity GEMMs ========================
    if (bid < 320) {
        const int id = bid % 40, b = bid / 40;
        int mt, nt, ldo; const float *X, *Y; float* outp; float scale;
        if (id < 4) {
            mt = (id >> 1) * 32; nt = (id & 1) * 32; ldo = 64;
            X = hbuf + (size_t)b * 64 * kDp;
            Y = hbuf + (512 + (size_t)b * 64) * kDp;
            outp = Kp + (size_t)b * 4096; scale = 1.0f;
        } else {
            int e = id - 4;
            mt = (e / 6) * 32; nt = (e % 6) * 32; ldo = 192;
            X = hbuf + (1024 + (size_t)b * 192) * kDp;
            Y = hbuf + (2560 + (size_t)b * 192) * kDp;
            outp = Ke + (size_t)b * 36864; scale = 0.5f;
        }
        const int row = t >> 3, kq = t & 7;
        const int ty = t >> 4, tx = t & 15;
        float acc[2][2] = {};
        for (int k0 = 0; k0 < kDp; k0 += 32) {
            float4 xa = *(const float4*)(X + (size_t)(mt + row) * kDp + k0 + kq * 4);
            float4 ya = *(const float4*)(Y + (size_t)(nt + row) * kDp + k0 + kq * 4);
            u.sim.Xs[kq * 4 + 0][row] = xa.x; u.sim.Xs[kq * 4 + 1][row] = xa.y;
            u.sim.Xs[kq * 4 + 2][row] = xa.z; u.sim.Xs[kq * 4 + 3][row] = xa.w;
            u.sim.Ys[kq * 4 + 0][row] = ya.x; u.sim.Ys[kq * 4 + 1][row] = ya.y;
            u.sim.Ys[kq * 4 + 2][row] = ya.z; u.sim.Ys[kq * 4 + 3][row] = ya.w;
            __syncthreads();
#pragma unroll
            for (int kk = 0; kk < 32; ++kk) {
                float2 xv = *(const float2*)&u.sim.Xs[kk][ty * 2];
                float2 yv = *(const float2*)&u.sim.Ys[kk][tx * 2];
                acc[0][0] += xv.x * yv.x; acc[0][1] += xv.x * yv.y;
                acc[1][0] += xv.y * yv.x; acc[1][1] += xv.y * yv.y;
            }
            __syncthreads();
        }
#pragma unroll
        for (int i = 0; i < 2; ++i)
#pragma unroll
            for (int j = 0; j < 2; ++j)
                outp[(size_t)(mt + ty * 2 + i) * ldo + nt + tx * 2 + j] = scale * acc[i][j];
    }
    gsync(bars, 2);

    // ======================= phase 3: pairdeg ==============================
    {
        const int b = bid >> 6, ch0 = bid & 63;
        auto& D = u.pd;
        for (int i = t; i < kE; i += 256) {
            D.rs1[i] = (short)src1[b * kE + i]; D.rd1[i] = (short)dst1[b * kE + i];
            D.rs2[i] = (short)src2[b * kE + i]; D.rd2[i] = (short)dst2[b * kE + i];
            D.rp1[i] = (short)rep1g[b * kE + i]; D.rp2[i] = (short)rep2g[b * kE + i];
            D.cl1[i] = (short)clst1[b * kE + i]; D.cl2[i] = (short)clst2[b * kE + i];
        }
        for (int i = t; i < kE + 1; i += 256) {
            D.co1[i] = coff1[b * 193 + i]; D.co2[i] = coff2[b * 193 + i];
        }
        __syncthreads();
        const float* Keb = Ke + (size_t)b * kE * kE;
        for (int chunk = ch0; chunk < 144; chunk += 64) {
            int idx = chunk * 256 + t;
            if (idx < kE * kE) {
                int i = idx / kE, j = idx - i * kE;
                if (D.rp1[i] == i && D.rp2[j] == j) {
                    float sum = 0.f;
                    for (int m = D.co1[i]; m < D.co1[i + 1]; ++m) {
                        int ii = D.cl1[m];
                        const float* kr = Keb + (size_t)ii * kE;
                        for (int n = D.co2[j]; n < D.co2[j + 1]; ++n) sum += kr[D.cl2[n]];
                    }
                    int rr = D.rs2[j] * 64 + D.rs1[i];
                    int cc = D.rd2[j] * 64 + D.rd1[i];
                    if (rr != cc && sum > 0.0f) atomicAdd(&degcnt[b * kNN + rr], 1);
                }
            }
        }
    }
    gsync(bars, 3);

    // ============ GNN layers (ss computed redundantly per block) ===========
    layer_phase<1>(bid, t, u.ly, off1, lst1, off2, lst2, dst1, dst2,
                   Ke, nullptr, Kp, degcnt, W0, b0, S0, c0, nullptr, xA, vA);
    gsync(bars, 4);
    layer_phase<17>(bid, t, u.ly, off1, lst1, off2, lst2, dst1, dst2,
                    Ke, xA, Kp, degcnt, W1, b1, S1, c1, vA, xB, vB);
    gsync(bars, 5);
    layer_phase<17>(bid, t, u.ly, off1, lst1, off2, lst2, dst1, dst2,
                    Ke, xB, Kp, degcnt, W2, b2, S2, c2, vB, xA, vA);
    gsync(bars, 6);

    // ====== final: 8 blocks only — sink64 + sink65 + max + normalize =======
    if ((bid & 63) == 0) {
        const int b = bid >> 6;
        auto& S = u.sk;
        if (t < 17) S.WcL[t] = Wc[t];
        if (t == 17) S.bcv = bc[0];
        if (t == 18) S.binvv = binv[0];
        sink64_local(b, t, S.mat, S.fL, S.gL, vA);   // ss in mat[0..63][0..63]

        // build 65x65 log-matrix in place (elementwise; own-cell reads only)
        for (int idx = t; idx < 65 * 65; idx += 256) {
            int q = idx / 65, p = idx - q * 65;
            float v;
            if (p < 64 && q < 64) {
                const float* xr = xA + (size_t)(b * kNN + q * 64 + p) * 17;
                v = S.bcv;
#pragma unroll
                for (int c = 0; c < 16; ++c) v += xr[c] * S.WcL[c];
                v += S.mat[p][q] * S.WcL[16];
            } else v = S.binvv;
            S.mat[p][q] = v;
        }
        if (t < 65) { S.fL[t] = 0.f; S.gL[t] = 0.f; }
        __syncthreads();

        const int r = t >> 2, s = t & 3;
        for (int it = 0; it < 10; ++it) {
            for (int rr = r; rr < 65; rr += 64) {
                float tv[17];
                float mx = -1e30f;
#pragma unroll
                for (int k = 0; k < 17; ++k) {
                    int q = s + 4 * k;
                    float v = (q < 65) ? S.mat[rr][q] + S.gL[q] : -1e30f;
                    tv[k] = v; mx = fmaxf(mx, v);
                }
                mx = fmaxf(mx, __shfl_xor(mx, 1));
                mx = fmaxf(mx, __shfl_xor(mx, 2));
                float sum = 0.f;
#pragma unroll
                for (int k = 0; k < 17; ++k) sum += __expf(tv[k] - mx);
                sum += __shfl_xor(sum, 1);
                sum += __shfl_xor(sum, 2);
                if (s == 0) S.fL[rr] = -(mx + __logf(sum));
            }
            __syncthreads();
            for (int rr = r; rr < 65; rr += 64) {
                float tv[17];
                float mx = -1e30f;
#pragma unroll
                for (int k = 0; k < 17; ++k) {
                    int p = s + 4 * k;
                    float v = (p < 65) ? S.mat[p][rr] + S.fL[p] : -1e30f;
                    tv[k] = v; mx = fmaxf(mx, v);
                }
                mx = fmaxf(mx, __shfl_xor(mx, 1));
                mx = fmaxf(mx, __shfl_xor(mx, 2));
                float sum = 0.f;
#pragma unroll
                for (int k = 0; k < 17; ++k) sum += __expf(tv[k] - mx);
                sum += __shfl_xor(sum, 1);
                sum += __shfl_xor(sum, 2);
                if (s == 0) S.gL[rr] = -(mx + __logf(sum));
            }
            __syncthreads();
        }

        // exp values held in registers; global max via atomicMax
        float ev[16];
        float lmax = 0.f;
        {
            const float fr = S.fL[r];
#pragma unroll
            for (int k = 0; k < 16; ++k) {
                int q = s + 4 * k;                       // q <= 63
                ev[k] = __expf(S.mat[r][q] + fr + S.gL[q]);
                lmax = fmaxf(lmax, ev[k]);
            }
        }
#pragma unroll
        for (int o = 32; o >= 1; o >>= 1) lmax = fmaxf(lmax, __shfl_xor(lmax, o));
        if ((t & 63) == 0) S.wred[t >> 6] = lmax;
        __syncthreads();
        int* mcnt = bars + 3584;
        int* gmax = bars + 3600;
        if (t == 0) {
            float mb = fmaxf(fmaxf(S.wred[0], S.wred[1]), fmaxf(S.wred[2], S.wred[3]));
            atomicMax(gmax, __float_as_int(mb));   // all values > 0
            __builtin_amdgcn_fence(__ATOMIC_RELEASE, "agent");
            __hip_atomic_fetch_add(mcnt, 1, __ATOMIC_RELAXED, __HIP_MEMORY_SCOPE_AGENT);
            while (__hip_atomic_load(mcnt, __ATOMIC_RELAXED, __HIP_MEMORY_SCOPE_AGENT) < 8)
                __builtin_amdgcn_s_sleep(2);
            __builtin_amdgcn_fence(__ATOMIC_ACQUIRE, "agent");
        }
        __syncthreads();
        const float inv = 1.f / __int_as_float(
            __hip_atomic_load(gmax, __ATOMIC_RELAXED, __HIP_MEMORY_SCOPE_AGENT));
#pragma unroll
        for (int k = 0; k < 16; ++k) {
            int q = s + 4 * k;
            out[((size_t)b * kN + r) * kN + q] = ev[k] * inv;
        }
    }
}

// ---------------------------------------------------------------------------
extern "C" void kernel_launch(void* const* d_in, const int* in_sizes, int n_in,
                              void* d_out, int out_size, void* d_ws, size_t ws_size,
                              hipStream_t stream)
{
    (void)in_sizes; (void)n_in; (void)out_size; (void)ws_size;

    const float* x1    = (const float*)d_in[0];
    const float* x2    = (const float*)d_in[1];
    const float* e1    = (const float*)d_in[2];
    const float* e2    = (const float*)d_in[3];
    const float* Wp    = (const float*)d_in[4];
    const float* bp    = (const float*)d_in[5];
    const float* gamma = (const float*)d_in[6];
    const float* beta  = (const float*)d_in[7];
    const float* W0 = (const float*)d_in[8];
    const float* b0 = (const float*)d_in[9];
    const float* S0 = (const float*)d_in[10];
    const float* c0 = (const float*)d_in[11];
    const float* W1 = (const float*)d_in[12];
    const float* b1 = (const float*)d_in[13];
    const float* S1 = (const float*)d_in[14];
    const float* c1 = (const float*)d_in[15];
    const float* W2 = (const float*)d_in[16];
    const float* b2 = (const float*)d_in[17];
    const float* S2 = (const float*)d_in[18];
    const float* c2 = (const float*)d_in[19];
    const float* Wc = (const float*)d_in[20];
    const float* bc = (const float*)d_in[21];
    const float* binv = (const float*)d_in[22];
    const int* src1 = (const int*)d_in[23];
    const int* dst1 = (const int*)d_in[24];
    const int* src2 = (const int*)d_in[25];
    const int* dst2 = (const int*)d_in[26];

    float* out = (float*)d_out;
    float* wsf = (float*)d_ws;

    float* hbuf  = wsf;                    // 1,048,576
    float* Kp    = hbuf + 1048576;         // 32,768
    float* Ke    = Kp + 32768;             // 294,912
    float* vA    = Ke + 294912;            // 32,768
    float* vB    = vA + 32768;             // 32,768
    float* xA    = vB + 32768;             // 557,056
    float* xB    = xA + 557056;            // 557,056
    int*   degcnt = (int*)(xB + 557056);   // 32,768
    int*   off1 = degcnt + 32768;          // 520
    int*   off2 = off1 + 520;              // 520
    int*   lst1 = off2 + 520;              // 1,536
    int*   lst2 = lst1 + 1536;             // 1,536
    int*   rep1g = lst2 + 1536;            // 1,536
    int*   rep2g = rep1g + 1536;           // 1,536
    int*   coff1 = rep2g + 1536;           // 1,544
    int*   coff2 = coff1 + 1544;           // 1,544
    int*   clst1 = coff2 + 1544;           // 1,536
    int*   clst2 = clst1 + 1536;           // 1,536
    float* stats = (float*)(clst2 + 1536); // 2,048   (zeroed by memset)
    int*   bars  = (int*)(stats + 2048);   // 4,096   (zeroed by memset)

    // one memset zeroes stats + all barrier slots + minibar + gmax
    hipMemsetAsync(stats, 0, (2048 + 4096) * sizeof(int), stream);
    mega<<<dim3(GRID), dim3(256), 0, stream>>>(
        x1, x2, e1, e2, Wp, bp, gamma, beta,
        W0, b0, S0, c0, W1, b1, S1, c1, W2, b2, S2, c2,
        Wc, bc, binv, src1, dst1, src2, dst2,
        hbuf, stats, Kp, Ke, vA, vB, xA, xB,
        degcnt, off1, off2, lst1, lst2, rep1g, rep2g,
        coff1, coff2, clst1, clst2, bars, out);
}

// Round 5
// 413.253 us; speedup vs baseline: 4.3865x; 1.0297x over previous
//
#include <hip/hip_runtime.h>

constexpr int kB   = 8;
constexpr int kN   = 64;
constexpr int kE   = 192;
constexpr int kDin = 1024;
constexpr int kDp  = 256;
constexpr int kNN  = 4096;
constexpr float kTauInv = 20.0f;
constexpr int GRID = 512;

typedef float vfloat4 __attribute__((ext_vector_type(4)));

// ---------------------------------------------------------------------------
// LDS phase union — max member (csr) = 38,400 B
// ---------------------------------------------------------------------------
struct SmemGemm {
    float As[2][16][36]; float Ws[2][16][68];
    float colS[64], colS2[64];
};
struct SmemSim  {
    float Xs[32][36]; float Ys[32][36];
    float muX[256], isX[256], muY[256], isY[256];
    float ga[256], be[256];
    float scX[32], scY[32];
};
struct SmemCsr  {
    int km1[4096], km2[4096];
    short es1[kE], es2[kE], rp1[kE], rp2[kE];
    int cnt1[64], cnt2[64], pos1[64], pos2[64];
    int ccnt1[kE], ccnt2[kE], cpos1[kE], cpos2[kE];
};
struct SmemLayer {
    float mat[64][68]; float fL[64], gL[64];     // local sinkhorn (C=17 only)
    float WL[17 * 16]; float bL[16], SL[16]; float c0v;
    int jd2[kE]; int il[kE]; float msgT[64][18];
    int co1L[kE + 1], co2L[kE + 1];              // cluster CSR (C=1 only)
    short cl1L[kE], cl2L[kE];
};
struct SmemSink {
    float mat[65][68]; float fL[65], gL[65];
    float WcL[17]; float bcv, binvv; float wred[4];
};
union __align__(16) SmemU {
    SmemGemm g; SmemSim sim; SmemCsr csr; SmemLayer ly; SmemSink sk;
};
static_assert(sizeof(SmemU) <= 49152, "LDS budget");

// ---------------------------------------------------------------------------
// Two-level grid barrier (R2: relaxed polls; R3: tree). Per-barrier cost is
// fence pair + cold refill (~30us) -> this round cuts barrier COUNT 7->5.
// ---------------------------------------------------------------------------
__device__ __forceinline__ void gsync(int* bars, int slot)
{
    __syncthreads();
    if (threadIdx.x == 0) {
        int* base = bars + slot * 512;
        const int g = (int)blockIdx.x >> 6;
        __builtin_amdgcn_fence(__ATOMIC_RELEASE, "agent");   // writeback once
        int prev = __hip_atomic_fetch_add(&base[g * 16], 1, __ATOMIC_RELAXED,
                                          __HIP_MEMORY_SCOPE_AGENT);
        if (prev == 63) {
            int r = __hip_atomic_fetch_add(&base[128], 1, __ATOMIC_RELAXED,
                                           __HIP_MEMORY_SCOPE_AGENT);
            if (r == 7) {
#pragma unroll
                for (int gg = 0; gg < 8; ++gg)
                    __hip_atomic_store(&base[256 + gg * 16], 1, __ATOMIC_RELAXED,
                                       __HIP_MEMORY_SCOPE_AGENT);
            }
        }
        while (__hip_atomic_load(&base[256 + g * 16], __ATOMIC_RELAXED,
                                 __HIP_MEMORY_SCOPE_AGENT) == 0)
            __builtin_amdgcn_s_sleep(16);
        __builtin_amdgcn_fence(__ATOMIC_ACQUIRE, "agent");   // invalidate once
    }
    __syncthreads();
}

// ---------------------------------------------------------------------------
// Local (redundant, per-block) 64x64 sinkhorn from vbuf into LDS.
// ---------------------------------------------------------------------------
__device__ void sink64_local(int b, int t, float (*mat)[68], float* fL, float* gL,
                             const float* __restrict__ vin)
{
    for (int idx = t; idx < kNN; idx += 256) {
        int q = idx >> 6, p = idx & 63;
        mat[p][q] = vin[b * kNN + idx] * kTauInv;
    }
    if (t < 64) { fL[t] = 0.f; gL[t] = 0.f; }
    __syncthreads();
    const int r = t >> 2, s = t & 3;
    float tv[16];
    for (int it = 0; it < 10; ++it) {
        float mx = -1e30f;
#pragma unroll
        for (int k = 0; k < 16; ++k) {
            float v = mat[r][s + 4 * k] + gL[s + 4 * k];
            tv[k] = v; mx = fmaxf(mx, v);
        }
        mx = fmaxf(mx, __shfl_xor(mx, 1));
        mx = fmaxf(mx, __shfl_xor(mx, 2));
        float sum = 0.f;
#pragma unroll
        for (int k = 0; k < 16; ++k) sum += __expf(tv[k] - mx);
        sum += __shfl_xor(sum, 1);
        sum += __shfl_xor(sum, 2);
        if (s == 0) fL[r] = -(mx + __logf(sum));
        __syncthreads();
        mx = -1e30f;
#pragma unroll
        for (int k = 0; k < 16; ++k) {
            float v = mat[s + 4 * k][r] + fL[s + 4 * k];
            tv[k] = v; mx = fmaxf(mx, v);
        }
        mx = fmaxf(mx, __shfl_xor(mx, 1));
        mx = fmaxf(mx, __shfl_xor(mx, 2));
        sum = 0.f;
#pragma unroll
        for (int k = 0; k < 16; ++k) sum += __expf(tv[k] - mx);
        sum += __shfl_xor(sum, 1);
        sum += __shfl_xor(sum, 2);
        if (s == 0) gL[r] = -(mx + __logf(sum));
        __syncthreads();
    }
    const float fr = fL[r];
#pragma unroll
    for (int k = 0; k < 16; ++k) {
        int q = s + 4 * k;
        mat[r][q] = __expf(mat[r][q] + fr + gL[q]);
    }
    __syncthreads();
}

// ---------------------------------------------------------------------------
// Fused gather + layer MLP. C==1: also computes this row's degree inline
// (same per-pair summation as old pairdeg) and nt-stores it for layers 1-2.
// C==17: ss channel from the local sinkhorn in L.mat.
// ---------------------------------------------------------------------------
template <int C>
__device__ void layer_phase(int bid, int t, SmemLayer& L,
    const int* off1, const int* lst1, const int* off2, const int* lst2,
    const int* d1, const int* d2,
    const int* rep1g, const int* rep2g,
    const int* coff1, const int* coff2,
    const int* clst1, const int* clst2,
    const float* Ke, const float* x, const float* Kp, int* degcnt,
    const float* W, const float* bb, const float* S, const float* c0,
    const float* vprev, float* xn, float* vout)
{
    const int r2 = bid & 63, b = bid >> 6;
    for (int k = t; k < C * 16; k += 256) L.WL[k] = W[k];
    if (t < 16) { L.bL[t] = bb[t]; L.SL[t] = S[t]; }
    if (t == 0) L.c0v = c0[0];
    const int j0 = off2[b * 65 + r2];
    const int n2 = off2[b * 65 + r2 + 1] - j0;
    for (int k = t; k < n2; k += 256) {
        int j = lst2[b * kE + j0 + k];
        int v = (j << 8) | d2[b * kE + j];
        if (C == 1 && rep2g[b * kE + j] == j) v |= 1 << 16;
        L.jd2[k] = v;
    }
    for (int k = t; k < kE; k += 256) {
        int i = lst1[b * kE + k];
        int v = (i << 8) | d1[b * kE + i];
        if (C == 1 && rep1g[b * kE + i] == i) v |= 1 << 16;
        L.il[k] = v;
    }
    if constexpr (C == 1) {
        for (int k = t; k < kE + 1; k += 256) {
            L.co1L[k] = coff1[b * 193 + k];
            L.co2L[k] = coff2[b * 193 + k];
        }
        for (int k = t; k < kE; k += 256) {
            L.cl1L[k] = (short)clst1[b * kE + k];
            L.cl2L[k] = (short)clst2[b * kE + k];
        }
    }
    if constexpr (C == 17) {
        sink64_local(b, t, L.mat, L.fL, L.gL, vprev);  // includes syncthreads
    } else {
        __syncthreads();
    }

    const int r1 = t >> 2, lane = t & 3;
    const int i0 = off1[b * 65 + r1], i1 = off1[b * 65 + r1 + 1];
    const float* Keb = Ke + (size_t)b * kE * kE;
    const float* KpB = Kp + (size_t)b * kNN;
    int degLocal = 0;

    if constexpr (C == 1) {
        // gather (k outer, m inner: identical FP order to verified version)
        float acc = 0.f;
        for (int k = 0; k < n2; ++k) {
            int pk = L.jd2[k], j = (pk >> 8) & 255, dd2 = pk & 255;
            for (int m = i0 + lane; m < i1; m += 4) {
                int pi = L.il[m], i = (pi >> 8) & 255, dd1 = pi & 255;
                if (dd2 == r2 && dd1 == r1) continue;
                acc += Keb[(size_t)i * kE + j] * KpB[dd1 * 64 + dd2];
            }
        }
        acc += __shfl_xor(acc, 1);
        acc += __shfl_xor(acc, 2);
        if (lane == 0) L.msgT[r1][0] = acc;
        // inline degree for row r2*64+r1 (rep pairs only; int adds commute)
        for (int m = i0 + lane; m < i1; m += 4) {
            int pi = L.il[m];
            if (!(pi >> 16)) continue;
            int i = (pi >> 8) & 255, dd1 = pi & 255;
            for (int k = 0; k < n2; ++k) {
                int pk = L.jd2[k];
                if (!(pk >> 16)) continue;
                int j = (pk >> 8) & 255, dd2 = pk & 255;
                float sum = 0.f;
                for (int mm = L.co1L[i]; mm < L.co1L[i + 1]; ++mm) {
                    const float* kr = Keb + (size_t)L.cl1L[mm] * kE;
                    for (int nn = L.co2L[j]; nn < L.co2L[j + 1]; ++nn)
                        sum += kr[L.cl2L[nn]];
                }
                if ((r2 * 64 + r1) != (dd2 * 64 + dd1) && sum > 0.0f) ++degLocal;
            }
        }
        degLocal += __shfl_xor(degLocal, 1);
        degLocal += __shfl_xor(degLocal, 2);
    } else {
        const float* xb = x + (size_t)b * kNN * C;
        float acc[5];
#pragma unroll
        for (int cc = 0; cc < 5; ++cc) acc[cc] = 0.f;
        for (int k = 0; k < n2; ++k) {
            int pk = L.jd2[k], j = (pk >> 8) & 255, dd2 = pk & 255;
            const float* xrow = xb + (size_t)(dd2 * 64) * C;
            for (int m = i0; m < i1; ++m) {
                int pi = L.il[m], i = (pi >> 8) & 255, dd1 = pi & 255;
                if (dd2 == r2 && dd1 == r1) continue;
                float kv = Keb[(size_t)i * kE + j];
                const float* xc = xrow + dd1 * C;
#pragma unroll
                for (int cc = 0; cc < 4; ++cc)
                    acc[cc] += kv * xc[lane + cc * 4];
                if (lane == 0) acc[4] += kv * L.mat[dd1][dd2];   // ss from LDS
            }
        }
#pragma unroll
        for (int cc = 0; cc < 5; ++cc) {
            int c = lane + cc * 4;
            if (c < C) L.msgT[r1][c] = acc[cc];
        }
    }
    __syncthreads();

    const int row = r2 * 64 + r1;
    const int idx = b * kNN + row;
    const float kd = KpB[r1 * 64 + r2];
    int degv;
    if constexpr (C == 1) {
        degv = degLocal;
        if (lane == 0) __builtin_nontemporal_store(degLocal, &degcnt[idx]);
    } else {
        degv = degcnt[idx];
    }
    const float dg = fmaxf((float)(degv + (kd > 0.f ? 1 : 0)), 1.f);
    float m[C];
    if constexpr (C == 1) {
        m[0] = (L.msgT[r1][0] + kd * kd) / dg;
    } else {
        const float* xr = x + (size_t)idx * C;
#pragma unroll
        for (int c = 0; c < 16; ++c)
            m[c] = (L.msgT[r1][c] + kd * xr[c]) / dg;
        m[16] = (L.msgT[r1][16] + kd * L.mat[r1][r2]) / dg;   // own ss from LDS
    }
    float vpart = 0.f;
#pragma unroll
    for (int ff = 0; ff < 4; ++ff) {
        int f = lane * 4 + ff;
        float a = L.bL[f];
#pragma unroll
        for (int c = 0; c < C; ++c) a += m[c] * L.WL[c * 16 + f];
        float h = fmaxf(a, 0.f);
        __builtin_nontemporal_store(h, &xn[(size_t)idx * 17 + f]);
        vpart += h * L.SL[f];
    }
    vpart += __shfl_xor(vpart, 1);
    vpart += __shfl_xor(vpart, 2);
    if (lane == 0) __builtin_nontemporal_store(vpart + L.c0v, &vout[idx]);
}

// ---------------------------------------------------------------------------
// Persistent megakernel: 512 blocks x 256 threads, 5 grid barriers.
// ---------------------------------------------------------------------------
__global__ __launch_bounds__(256, 2) void mega(
    const float* __restrict__ x1, const float* __restrict__ x2,
    const float* __restrict__ e1, const float* __restrict__ e2,
    const float* __restrict__ Wp, const float* __restrict__ bp,
    const float* __restrict__ gamma, const float* __restrict__ beta,
    const float* __restrict__ W0, const float* __restrict__ b0,
    const float* __restrict__ S0, const float* __restrict__ c0,
    const float* __restrict__ W1, const float* __restrict__ b1,
    const float* __restrict__ S1, const float* __restrict__ c1,
    const float* __restrict__ W2, const float* __restrict__ b2,
    const float* __restrict__ S2, const float* __restrict__ c2,
    const float* __restrict__ Wc, const float* __restrict__ bc,
    const float* __restrict__ binv,
    const int* __restrict__ src1, const int* __restrict__ dst1,
    const int* __restrict__ src2, const int* __restrict__ dst2,
    float* __restrict__ hbuf, float* __restrict__ stats,
    float* __restrict__ Kp, float* __restrict__ Ke,
    float* __restrict__ vA, float* __restrict__ vB,
    float* __restrict__ xA, float* __restrict__ xB,
    int* __restrict__ degcnt,
    int* __restrict__ off1, int* __restrict__ off2,
    int* __restrict__ lst1, int* __restrict__ lst2,
    int* __restrict__ rep1g, int* __restrict__ rep2g,
    int* __restrict__ coff1, int* __restrict__ coff2,
    int* __restrict__ clst1, int* __restrict__ clst2,
    int* __restrict__ bars, float* __restrict__ out)
{
    const int bid = blockIdx.x;
    const int t = threadIdx.x;
    __shared__ SmemU u;

    // ====== phase 0: projection GEMM, full K, + bias + BN-stats ===========
    {
        const int rt = bid >> 2, ct = bid & 3;
        const int grow0 = rt * 32, col0 = ct * 64;
        const int seg = (rt < 16) ? 0 : (rt < 32 ? 1 : (rt < 80 ? 2 : 3));
        const float* src; int lrow0;
        if (rt < 16)      { src = x1; lrow0 = grow0; }
        else if (rt < 32) { src = x2; lrow0 = grow0 - 512; }
        else if (rt < 80) { src = e1; lrow0 = grow0 - 1024; }
        else              { src = e2; lrow0 = grow0 - 2560; }

        const int tx = t & 15, ty = t >> 4;
        const int arow = t >> 3, acol = (t & 7) * 2;
        const int wrow = t >> 4, wcol = (t & 15) * 4;
        if (t < 64) { u.g.colS[t] = 0.f; u.g.colS2[t] = 0.f; }

        const float* Abase = src + (size_t)(lrow0 + arow) * kDin + acol;
        const float* Wbase = Wp + (size_t)wrow * kDp + col0 + wcol;

        float2 a2 = *(const float2*)Abase;
        float4 w4 = *(const float4*)Wbase;
        float acc[2][4] = {};

        for (int c = 0; c < 64; ++c) {
            const int cur = c & 1;
            u.g.As[cur][acol + 0][arow] = a2.x;
            u.g.As[cur][acol + 1][arow] = a2.y;
            *(float4*)&u.g.Ws[cur][wrow][wcol] = w4;
            __syncthreads();
            if (c < 63) {
                a2 = *(const float2*)(Abase + (c + 1) * 16);
                w4 = *(const float4*)(Wbase + (size_t)(c + 1) * 16 * kDp);
            }
#pragma unroll
            for (int kk = 0; kk < 16; ++kk) {
                float2 av = *(const float2*)&u.g.As[cur][kk][ty * 2];
                float4 wv = *(const float4*)&u.g.Ws[cur][kk][tx * 4];
                acc[0][0] += av.x * wv.x; acc[0][1] += av.x * wv.y;
                acc[0][2] += av.x * wv.z; acc[0][3] += av.x * wv.w;
                acc[1][0] += av.y * wv.x; acc[1][1] += av.y * wv.y;
                acc[1][2] += av.y * wv.z; acc[1][3] += av.y * wv.w;
            }
        }
        const float4 bb4 = *(const float4*)&bp[col0 + tx * 4];
        float sC[4] = {0.f, 0.f, 0.f, 0.f}, qC[4] = {0.f, 0.f, 0.f, 0.f};
#pragma unroll
        for (int i = 0; i < 2; ++i) {
            const int row = grow0 + ty * 2 + i;
            vfloat4 v;
            v.x = acc[i][0] + bb4.x; v.y = acc[i][1] + bb4.y;
            v.z = acc[i][2] + bb4.z; v.w = acc[i][3] + bb4.w;
            __builtin_nontemporal_store(v, (vfloat4*)&hbuf[(size_t)row * kDp + col0 + tx * 4]);
            sC[0] += v.x; sC[1] += v.y; sC[2] += v.z; sC[3] += v.w;
            qC[0] += v.x * v.x; qC[1] += v.y * v.y;
            qC[2] += v.z * v.z; qC[3] += v.w * v.w;
        }
#pragma unroll
        for (int j = 0; j < 4; ++j) {
            atomicAdd(&u.g.colS[tx * 4 + j], sC[j]);
            atomicAdd(&u.g.colS2[tx * 4 + j], qC[j]);
        }
        __syncthreads();
        if (t < 64) {
            atomicAdd(&stats[seg * 512 + col0 + t], u.g.colS[t]);
            atomicAdd(&stats[seg * 512 + 256 + col0 + t], u.g.colS2[t]);
        }
    }
    gsync(bars, 0);

    // === phase 1: sim GEMMs w/ inline BN+ReLU+L2 (bid<320) || csr (>=504) ==
    if (bid < 320) {
        const int id = bid % 40, b = bid / 40;
        int mt, nt_, ldo, segX, segY, xrow0, yrow0; float* outp; float scale;
        if (id < 4) {
            mt = (id >> 1) * 32; nt_ = (id & 1) * 32; ldo = 64;
            xrow0 = b * 64; yrow0 = 512 + b * 64;
            segX = 0; segY = 1;
            outp = Kp + (size_t)b * 4096; scale = 1.0f;
        } else {
            int e = id - 4;
            mt = (e / 6) * 32; nt_ = (e % 6) * 32; ldo = 192;
            xrow0 = 1024 + b * 192; yrow0 = 2560 + b * 192;
            segX = 2; segY = 3;
            outp = Ke + (size_t)b * 36864; scale = 0.5f;
        }
        // BN params into LDS (bit-identical mu/istd computation)
        {
            const float n = (segX < 2) ? 512.f : 1536.f;
            float mu = stats[segX * 512 + t] / n;
            float var = stats[segX * 512 + 256 + t] / n - mu * mu;
            u.sim.muX[t] = mu; u.sim.isX[t] = rsqrtf(var + 1e-5f);
            mu = stats[segY * 512 + t] / n;
            var = stats[segY * 512 + 256 + t] / n - mu * mu;
            u.sim.muY[t] = mu; u.sim.isY[t] = rsqrtf(var + 1e-5f);
            u.sim.ga[t] = gamma[t]; u.sim.be[t] = beta[t];
        }
        __syncthreads();
        // pre-pass: per-row L2 scales of BN'd+ReLU'd values
        {
            const int ri = t >> 2, lane = t & 3;
            const bool isXr = ri < 32;
            const int grow = isXr ? (xrow0 + mt + ri) : (yrow0 + nt_ + (ri - 32));
            const float* mus = isXr ? u.sim.muX : u.sim.muY;
            const float* iss = isXr ? u.sim.isX : u.sim.isY;
            const float* hr = hbuf + (size_t)grow * kDp;
            float ss = 0.f;
            for (int c4 = 0; c4 < 16; ++c4) {
                int c = lane * 64 + c4 * 4;
                float4 v = *(const float4*)&hr[c];
                float p;
                p = fmaxf((v.x - mus[c+0]) * iss[c+0] * u.sim.ga[c+0] + u.sim.be[c+0], 0.f); ss += p * p;
                p = fmaxf((v.y - mus[c+1]) * iss[c+1] * u.sim.ga[c+1] + u.sim.be[c+1], 0.f); ss += p * p;
                p = fmaxf((v.z - mus[c+2]) * iss[c+2] * u.sim.ga[c+2] + u.sim.be[c+2], 0.f); ss += p * p;
                p = fmaxf((v.w - mus[c+3]) * iss[c+3] * u.sim.ga[c+3] + u.sim.be[c+3], 0.f); ss += p * p;
            }
            ss += __shfl_xor(ss, 1);
            ss += __shfl_xor(ss, 2);
            if (lane == 0) {
                float sc = 1.f / fmaxf(sqrtf(ss), 1e-12f);
                if (isXr) u.sim.scX[ri] = sc; else u.sim.scY[ri - 32] = sc;
            }
        }
        __syncthreads();
        const int row = t >> 3, kq = t & 7;
        const int ty = t >> 4, tx = t & 15;
        const float* Xp = hbuf + (size_t)(xrow0 + mt) * kDp;
        const float* Yp = hbuf + (size_t)(yrow0 + nt_) * kDp;
        float acc[2][2] = {};
        for (int k0 = 0; k0 < kDp; k0 += 32) {
            const int c = k0 + kq * 4;
            float4 xa = *(const float4*)(Xp + (size_t)row * kDp + c);
            float4 ya = *(const float4*)(Yp + (size_t)row * kDp + c);
            const float sx = u.sim.scX[row], sy = u.sim.scY[row];
            u.sim.Xs[kq*4+0][row] = fmaxf((xa.x - u.sim.muX[c+0]) * u.sim.isX[c+0] * u.sim.ga[c+0] + u.sim.be[c+0], 0.f) * sx;
            u.sim.Xs[kq*4+1][row] = fmaxf((xa.y - u.sim.muX[c+1]) * u.sim.isX[c+1] * u.sim.ga[c+1] + u.sim.be[c+1], 0.f) * sx;
            u.sim.Xs[kq*4+2][row] = fmaxf((xa.z - u.sim.muX[c+2]) * u.sim.isX[c+2] * u.sim.ga[c+2] + u.sim.be[c+2], 0.f) * sx;
            u.sim.Xs[kq*4+3][row] = fmaxf((xa.w - u.sim.muX[c+3]) * u.sim.isX[c+3] * u.sim.ga[c+3] + u.sim.be[c+3], 0.f) * sx;
            u.sim.Ys[kq*4+0][row] = fmaxf((ya.x - u.sim.muY[c+0]) * u.sim.isY[c+0] * u.sim.ga[c+0] + u.sim.be[c+0], 0.f) * sy;
            u.sim.Ys[kq*4+1][row] = fmaxf((ya.y - u.sim.muY[c+1]) * u.sim.isY[c+1] * u.sim.ga[c+1] + u.sim.be[c+1], 0.f) * sy;
            u.sim.Ys[kq*4+2][row] = fmaxf((ya.z - u.sim.muY[c+2]) * u.sim.isY[c+2] * u.sim.ga[c+2] + u.sim.be[c+2], 0.f) * sy;
            u.sim.Ys[kq*4+3][row] = fmaxf((ya.w - u.sim.muY[c+3]) * u.sim.isY[c+3] * u.sim.ga[c+3] + u.sim.be[c+3], 0.f) * sy;
            __syncthreads();
#pragma unroll
            for (int kk = 0; kk < 32; ++kk) {
                float2 xv = *(const float2*)&u.sim.Xs[kk][ty * 2];
                float2 yv = *(const float2*)&u.sim.Ys[kk][tx * 2];
                acc[0][0] += xv.x * yv.x; acc[0][1] += xv.x * yv.y;
                acc[1][0] += xv.y * yv.x; acc[1][1] += xv.y * yv.y;
            }
            __syncthreads();
        }
#pragma unroll
        for (int i = 0; i < 2; ++i)
#pragma unroll
            for (int j = 0; j < 2; ++j)
                __builtin_nontemporal_store(scale * acc[i][j],
                    &outp[(size_t)(mt + ty * 2 + i) * ldo + nt_ + tx * 2 + j]);
    } else if (bid >= 504) {
        const int b = bid - 504;
        auto& C = u.csr;
        for (int i = t; i < 4096; i += 256) {
            C.km1[i] = 0x7fffffff; C.km2[i] = 0x7fffffff;
        }
        if (t < 64) { C.cnt1[t] = 0; C.cnt2[t] = 0; }
        for (int i = t; i < kE; i += 256) { C.ccnt1[i] = 0; C.ccnt2[i] = 0; }
        __syncthreads();
        if (t < kE) {
            int v1 = src1[b * kE + t], v2 = src2[b * kE + t];
            C.es1[t] = (short)v1; C.es2[t] = (short)v2;
            atomicAdd(&C.cnt1[v1], 1);
            atomicAdd(&C.cnt2[v2], 1);
            atomicMin(&C.km1[v1 * 64 + dst1[b * kE + t]], t);
            atomicMin(&C.km2[v2 * 64 + dst2[b * kE + t]], t);
        }
        __syncthreads();
        if (t < kE) {
            int r1 = C.km1[C.es1[t] * 64 + dst1[b * kE + t]];
            int r2 = C.km2[C.es2[t] * 64 + dst2[b * kE + t]];
            C.rp1[t] = (short)r1; C.rp2[t] = (short)r2;
            rep1g[b * kE + t] = r1; rep2g[b * kE + t] = r2;
            atomicAdd(&C.ccnt1[r1], 1);
            atomicAdd(&C.ccnt2[r2], 1);
        }
        __syncthreads();
        if (t == 0) {
            int a = 0, c = 0;
            for (int v = 0; v < 64; ++v) { C.pos1[v] = a; a += C.cnt1[v]; C.pos2[v] = c; c += C.cnt2[v]; }
            a = 0; c = 0;
            for (int v = 0; v < kE; ++v) { C.cpos1[v] = a; a += C.ccnt1[v]; C.cpos2[v] = c; c += C.ccnt2[v]; }
        }
        __syncthreads();
        if (t < 64) { off1[b * 65 + t] = C.pos1[t]; off2[b * 65 + t] = C.pos2[t]; }
        if (t == 0) { off1[b * 65 + 64] = kE; off2[b * 65 + 64] = kE; }
        if (t < kE) { coff1[b * 193 + t] = C.cpos1[t]; coff2[b * 193 + t] = C.cpos2[t]; }
        if (t == 0) { coff1[b * 193 + kE] = kE; coff2[b * 193 + kE] = kE; }
        __syncthreads();
        if (t < kE) {
            int p = atomicAdd(&C.pos1[C.es1[t]], 1); lst1[b * kE + p] = t;
            int q = atomicAdd(&C.pos2[C.es2[t]], 1); lst2[b * kE + q] = t;
            int cp = atomicAdd(&C.cpos1[C.rp1[t]], 1); clst1[b * kE + cp] = t;
            int cq = atomicAdd(&C.cpos2[C.rp2[t]], 1); clst2[b * kE + cq] = t;
        }
    }
    gsync(bars, 1);

    // ============ GNN layers (deg inline in layer0; ss in-LDS) =============
    layer_phase<1>(bid, t, u.ly, off1, lst1, off2, lst2, dst1, dst2,
                   rep1g, rep2g, coff1, coff2, clst1, clst2,
                   Ke, nullptr, Kp, degcnt, W0, b0, S0, c0, nullptr, xA, vA);
    gsync(bars, 2);
    layer_phase<17>(bid, t, u.ly, off1, lst1, off2, lst2, dst1, dst2,
                    rep1g, rep2g, coff1, coff2, clst1, clst2,
                    Ke, xA, Kp, degcnt, W1, b1, S1, c1, vA, xB, vB);
    gsync(bars, 3);
    layer_phase<17>(bid, t, u.ly, off1, lst1, off2, lst2, dst1, dst2,
                    rep1g, rep2g, coff1, coff2, clst1, clst2,
                    Ke, xB, Kp, degcnt, W2, b2, S2, c2, vB, xA, vA);
    gsync(bars, 4);

    // ====== final: 8 blocks only — sink64 + sink65 + max + normalize =======
    if ((bid & 63) == 0) {
        const int b = bid >> 6;
        auto& S = u.sk;
        if (t < 17) S.WcL[t] = Wc[t];
        if (t == 17) S.bcv = bc[0];
        if (t == 18) S.binvv = binv[0];
        sink64_local(b, t, S.mat, S.fL, S.gL, vA);   // ss in mat[0..63][0..63]

        for (int idx = t; idx < 65 * 65; idx += 256) {
            int q = idx / 65, p = idx - q * 65;
            float v;
            if (p < 64 && q < 64) {
                const float* xr = xA + (size_t)(b * kNN + q * 64 + p) * 17;
                v = S.bcv;
#pragma unroll
                for (int c = 0; c < 16; ++c) v += xr[c] * S.WcL[c];
                v += S.mat[p][q] * S.WcL[16];
            } else v = S.binvv;
            S.mat[p][q] = v;
        }
        if (t < 65) { S.fL[t] = 0.f; S.gL[t] = 0.f; }
        __syncthreads();

        const int r = t >> 2, s = t & 3;
        for (int it = 0; it < 10; ++it) {
            for (int rr = r; rr < 65; rr += 64) {
                float tv[17];
                float mx = -1e30f;
#pragma unroll
                for (int k = 0; k < 17; ++k) {
                    int q = s + 4 * k;
                    float v = (q < 65) ? S.mat[rr][q] + S.gL[q] : -1e30f;
                    tv[k] = v; mx = fmaxf(mx, v);
                }
                mx = fmaxf(mx, __shfl_xor(mx, 1));
                mx = fmaxf(mx, __shfl_xor(mx, 2));
                float sum = 0.f;
#pragma unroll
                for (int k = 0; k < 17; ++k) sum += __expf(tv[k] - mx);
                sum += __shfl_xor(sum, 1);
                sum += __shfl_xor(sum, 2);
                if (s == 0) S.fL[rr] = -(mx + __logf(sum));
            }
            __syncthreads();
            for (int rr = r; rr < 65; rr += 64) {
                float tv[17];
                float mx = -1e30f;
#pragma unroll
                for (int k = 0; k < 17; ++k) {
                    int p = s + 4 * k;
                    float v = (p < 65) ? S.mat[p][rr] + S.fL[p] : -1e30f;
                    tv[k] = v; mx = fmaxf(mx, v);
                }
                mx = fmaxf(mx, __shfl_xor(mx, 1));
                mx = fmaxf(mx, __shfl_xor(mx, 2));
                float sum = 0.f;
#pragma unroll
                for (int k = 0; k < 17; ++k) sum += __expf(tv[k] - mx);
                sum += __shfl_xor(sum, 1);
                sum += __shfl_xor(sum, 2);
                if (s == 0) S.gL[rr] = -(mx + __logf(sum));
            }
            __syncthreads();
        }

        float ev[16];
        float lmax = 0.f;
        {
            const float fr = S.fL[r];
#pragma unroll
            for (int k = 0; k < 16; ++k) {
                int q = s + 4 * k;
                ev[k] = __expf(S.mat[r][q] + fr + S.gL[q]);
                lmax = fmaxf(lmax, ev[k]);
            }
        }
#pragma unroll
        for (int o = 32; o >= 1; o >>= 1) lmax = fmaxf(lmax, __shfl_xor(lmax, o));
        if ((t & 63) == 0) S.wred[t >> 6] = lmax;
        __syncthreads();
        int* mcnt = bars + 3584;
        int* gmax = bars + 3600;
        if (t == 0) {
            float mb = fmaxf(fmaxf(S.wred[0], S.wred[1]), fmaxf(S.wred[2], S.wred[3]));
            atomicMax(gmax, __float_as_int(mb));   // all values > 0
            __builtin_amdgcn_fence(__ATOMIC_RELEASE, "agent");
            __hip_atomic_fetch_add(mcnt, 1, __ATOMIC_RELAXED, __HIP_MEMORY_SCOPE_AGENT);
            while (__hip_atomic_load(mcnt, __ATOMIC_RELAXED, __HIP_MEMORY_SCOPE_AGENT) < 8)
                __builtin_amdgcn_s_sleep(2);
            __builtin_amdgcn_fence(__ATOMIC_ACQUIRE, "agent");
        }
        __syncthreads();
        const float inv = 1.f / __int_as_float(
            __hip_atomic_load(gmax, __ATOMIC_RELAXED, __HIP_MEMORY_SCOPE_AGENT));
#pragma unroll
        for (int k = 0; k < 16; ++k) {
            int q = s + 4 * k;
            out[((size_t)b * kN + r) * kN + q] = ev[k] * inv;
        }
    }
}

// ---------------------------------------------------------------------------
extern "C" void kernel_launch(void* const* d_in, const int* in_sizes, int n_in,
                              void* d_out, int out_size, void* d_ws, size_t ws_size,
                              hipStream_t stream)
{
    (void)in_sizes; (void)n_in; (void)out_size; (void)ws_size;

    const float* x1    = (const float*)d_in[0];
    const float* x2    = (const float*)d_in[1];
    const float* e1    = (const float*)d_in[2];
    const float* e2    = (const float*)d_in[3];
    const float* Wp    = (const float*)d_in[4];
    const float* bp    = (const float*)d_in[5];
    const float* gamma = (const float*)d_in[6];
    const float* beta  = (const float*)d_in[7];
    const float* W0 = (const float*)d_in[8];
    const float* b0 = (const float*)d_in[9];
    const float* S0 = (const float*)d_in[10];
    const float* c0 = (const float*)d_in[11];
    const float* W1 = (const float*)d_in[12];
    const float* b1 = (const float*)d_in[13];
    const float* S1 = (const float*)d_in[14];
    const float* c1 = (const float*)d_in[15];
    const float* W2 = (const float*)d_in[16];
    const float* b2 = (const float*)d_in[17];
    const float* S2 = (const float*)d_in[18];
    const float* c2 = (const float*)d_in[19];
    const float* Wc = (const float*)d_in[20];
    const float* bc = (const float*)d_in[21];
    const float* binv = (const float*)d_in[22];
    const int* src1 = (const int*)d_in[23];
    const int* dst1 = (const int*)d_in[24];
    const int* src2 = (const int*)d_in[25];
    const int* dst2 = (const int*)d_in[26];

    float* out = (float*)d_out;
    float* wsf = (float*)d_ws;

    float* hbuf  = wsf;                    // 1,048,576
    float* Kp    = hbuf + 1048576;         // 32,768
    float* Ke    = Kp + 32768;             // 294,912
    float* vA    = Ke + 294912;            // 32,768
    float* vB    = vA + 32768;             // 32,768
    float* xA    = vB + 32768;             // 557,056
    float* xB    = xA + 557056;            // 557,056
    int*   degcnt = (int*)(xB + 557056);   // 32,768
    int*   off1 = degcnt + 32768;          // 520
    int*   off2 = off1 + 520;              // 520
    int*   lst1 = off2 + 520;              // 1,536
    int*   lst2 = lst1 + 1536;             // 1,536
    int*   rep1g = lst2 + 1536;            // 1,536
    int*   rep2g = rep1g + 1536;           // 1,536
    int*   coff1 = rep2g + 1536;           // 1,544
    int*   coff2 = coff1 + 1544;           // 1,544
    int*   clst1 = coff2 + 1544;           // 1,536
    int*   clst2 = clst1 + 1536;           // 1,536
    float* stats = (float*)(clst2 + 1536); // 2,048   (zeroed by memset)
    int*   bars  = (int*)(stats + 2048);   // 4,096   (zeroed by memset)

    // one memset zeroes stats + all barrier slots + minibar + gmax
    (void)hipMemsetAsync(stats, 0, (2048 + 4096) * sizeof(int), stream);
    mega<<<dim3(GRID), dim3(256), 0, stream>>>(
        x1, x2, e1, e2, Wp, bp, gamma, beta,
        W0, b0, S0, c0, W1, b1, S1, c1, W2, b2, S2, c2,
        Wc, bc, binv, src1, dst1, src2, dst2,
        hbuf, stats, Kp, Ke, vA, vB, xA, xB,
        degcnt, off1, off2, lst1, lst2, rep1g, rep2g,
        coff1, coff2, clst1, clst2, bars, out);
}

// Round 6
// 388.308 us; speedup vs baseline: 4.6683x; 1.0642x over previous
//
#include <hip/hip_runtime.h>

constexpr int kB   = 8;
constexpr int kN   = 64;
constexpr int kE   = 192;
constexpr int kDin = 1024;
constexpr int kDp  = 256;
constexpr int kNN  = 4096;
constexpr float kTauInv = 20.0f;

typedef float vfloat4 __attribute__((ext_vector_type(4)));

// ---------------------------------------------------------------------------
// Device-coherent accessors: sc0/sc1 ops live at the coherence point.
// Data passed between K3 phases uses ONLY these -> barriers need NO fences
// (R3/R5 evidence: barrier cost = buffer_wbl2/buffer_inv walks, ~35us each).
// ---------------------------------------------------------------------------
__device__ __forceinline__ float cload(const float* p) {
    return __hip_atomic_load((const float*)p, __ATOMIC_RELAXED, __HIP_MEMORY_SCOPE_AGENT);
}
__device__ __forceinline__ void cstore(float* p, float v) {
    __hip_atomic_store(p, v, __ATOMIC_RELAXED, __HIP_MEMORY_SCOPE_AGENT);
}
__device__ __forceinline__ int cloadi(const int* p) {
    return __hip_atomic_load((const int*)p, __ATOMIC_RELAXED, __HIP_MEMORY_SCOPE_AGENT);
}
__device__ __forceinline__ void cstorei(int* p, int v) {
    __hip_atomic_store(p, v, __ATOMIC_RELAXED, __HIP_MEMORY_SCOPE_AGENT);
}

// ---------------------------------------------------------------------------
// Fence-free two-level grid barrier (K3 only; all cross-phase data coherent).
// vmcnt(0) drains this block's coherent stores before arrival; the arrival
// RMW's returned value forces its own completion; flags relaxed.
// ---------------------------------------------------------------------------
__device__ __forceinline__ void gsync_nf(int* bars, int slot)
{
    __syncthreads();
    if (threadIdx.x == 0) {
        int* base = bars + slot * 512;
        const int g = (int)blockIdx.x >> 6;
        asm volatile("s_waitcnt vmcnt(0)" ::: "memory");
        int prev = __hip_atomic_fetch_add(&base[g * 16], 1, __ATOMIC_RELAXED,
                                          __HIP_MEMORY_SCOPE_AGENT);
        if (prev == 63) {
            int r = __hip_atomic_fetch_add(&base[128], 1, __ATOMIC_RELAXED,
                                           __HIP_MEMORY_SCOPE_AGENT);
            if (r == 7) {
#pragma unroll
                for (int gg = 0; gg < 8; ++gg)
                    __hip_atomic_store(&base[256 + gg * 16], 1, __ATOMIC_RELAXED,
                                       __HIP_MEMORY_SCOPE_AGENT);
            }
        }
        while (__hip_atomic_load(&base[256 + g * 16], __ATOMIC_RELAXED,
                                 __HIP_MEMORY_SCOPE_AGENT) == 0)
            __builtin_amdgcn_s_sleep(8);
    }
    __syncthreads();
}

// ===========================================================================
// K1: projection GEMM (full K) + bias + BN-stats.  512 blocks, no barriers.
// ===========================================================================
__global__ __launch_bounds__(256) void k_proj(
    const float* __restrict__ x1, const float* __restrict__ x2,
    const float* __restrict__ e1, const float* __restrict__ e2,
    const float* __restrict__ Wp, const float* __restrict__ bp,
    float* __restrict__ hbuf, float* __restrict__ stats)
{
    __shared__ float As[2][16][36];
    __shared__ float Ws[2][16][68];
    __shared__ float colS[64], colS2[64];

    const int bid = blockIdx.x, t = threadIdx.x;
    const int rt = bid >> 2, ct = bid & 3;
    const int grow0 = rt * 32, col0 = ct * 64;
    const int seg = (rt < 16) ? 0 : (rt < 32 ? 1 : (rt < 80 ? 2 : 3));
    const float* src; int lrow0;
    if (rt < 16)      { src = x1; lrow0 = grow0; }
    else if (rt < 32) { src = x2; lrow0 = grow0 - 512; }
    else if (rt < 80) { src = e1; lrow0 = grow0 - 1024; }
    else              { src = e2; lrow0 = grow0 - 2560; }

    const int tx = t & 15, ty = t >> 4;
    const int arow = t >> 3, acol = (t & 7) * 2;
    const int wrow = t >> 4, wcol = (t & 15) * 4;
    if (t < 64) { colS[t] = 0.f; colS2[t] = 0.f; }

    const float* Abase = src + (size_t)(lrow0 + arow) * kDin + acol;
    const float* Wbase = Wp + (size_t)wrow * kDp + col0 + wcol;

    float2 a2 = *(const float2*)Abase;
    float4 w4 = *(const float4*)Wbase;
    float acc[2][4] = {};

    for (int c = 0; c < 64; ++c) {
        const int cur = c & 1;
        As[cur][acol + 0][arow] = a2.x;
        As[cur][acol + 1][arow] = a2.y;
        *(float4*)&Ws[cur][wrow][wcol] = w4;
        __syncthreads();
        if (c < 63) {
            a2 = *(const float2*)(Abase + (c + 1) * 16);
            w4 = *(const float4*)(Wbase + (size_t)(c + 1) * 16 * kDp);
        }
#pragma unroll
        for (int kk = 0; kk < 16; ++kk) {
            float2 av = *(const float2*)&As[cur][kk][ty * 2];
            float4 wv = *(const float4*)&Ws[cur][kk][tx * 4];
            acc[0][0] += av.x * wv.x; acc[0][1] += av.x * wv.y;
            acc[0][2] += av.x * wv.z; acc[0][3] += av.x * wv.w;
            acc[1][0] += av.y * wv.x; acc[1][1] += av.y * wv.y;
            acc[1][2] += av.y * wv.z; acc[1][3] += av.y * wv.w;
        }
    }
    const float4 bb4 = *(const float4*)&bp[col0 + tx * 4];
    float sC[4] = {0.f, 0.f, 0.f, 0.f}, qC[4] = {0.f, 0.f, 0.f, 0.f};
#pragma unroll
    for (int i = 0; i < 2; ++i) {
        const int row = grow0 + ty * 2 + i;
        vfloat4 v;
        v.x = acc[i][0] + bb4.x; v.y = acc[i][1] + bb4.y;
        v.z = acc[i][2] + bb4.z; v.w = acc[i][3] + bb4.w;
        __builtin_nontemporal_store(v, (vfloat4*)&hbuf[(size_t)row * kDp + col0 + tx * 4]);
        sC[0] += v.x; sC[1] += v.y; sC[2] += v.z; sC[3] += v.w;
        qC[0] += v.x * v.x; qC[1] += v.y * v.y;
        qC[2] += v.z * v.z; qC[3] += v.w * v.w;
    }
#pragma unroll
    for (int j = 0; j < 4; ++j) {
        atomicAdd(&colS[tx * 4 + j], sC[j]);
        atomicAdd(&colS2[tx * 4 + j], qC[j]);
    }
    __syncthreads();
    if (t < 64) {
        atomicAdd(&stats[seg * 512 + col0 + t], colS[t]);
        atomicAdd(&stats[seg * 512 + 256 + col0 + t], colS2[t]);
    }
}

// ===========================================================================
// K2: similarity GEMMs with inline BN+ReLU+L2 (blocks 0..319)  ||  CSR build
// (blocks 320..327).  No internal barriers.
// ===========================================================================
struct SmemSim  {
    float Xs[32][36]; float Ys[32][36];
    float muX[256], isX[256], muY[256], isY[256];
    float ga[256], be[256];
    float scX[32], scY[32];
};
struct SmemCsr  {
    int km1[4096], km2[4096];
    short es1[kE], es2[kE], rp1[kE], rp2[kE];
    int cnt1[64], cnt2[64], pos1[64], pos2[64];
    int ccnt1[kE], ccnt2[kE], cpos1[kE], cpos2[kE];
};
union __align__(16) SmemK2 { SmemSim sim; SmemCsr csr; };

__global__ __launch_bounds__(256) void k_simcsr(
    const float* __restrict__ hbuf, const float* __restrict__ stats,
    const float* __restrict__ gamma, const float* __restrict__ beta,
    const int* __restrict__ src1, const int* __restrict__ dst1,
    const int* __restrict__ src2, const int* __restrict__ dst2,
    float* __restrict__ Kp, float* __restrict__ Ke,
    int* __restrict__ off1, int* __restrict__ off2,
    int* __restrict__ lst1, int* __restrict__ lst2,
    int* __restrict__ rep1g, int* __restrict__ rep2g,
    int* __restrict__ coff1, int* __restrict__ coff2,
    int* __restrict__ clst1, int* __restrict__ clst2)
{
    const int bid = blockIdx.x, t = threadIdx.x;
    __shared__ SmemK2 u;

    if (bid < 320) {
        const int id = bid % 40, b = bid / 40;
        int mt, nt_, ldo, segX, segY, xrow0, yrow0; float* outp; float scale;
        if (id < 4) {
            mt = (id >> 1) * 32; nt_ = (id & 1) * 32; ldo = 64;
            xrow0 = b * 64; yrow0 = 512 + b * 64;
            segX = 0; segY = 1;
            outp = Kp + (size_t)b * 4096; scale = 1.0f;
        } else {
            int e = id - 4;
            mt = (e / 6) * 32; nt_ = (e % 6) * 32; ldo = 192;
            xrow0 = 1024 + b * 192; yrow0 = 2560 + b * 192;
            segX = 2; segY = 3;
            outp = Ke + (size_t)b * 36864; scale = 0.5f;
        }
        {
            const float n = (segX < 2) ? 512.f : 1536.f;
            float mu = stats[segX * 512 + t] / n;
            float var = stats[segX * 512 + 256 + t] / n - mu * mu;
            u.sim.muX[t] = mu; u.sim.isX[t] = rsqrtf(var + 1e-5f);
            mu = stats[segY * 512 + t] / n;
            var = stats[segY * 512 + 256 + t] / n - mu * mu;
            u.sim.muY[t] = mu; u.sim.isY[t] = rsqrtf(var + 1e-5f);
            u.sim.ga[t] = gamma[t]; u.sim.be[t] = beta[t];
        }
        __syncthreads();
        {
            const int ri = t >> 2, lane = t & 3;
            const bool isXr = ri < 32;
            const int grow = isXr ? (xrow0 + mt + ri) : (yrow0 + nt_ + (ri - 32));
            const float* mus = isXr ? u.sim.muX : u.sim.muY;
            const float* iss = isXr ? u.sim.isX : u.sim.isY;
            const float* hr = hbuf + (size_t)grow * kDp;
            float ss = 0.f;
            for (int c4 = 0; c4 < 16; ++c4) {
                int c = lane * 64 + c4 * 4;
                float4 v = *(const float4*)&hr[c];
                float p;
                p = fmaxf((v.x - mus[c+0]) * iss[c+0] * u.sim.ga[c+0] + u.sim.be[c+0], 0.f); ss += p * p;
                p = fmaxf((v.y - mus[c+1]) * iss[c+1] * u.sim.ga[c+1] + u.sim.be[c+1], 0.f); ss += p * p;
                p = fmaxf((v.z - mus[c+2]) * iss[c+2] * u.sim.ga[c+2] + u.sim.be[c+2], 0.f); ss += p * p;
                p = fmaxf((v.w - mus[c+3]) * iss[c+3] * u.sim.ga[c+3] + u.sim.be[c+3], 0.f); ss += p * p;
            }
            ss += __shfl_xor(ss, 1);
            ss += __shfl_xor(ss, 2);
            if (lane == 0) {
                float sc = 1.f / fmaxf(sqrtf(ss), 1e-12f);
                if (isXr) u.sim.scX[ri] = sc; else u.sim.scY[ri - 32] = sc;
            }
        }
        __syncthreads();
        const int row = t >> 3, kq = t & 7;
        const int ty = t >> 4, tx = t & 15;
        const float* Xp = hbuf + (size_t)(xrow0 + mt) * kDp;
        const float* Yp = hbuf + (size_t)(yrow0 + nt_) * kDp;
        float acc[2][2] = {};
        for (int k0 = 0; k0 < kDp; k0 += 32) {
            const int c = k0 + kq * 4;
            float4 xa = *(const float4*)(Xp + (size_t)row * kDp + c);
            float4 ya = *(const float4*)(Yp + (size_t)row * kDp + c);
            const float sx = u.sim.scX[row], sy = u.sim.scY[row];
            u.sim.Xs[kq*4+0][row] = fmaxf((xa.x - u.sim.muX[c+0]) * u.sim.isX[c+0] * u.sim.ga[c+0] + u.sim.be[c+0], 0.f) * sx;
            u.sim.Xs[kq*4+1][row] = fmaxf((xa.y - u.sim.muX[c+1]) * u.sim.isX[c+1] * u.sim.ga[c+1] + u.sim.be[c+1], 0.f) * sx;
            u.sim.Xs[kq*4+2][row] = fmaxf((xa.z - u.sim.muX[c+2]) * u.sim.isX[c+2] * u.sim.ga[c+2] + u.sim.be[c+2], 0.f) * sx;
            u.sim.Xs[kq*4+3][row] = fmaxf((xa.w - u.sim.muX[c+3]) * u.sim.isX[c+3] * u.sim.ga[c+3] + u.sim.be[c+3], 0.f) * sx;
            u.sim.Ys[kq*4+0][row] = fmaxf((ya.x - u.sim.muY[c+0]) * u.sim.isY[c+0] * u.sim.ga[c+0] + u.sim.be[c+0], 0.f) * sy;
            u.sim.Ys[kq*4+1][row] = fmaxf((ya.y - u.sim.muY[c+1]) * u.sim.isY[c+1] * u.sim.ga[c+1] + u.sim.be[c+1], 0.f) * sy;
            u.sim.Ys[kq*4+2][row] = fmaxf((ya.z - u.sim.muY[c+2]) * u.sim.isY[c+2] * u.sim.ga[c+2] + u.sim.be[c+2], 0.f) * sy;
            u.sim.Ys[kq*4+3][row] = fmaxf((ya.w - u.sim.muY[c+3]) * u.sim.isY[c+3] * u.sim.ga[c+3] + u.sim.be[c+3], 0.f) * sy;
            __syncthreads();
#pragma unroll
            for (int kk = 0; kk < 32; ++kk) {
                float2 xv = *(const float2*)&u.sim.Xs[kk][ty * 2];
                float2 yv = *(const float2*)&u.sim.Ys[kk][tx * 2];
                acc[0][0] += xv.x * yv.x; acc[0][1] += xv.x * yv.y;
                acc[1][0] += xv.y * yv.x; acc[1][1] += xv.y * yv.y;
            }
            __syncthreads();
        }
#pragma unroll
        for (int i = 0; i < 2; ++i)
#pragma unroll
            for (int j = 0; j < 2; ++j)
                __builtin_nontemporal_store(scale * acc[i][j],
                    &outp[(size_t)(mt + ty * 2 + i) * ldo + nt_ + tx * 2 + j]);
    } else {
        const int b = bid - 320;
        auto& C = u.csr;
        for (int i = t; i < 4096; i += 256) {
            C.km1[i] = 0x7fffffff; C.km2[i] = 0x7fffffff;
        }
        if (t < 64) { C.cnt1[t] = 0; C.cnt2[t] = 0; }
        for (int i = t; i < kE; i += 256) { C.ccnt1[i] = 0; C.ccnt2[i] = 0; }
        __syncthreads();
        if (t < kE) {
            int v1 = src1[b * kE + t], v2 = src2[b * kE + t];
            C.es1[t] = (short)v1; C.es2[t] = (short)v2;
            atomicAdd(&C.cnt1[v1], 1);
            atomicAdd(&C.cnt2[v2], 1);
            atomicMin(&C.km1[v1 * 64 + dst1[b * kE + t]], t);
            atomicMin(&C.km2[v2 * 64 + dst2[b * kE + t]], t);
        }
        __syncthreads();
        if (t < kE) {
            int r1 = C.km1[C.es1[t] * 64 + dst1[b * kE + t]];
            int r2 = C.km2[C.es2[t] * 64 + dst2[b * kE + t]];
            C.rp1[t] = (short)r1; C.rp2[t] = (short)r2;
            rep1g[b * kE + t] = r1; rep2g[b * kE + t] = r2;
            atomicAdd(&C.ccnt1[r1], 1);
            atomicAdd(&C.ccnt2[r2], 1);
        }
        __syncthreads();
        if (t == 0) {
            int a = 0, c = 0;
            for (int v = 0; v < 64; ++v) { C.pos1[v] = a; a += C.cnt1[v]; C.pos2[v] = c; c += C.cnt2[v]; }
            a = 0; c = 0;
            for (int v = 0; v < kE; ++v) { C.cpos1[v] = a; a += C.ccnt1[v]; C.cpos2[v] = c; c += C.ccnt2[v]; }
        }
        __syncthreads();
        if (t < 64) { off1[b * 65 + t] = C.pos1[t]; off2[b * 65 + t] = C.pos2[t]; }
        if (t == 0) { off1[b * 65 + 64] = kE; off2[b * 65 + 64] = kE; }
        if (t < kE) { coff1[b * 193 + t] = C.cpos1[t]; coff2[b * 193 + t] = C.cpos2[t]; }
        if (t == 0) { coff1[b * 193 + kE] = kE; coff2[b * 193 + kE] = kE; }
        __syncthreads();
        if (t < kE) {
            int p = atomicAdd(&C.pos1[C.es1[t]], 1); lst1[b * kE + p] = t;
            int q = atomicAdd(&C.pos2[C.es2[t]], 1); lst2[b * kE + q] = t;
            int cp = atomicAdd(&C.cpos1[C.rp1[t]], 1); clst1[b * kE + cp] = t;
            int cq = atomicAdd(&C.cpos2[C.rp2[t]], 1); clst2[b * kE + cq] = t;
        }
    }
}

// ===========================================================================
// K3: persistent 512 blocks — 3 GNN layers + final sinkhorns.
// Fence-free barriers; all cross-phase data via coherent accessors.
// Ke/Kp/CSR lists are RO (from K2) -> normal cached loads, stay L2-warm.
// ===========================================================================
struct SmemLayer {
    float mat[64][68]; float fL[64], gL[64];
    float WL[17 * 16]; float bL[16], SL[16]; float c0v;
    int jd2[kE]; int il[kE]; float msgT[64][18];
    int co1L[kE + 1], co2L[kE + 1];
    short cl1L[kE], cl2L[kE];
};
struct SmemSink {
    float mat[65][68]; float fL[65], gL[65];
    float WcL[17]; float bcv, binvv; float wred[4];
};
union __align__(16) SmemK3 { SmemLayer ly; SmemSink sk; };

// Local (redundant, per-block) 64x64 sinkhorn from vbuf (coherent) into LDS.
__device__ void sink64_local(int b, int t, float (*mat)[68], float* fL, float* gL,
                             const float* __restrict__ vin)
{
    for (int idx = t; idx < kNN; idx += 256) {
        int q = idx >> 6, p = idx & 63;
        mat[p][q] = cload(&vin[b * kNN + idx]) * kTauInv;
    }
    if (t < 64) { fL[t] = 0.f; gL[t] = 0.f; }
    __syncthreads();
    const int r = t >> 2, s = t & 3;
    float tv[16];
    for (int it = 0; it < 10; ++it) {
        float mx = -1e30f;
#pragma unroll
        for (int k = 0; k < 16; ++k) {
            float v = mat[r][s + 4 * k] + gL[s + 4 * k];
            tv[k] = v; mx = fmaxf(mx, v);
        }
        mx = fmaxf(mx, __shfl_xor(mx, 1));
        mx = fmaxf(mx, __shfl_xor(mx, 2));
        float sum = 0.f;
#pragma unroll
        for (int k = 0; k < 16; ++k) sum += __expf(tv[k] - mx);
        sum += __shfl_xor(sum, 1);
        sum += __shfl_xor(sum, 2);
        if (s == 0) fL[r] = -(mx + __logf(sum));
        __syncthreads();
        mx = -1e30f;
#pragma unroll
        for (int k = 0; k < 16; ++k) {
            float v = mat[s + 4 * k][r] + fL[s + 4 * k];
            tv[k] = v; mx = fmaxf(mx, v);
        }
        mx = fmaxf(mx, __shfl_xor(mx, 1));
        mx = fmaxf(mx, __shfl_xor(mx, 2));
        sum = 0.f;
#pragma unroll
        for (int k = 0; k < 16; ++k) sum += __expf(tv[k] - mx);
        sum += __shfl_xor(sum, 1);
        sum += __shfl_xor(sum, 2);
        if (s == 0) gL[r] = -(mx + __logf(sum));
        __syncthreads();
    }
    const float fr = fL[r];
#pragma unroll
    for (int k = 0; k < 16; ++k) {
        int q = s + 4 * k;
        mat[r][q] = __expf(mat[r][q] + fr + gL[q]);
    }
    __syncthreads();
}

template <int C>
__device__ void layer_phase(int bid, int t, SmemLayer& L,
    const int* off1, const int* lst1, const int* off2, const int* lst2,
    const int* d1, const int* d2,
    const int* rep1g, const int* rep2g,
    const int* coff1, const int* coff2,
    const int* clst1, const int* clst2,
    const float* Ke, const float* x, const float* Kp, int* degcnt,
    const float* W, const float* bb, const float* S, const float* c0,
    const float* vprev, float* xn, float* vout)
{
    const int r2 = bid & 63, b = bid >> 6;
    for (int k = t; k < C * 16; k += 256) L.WL[k] = W[k];
    if (t < 16) { L.bL[t] = bb[t]; L.SL[t] = S[t]; }
    if (t == 0) L.c0v = c0[0];
    const int j0 = off2[b * 65 + r2];
    const int n2 = off2[b * 65 + r2 + 1] - j0;
    for (int k = t; k < n2; k += 256) {
        int j = lst2[b * kE + j0 + k];
        int v = (j << 8) | d2[b * kE + j];
        if (C == 1 && rep2g[b * kE + j] == j) v |= 1 << 16;
        L.jd2[k] = v;
    }
    for (int k = t; k < kE; k += 256) {
        int i = lst1[b * kE + k];
        int v = (i << 8) | d1[b * kE + i];
        if (C == 1 && rep1g[b * kE + i] == i) v |= 1 << 16;
        L.il[k] = v;
    }
    if constexpr (C == 1) {
        for (int k = t; k < kE + 1; k += 256) {
            L.co1L[k] = coff1[b * 193 + k];
            L.co2L[k] = coff2[b * 193 + k];
        }
        for (int k = t; k < kE; k += 256) {
            L.cl1L[k] = (short)clst1[b * kE + k];
            L.cl2L[k] = (short)clst2[b * kE + k];
        }
    }
    if constexpr (C == 17) {
        sink64_local(b, t, L.mat, L.fL, L.gL, vprev);  // includes syncthreads
    } else {
        __syncthreads();
    }

    const int r1 = t >> 2, lane = t & 3;
    const int i0 = off1[b * 65 + r1], i1 = off1[b * 65 + r1 + 1];
    const float* Keb = Ke + (size_t)b * kE * kE;
    const float* KpB = Kp + (size_t)b * kNN;
    int degLocal = 0;

    if constexpr (C == 1) {
        float acc = 0.f;
        for (int k = 0; k < n2; ++k) {
            int pk = L.jd2[k], j = (pk >> 8) & 255, dd2 = pk & 255;
            for (int m = i0 + lane; m < i1; m += 4) {
                int pi = L.il[m], i = (pi >> 8) & 255, dd1 = pi & 255;
                if (dd2 == r2 && dd1 == r1) continue;
                acc += Keb[(size_t)i * kE + j] * KpB[dd1 * 64 + dd2];
            }
        }
        acc += __shfl_xor(acc, 1);
        acc += __shfl_xor(acc, 2);
        if (lane == 0) L.msgT[r1][0] = acc;
        for (int m = i0 + lane; m < i1; m += 4) {
            int pi = L.il[m];
            if (!(pi >> 16)) continue;
            int i = (pi >> 8) & 255, dd1 = pi & 255;
            for (int k = 0; k < n2; ++k) {
                int pk = L.jd2[k];
                if (!(pk >> 16)) continue;
                int j = (pk >> 8) & 255, dd2 = pk & 255;
                float sum = 0.f;
                for (int mm = L.co1L[i]; mm < L.co1L[i + 1]; ++mm) {
                    const float* kr = Keb + (size_t)L.cl1L[mm] * kE;
                    for (int nn = L.co2L[j]; nn < L.co2L[j + 1]; ++nn)
                        sum += kr[L.cl2L[nn]];
                }
                if ((r2 * 64 + r1) != (dd2 * 64 + dd1) && sum > 0.0f) ++degLocal;
            }
        }
        degLocal += __shfl_xor(degLocal, 1);
        degLocal += __shfl_xor(degLocal, 2);
    } else {
        const float* xb = x + (size_t)b * kNN * C;
        float acc[5];
#pragma unroll
        for (int cc = 0; cc < 5; ++cc) acc[cc] = 0.f;
        for (int k = 0; k < n2; ++k) {
            int pk = L.jd2[k], j = (pk >> 8) & 255, dd2 = pk & 255;
            const float* xrow = xb + (size_t)(dd2 * 64) * C;
            for (int m = i0; m < i1; ++m) {
                int pi = L.il[m], i = (pi >> 8) & 255, dd1 = pi & 255;
                if (dd2 == r2 && dd1 == r1) continue;
                float kv = Keb[(size_t)i * kE + j];
                const float* xc = xrow + dd1 * C;
#pragma unroll
                for (int cc = 0; cc < 4; ++cc)
                    acc[cc] += kv * cload(&xc[lane + cc * 4]);
                if (lane == 0) acc[4] += kv * L.mat[dd1][dd2];   // ss from LDS
            }
        }
#pragma unroll
        for (int cc = 0; cc < 5; ++cc) {
            int c = lane + cc * 4;
            if (c < C) L.msgT[r1][c] = acc[cc];
        }
    }
    __syncthreads();

    const int row = r2 * 64 + r1;
    const int idx = b * kNN + row;
    const float kd = KpB[r1 * 64 + r2];
    int degv;
    if constexpr (C == 1) {
        degv = degLocal;
        if (lane == 0) cstorei(&degcnt[idx], degLocal);
    } else {
        degv = cloadi(&degcnt[idx]);
    }
    const float dg = fmaxf((float)(degv + (kd > 0.f ? 1 : 0)), 1.f);
    float m[C];
    if constexpr (C == 1) {
        m[0] = (L.msgT[r1][0] + kd * kd) / dg;
    } else {
        const float* xr = x + (size_t)idx * C;
#pragma unroll
        for (int c = 0; c < 16; ++c)
            m[c] = (L.msgT[r1][c] + kd * cload(&xr[c])) / dg;
        m[16] = (L.msgT[r1][16] + kd * L.mat[r1][r2]) / dg;   // own ss from LDS
    }
    float vpart = 0.f;
#pragma unroll
    for (int ff = 0; ff < 4; ++ff) {
        int f = lane * 4 + ff;
        float a = L.bL[f];
#pragma unroll
        for (int c = 0; c < C; ++c) a += m[c] * L.WL[c * 16 + f];
        float h = fmaxf(a, 0.f);
        cstore(&xn[(size_t)idx * 17 + f], h);
        vpart += h * L.SL[f];
    }
    vpart += __shfl_xor(vpart, 1);
    vpart += __shfl_xor(vpart, 2);
    if (lane == 0) cstore(&vout[idx], vpart + L.c0v);
}

__global__ __launch_bounds__(256, 2) void k_layers(
    const float* __restrict__ W0, const float* __restrict__ b0,
    const float* __restrict__ S0, const float* __restrict__ c0,
    const float* __restrict__ W1, const float* __restrict__ b1,
    const float* __restrict__ S1, const float* __restrict__ c1,
    const float* __restrict__ W2, const float* __restrict__ b2,
    const float* __restrict__ S2, const float* __restrict__ c2,
    const float* __restrict__ Wc, const float* __restrict__ bc,
    const float* __restrict__ binv,
    const int* __restrict__ dst1, const int* __restrict__ dst2,
    const float* __restrict__ Kp, const float* __restrict__ Ke,
    float* __restrict__ vA, float* __restrict__ vB,
    float* __restrict__ xA, float* __restrict__ xB,
    int* __restrict__ degcnt,
    const int* __restrict__ off1, const int* __restrict__ off2,
    const int* __restrict__ lst1, const int* __restrict__ lst2,
    const int* __restrict__ rep1g, const int* __restrict__ rep2g,
    const int* __restrict__ coff1, const int* __restrict__ coff2,
    const int* __restrict__ clst1, const int* __restrict__ clst2,
    int* __restrict__ bars, float* __restrict__ out)
{
    const int bid = blockIdx.x;
    const int t = threadIdx.x;
    __shared__ SmemK3 u;

    layer_phase<1>(bid, t, u.ly, off1, lst1, off2, lst2, dst1, dst2,
                   rep1g, rep2g, coff1, coff2, clst1, clst2,
                   Ke, nullptr, Kp, degcnt, W0, b0, S0, c0, nullptr, xA, vA);
    gsync_nf(bars, 0);
    layer_phase<17>(bid, t, u.ly, off1, lst1, off2, lst2, dst1, dst2,
                    rep1g, rep2g, coff1, coff2, clst1, clst2,
                    Ke, xA, Kp, degcnt, W1, b1, S1, c1, vA, xB, vB);
    gsync_nf(bars, 1);
    layer_phase<17>(bid, t, u.ly, off1, lst1, off2, lst2, dst1, dst2,
                    rep1g, rep2g, coff1, coff2, clst1, clst2,
                    Ke, xB, Kp, degcnt, W2, b2, S2, c2, vB, xA, vA);
    gsync_nf(bars, 2);

    // ====== final: 8 blocks only — sink64 + sink65 + max + normalize =======
    if ((bid & 63) == 0) {
        const int b = bid >> 6;
        auto& S = u.sk;
        if (t < 17) S.WcL[t] = Wc[t];
        if (t == 17) S.bcv = bc[0];
        if (t == 18) S.binvv = binv[0];
        sink64_local(b, t, S.mat, S.fL, S.gL, vA);   // ss in mat[0..63][0..63]

        for (int idx = t; idx < 65 * 65; idx += 256) {
            int q = idx / 65, p = idx - q * 65;
            float v;
            if (p < 64 && q < 64) {
                const float* xr = xA + (size_t)(b * kNN + q * 64 + p) * 17;
                v = S.bcv;
#pragma unroll
                for (int c = 0; c < 16; ++c) v += cload(&xr[c]) * S.WcL[c];
                v += S.mat[p][q] * S.WcL[16];
            } else v = S.binvv;
            S.mat[p][q] = v;
        }
        if (t < 65) { S.fL[t] = 0.f; S.gL[t] = 0.f; }
        __syncthreads();

        const int r = t >> 2, s = t & 3;
        for (int it = 0; it < 10; ++it) {
            for (int rr = r; rr < 65; rr += 64) {
                float tv[17];
                float mx = -1e30f;
#pragma unroll
                for (int k = 0; k < 17; ++k) {
                    int q = s + 4 * k;
                    float v = (q < 65) ? S.mat[rr][q] + S.gL[q] : -1e30f;
                    tv[k] = v; mx = fmaxf(mx, v);
                }
                mx = fmaxf(mx, __shfl_xor(mx, 1));
                mx = fmaxf(mx, __shfl_xor(mx, 2));
                float sum = 0.f;
#pragma unroll
                for (int k = 0; k < 17; ++k) sum += __expf(tv[k] - mx);
                sum += __shfl_xor(sum, 1);
                sum += __shfl_xor(sum, 2);
                if (s == 0) S.fL[rr] = -(mx + __logf(sum));
            }
            __syncthreads();
            for (int rr = r; rr < 65; rr += 64) {
                float tv[17];
                float mx = -1e30f;
#pragma unroll
                for (int k = 0; k < 17; ++k) {
                    int p = s + 4 * k;
                    float v = (p < 65) ? S.mat[p][rr] + S.fL[p] : -1e30f;
                    tv[k] = v; mx = fmaxf(mx, v);
                }
                mx = fmaxf(mx, __shfl_xor(mx, 1));
                mx = fmaxf(mx, __shfl_xor(mx, 2));
                float sum = 0.f;
#pragma unroll
                for (int k = 0; k < 17; ++k) sum += __expf(tv[k] - mx);
                sum += __shfl_xor(sum, 1);
                sum += __shfl_xor(sum, 2);
                if (s == 0) S.gL[rr] = -(mx + __logf(sum));
            }
            __syncthreads();
        }

        float ev[16];
        float lmax = 0.f;
        {
            const float fr = S.fL[r];
#pragma unroll
            for (int k = 0; k < 16; ++k) {
                int q = s + 4 * k;
                ev[k] = __expf(S.mat[r][q] + fr + S.gL[q]);
                lmax = fmaxf(lmax, ev[k]);
            }
        }
#pragma unroll
        for (int o = 32; o >= 1; o >>= 1) lmax = fmaxf(lmax, __shfl_xor(lmax, o));
        if ((t & 63) == 0) S.wred[t >> 6] = lmax;
        __syncthreads();
        int* mcnt = bars + 3584;
        int* gmax = bars + 3600;
        if (t == 0) {
            float mb = fmaxf(fmaxf(S.wred[0], S.wred[1]), fmaxf(S.wred[2], S.wred[3]));
            atomicMax(gmax, __float_as_int(mb));   // all values > 0
            asm volatile("s_waitcnt vmcnt(0)" ::: "memory");
            __hip_atomic_fetch_add(mcnt, 1, __ATOMIC_RELAXED, __HIP_MEMORY_SCOPE_AGENT);
            while (__hip_atomic_load(mcnt, __ATOMIC_RELAXED, __HIP_MEMORY_SCOPE_AGENT) < 8)
                __builtin_amdgcn_s_sleep(2);
        }
        __syncthreads();
        const float inv = 1.f / __int_as_float(
            __hip_atomic_load(gmax, __ATOMIC_RELAXED, __HIP_MEMORY_SCOPE_AGENT));
#pragma unroll
        for (int k = 0; k < 16; ++k) {
            int q = s + 4 * k;
            out[((size_t)b * kN + r) * kN + q] = ev[k] * inv;
        }
    }
}

// ---------------------------------------------------------------------------
extern "C" void kernel_launch(void* const* d_in, const int* in_sizes, int n_in,
                              void* d_out, int out_size, void* d_ws, size_t ws_size,
                              hipStream_t stream)
{
    (void)in_sizes; (void)n_in; (void)out_size; (void)ws_size;

    const float* x1    = (const float*)d_in[0];
    const float* x2    = (const float*)d_in[1];
    const float* e1    = (const float*)d_in[2];
    const float* e2    = (const float*)d_in[3];
    const float* Wp    = (const float*)d_in[4];
    const float* bp    = (const float*)d_in[5];
    const float* gamma = (const float*)d_in[6];
    const float* beta  = (const float*)d_in[7];
    const float* W0 = (const float*)d_in[8];
    const float* b0 = (const float*)d_in[9];
    const float* S0 = (const float*)d_in[10];
    const float* c0 = (const float*)d_in[11];
    const float* W1 = (const float*)d_in[12];
    const float* b1 = (const float*)d_in[13];
    const float* S1 = (const float*)d_in[14];
    const float* c1 = (const float*)d_in[15];
    const float* W2 = (const float*)d_in[16];
    const float* b2 = (const float*)d_in[17];
    const float* S2 = (const float*)d_in[18];
    const float* c2 = (const float*)d_in[19];
    const float* Wc = (const float*)d_in[20];
    const float* bc = (const float*)d_in[21];
    const float* binv = (const float*)d_in[22];
    const int* src1 = (const int*)d_in[23];
    const int* dst1 = (const int*)d_in[24];
    const int* src2 = (const int*)d_in[25];
    const int* dst2 = (const int*)d_in[26];

    float* out = (float*)d_out;
    float* wsf = (float*)d_ws;

    float* hbuf  = wsf;                    // 1,048,576
    float* Kp    = hbuf + 1048576;         // 32,768
    float* Ke    = Kp + 32768;             // 294,912
    float* vA    = Ke + 294912;            // 32,768
    float* vB    = vA + 32768;             // 32,768
    float* xA    = vB + 32768;             // 557,056
    float* xB    = xA + 557056;            // 557,056
    int*   degcnt = (int*)(xB + 557056);   // 32,768
    int*   off1 = degcnt + 32768;          // 520
    int*   off2 = off1 + 520;              // 520
    int*   lst1 = off2 + 520;              // 1,536
    int*   lst2 = lst1 + 1536;             // 1,536
    int*   rep1g = lst2 + 1536;            // 1,536
    int*   rep2g = rep1g + 1536;           // 1,536
    int*   coff1 = rep2g + 1536;           // 1,544
    int*   coff2 = coff1 + 1544;           // 1,544
    int*   clst1 = coff2 + 1544;           // 1,536
    int*   clst2 = clst1 + 1536;           // 1,536
    float* stats = (float*)(clst2 + 1536); // 2,048   (zeroed by memset)
    int*   bars  = (int*)(stats + 2048);   // 4,096   (zeroed by memset)

    (void)hipMemsetAsync(stats, 0, (2048 + 4096) * sizeof(int), stream);
    k_proj<<<dim3(512), dim3(256), 0, stream>>>(x1, x2, e1, e2, Wp, bp, hbuf, stats);
    k_simcsr<<<dim3(328), dim3(256), 0, stream>>>(hbuf, stats, gamma, beta,
        src1, dst1, src2, dst2, Kp, Ke,
        off1, off2, lst1, lst2, rep1g, rep2g, coff1, coff2, clst1, clst2);
    k_layers<<<dim3(512), dim3(256), 0, stream>>>(
        W0, b0, S0, c0, W1, b1, S1, c1, W2, b2, S2, c2, Wc, bc, binv,
        dst1, dst2, Kp, Ke, vA, vB, xA, xB, degcnt,
        off1, off2, lst1, lst2, rep1g, rep2g, coff1, coff2, clst1, clst2,
        bars, out);
}

// Round 7
// 359.252 us; speedup vs baseline: 5.0459x; 1.0809x over previous
//
#include <hip/hip_runtime.h>

constexpr int kB   = 8;
constexpr int kN   = 64;
constexpr int kE   = 192;
constexpr int kDin = 1024;
constexpr int kDp  = 256;
constexpr int kNN  = 4096;
constexpr float kTauInv = 20.0f;
constexpr int kXS  = 16;     // x row stride (ss channel lives in LDS only)

typedef float vfloat4 __attribute__((ext_vector_type(4)));
typedef unsigned long long ull;

// ---------------------------------------------------------------------------
// Device-coherent accessors (sc0/sc1, live at the coherence point).
// R6 lesson: semantics fine, SHAPE was wrong — scalar scattered 4B ops.
// This round: 8B packed + LDS staging to make them coalesced & rare.
// ---------------------------------------------------------------------------
__device__ __forceinline__ float cload(const float* p) {
    return __hip_atomic_load(p, __ATOMIC_RELAXED, __HIP_MEMORY_SCOPE_AGENT);
}
__device__ __forceinline__ void cstore(float* p, float v) {
    __hip_atomic_store(p, v, __ATOMIC_RELAXED, __HIP_MEMORY_SCOPE_AGENT);
}
__device__ __forceinline__ int cloadi(const int* p) {
    return __hip_atomic_load(p, __ATOMIC_RELAXED, __HIP_MEMORY_SCOPE_AGENT);
}
__device__ __forceinline__ void cstorei(int* p, int v) {
    __hip_atomic_store(p, v, __ATOMIC_RELAXED, __HIP_MEMORY_SCOPE_AGENT);
}
__device__ __forceinline__ ull cload8(const ull* p) {
    return __hip_atomic_load(p, __ATOMIC_RELAXED, __HIP_MEMORY_SCOPE_AGENT);
}
__device__ __forceinline__ void cstore8(ull* p, ull v) {
    __hip_atomic_store(p, v, __ATOMIC_RELAXED, __HIP_MEMORY_SCOPE_AGENT);
}

// ---------------------------------------------------------------------------
// Fence-free two-level grid barrier (cross-phase data is coherent-only).
// __syncthreads drains each wave's outstanding stores before arrival.
// ---------------------------------------------------------------------------
__device__ __forceinline__ void gsync_nf(int* bars, int slot)
{
    __syncthreads();
    if (threadIdx.x == 0) {
        int* base = bars + slot * 512;
        const int g = (int)blockIdx.x >> 6;
        asm volatile("s_waitcnt vmcnt(0)" ::: "memory");
        int prev = __hip_atomic_fetch_add(&base[g * 16], 1, __ATOMIC_RELAXED,
                                          __HIP_MEMORY_SCOPE_AGENT);
        if (prev == 63) {
            int r = __hip_atomic_fetch_add(&base[128], 1, __ATOMIC_RELAXED,
                                           __HIP_MEMORY_SCOPE_AGENT);
            if (r == 7) {
#pragma unroll
                for (int gg = 0; gg < 8; ++gg)
                    __hip_atomic_store(&base[256 + gg * 16], 1, __ATOMIC_RELAXED,
                                       __HIP_MEMORY_SCOPE_AGENT);
            }
        }
        while (__hip_atomic_load(&base[256 + g * 16], __ATOMIC_RELAXED,
                                 __HIP_MEMORY_SCOPE_AGENT) == 0)
            __builtin_amdgcn_s_sleep(8);
    }
    __syncthreads();
}

// ===========================================================================
// K1: projection GEMM (full K) + bias + BN-stats.  512 blocks.
// ===========================================================================
__global__ __launch_bounds__(256) void k_proj(
    const float* __restrict__ x1, const float* __restrict__ x2,
    const float* __restrict__ e1, const float* __restrict__ e2,
    const float* __restrict__ Wp, const float* __restrict__ bp,
    float* __restrict__ hbuf, float* __restrict__ stats)
{
    __shared__ float As[2][16][36];
    __shared__ float Ws[2][16][68];
    __shared__ float colS[64], colS2[64];

    const int bid = blockIdx.x, t = threadIdx.x;
    const int rt = bid >> 2, ct = bid & 3;
    const int grow0 = rt * 32, col0 = ct * 64;
    const int seg = (rt < 16) ? 0 : (rt < 32 ? 1 : (rt < 80 ? 2 : 3));
    const float* src; int lrow0;
    if (rt < 16)      { src = x1; lrow0 = grow0; }
    else if (rt < 32) { src = x2; lrow0 = grow0 - 512; }
    else if (rt < 80) { src = e1; lrow0 = grow0 - 1024; }
    else              { src = e2; lrow0 = grow0 - 2560; }

    const int tx = t & 15, ty = t >> 4;
    const int arow = t >> 3, acol = (t & 7) * 2;
    const int wrow = t >> 4, wcol = (t & 15) * 4;
    if (t < 64) { colS[t] = 0.f; colS2[t] = 0.f; }

    const float* Abase = src + (size_t)(lrow0 + arow) * kDin + acol;
    const float* Wbase = Wp + (size_t)wrow * kDp + col0 + wcol;

    float2 a2 = *(const float2*)Abase;
    float4 w4 = *(const float4*)Wbase;
    float acc[2][4] = {};

    for (int c = 0; c < 64; ++c) {
        const int cur = c & 1;
        As[cur][acol + 0][arow] = a2.x;
        As[cur][acol + 1][arow] = a2.y;
        *(float4*)&Ws[cur][wrow][wcol] = w4;
        __syncthreads();
        if (c < 63) {
            a2 = *(const float2*)(Abase + (c + 1) * 16);
            w4 = *(const float4*)(Wbase + (size_t)(c + 1) * 16 * kDp);
        }
#pragma unroll
        for (int kk = 0; kk < 16; ++kk) {
            float2 av = *(const float2*)&As[cur][kk][ty * 2];
            float4 wv = *(const float4*)&Ws[cur][kk][tx * 4];
            acc[0][0] += av.x * wv.x; acc[0][1] += av.x * wv.y;
            acc[0][2] += av.x * wv.z; acc[0][3] += av.x * wv.w;
            acc[1][0] += av.y * wv.x; acc[1][1] += av.y * wv.y;
            acc[1][2] += av.y * wv.z; acc[1][3] += av.y * wv.w;
        }
    }
    const float4 bb4 = *(const float4*)&bp[col0 + tx * 4];
    float sC[4] = {0.f, 0.f, 0.f, 0.f}, qC[4] = {0.f, 0.f, 0.f, 0.f};
#pragma unroll
    for (int i = 0; i < 2; ++i) {
        const int row = grow0 + ty * 2 + i;
        vfloat4 v;
        v.x = acc[i][0] + bb4.x; v.y = acc[i][1] + bb4.y;
        v.z = acc[i][2] + bb4.z; v.w = acc[i][3] + bb4.w;
        __builtin_nontemporal_store(v, (vfloat4*)&hbuf[(size_t)row * kDp + col0 + tx * 4]);
        sC[0] += v.x; sC[1] += v.y; sC[2] += v.z; sC[3] += v.w;
        qC[0] += v.x * v.x; qC[1] += v.y * v.y;
        qC[2] += v.z * v.z; qC[3] += v.w * v.w;
    }
#pragma unroll
    for (int j = 0; j < 4; ++j) {
        atomicAdd(&colS[tx * 4 + j], sC[j]);
        atomicAdd(&colS2[tx * 4 + j], qC[j]);
    }
    __syncthreads();
    if (t < 64) {
        atomicAdd(&stats[seg * 512 + col0 + t], colS[t]);
        atomicAdd(&stats[seg * 512 + 256 + col0 + t], colS2[t]);
    }
}

// ===========================================================================
// K2: similarity GEMMs with inline BN+ReLU+L2 (blocks 0..319) || CSR build.
// ===========================================================================
struct SmemSim  {
    float Xs[32][36]; float Ys[32][36];
    float muX[256], isX[256], muY[256], isY[256];
    float ga[256], be[256];
    float scX[32], scY[32];
};
struct SmemCsr  {
    int km1[4096], km2[4096];
    short es1[kE], es2[kE], rp1[kE], rp2[kE];
    int cnt1[64], cnt2[64], pos1[64], pos2[64];
    int ccnt1[kE], ccnt2[kE], cpos1[kE], cpos2[kE];
};
union __align__(16) SmemK2 { SmemSim sim; SmemCsr csr; };

__global__ __launch_bounds__(256) void k_simcsr(
    const float* __restrict__ hbuf, const float* __restrict__ stats,
    const float* __restrict__ gamma, const float* __restrict__ beta,
    const int* __restrict__ src1, const int* __restrict__ dst1,
    const int* __restrict__ src2, const int* __restrict__ dst2,
    float* __restrict__ Kp, float* __restrict__ Ke,
    int* __restrict__ off1, int* __restrict__ off2,
    int* __restrict__ lst1, int* __restrict__ lst2,
    int* __restrict__ rep1g, int* __restrict__ rep2g,
    int* __restrict__ coff1, int* __restrict__ coff2,
    int* __restrict__ clst1, int* __restrict__ clst2)
{
    const int bid = blockIdx.x, t = threadIdx.x;
    __shared__ SmemK2 u;

    if (bid < 320) {
        const int id = bid % 40, b = bid / 40;
        int mt, nt_, ldo, segX, segY, xrow0, yrow0; float* outp; float scale;
        if (id < 4) {
            mt = (id >> 1) * 32; nt_ = (id & 1) * 32; ldo = 64;
            xrow0 = b * 64; yrow0 = 512 + b * 64;
            segX = 0; segY = 1;
            outp = Kp + (size_t)b * 4096; scale = 1.0f;
        } else {
            int e = id - 4;
            mt = (e / 6) * 32; nt_ = (e % 6) * 32; ldo = 192;
            xrow0 = 1024 + b * 192; yrow0 = 2560 + b * 192;
            segX = 2; segY = 3;
            outp = Ke + (size_t)b * 36864; scale = 0.5f;
        }
        {
            const float n = (segX < 2) ? 512.f : 1536.f;
            float mu = stats[segX * 512 + t] / n;
            float var = stats[segX * 512 + 256 + t] / n - mu * mu;
            u.sim.muX[t] = mu; u.sim.isX[t] = rsqrtf(var + 1e-5f);
            mu = stats[segY * 512 + t] / n;
            var = stats[segY * 512 + 256 + t] / n - mu * mu;
            u.sim.muY[t] = mu; u.sim.isY[t] = rsqrtf(var + 1e-5f);
            u.sim.ga[t] = gamma[t]; u.sim.be[t] = beta[t];
        }
        __syncthreads();
        {
            const int ri = t >> 2, lane = t & 3;
            const bool isXr = ri < 32;
            const int grow = isXr ? (xrow0 + mt + ri) : (yrow0 + nt_ + (ri - 32));
            const float* mus = isXr ? u.sim.muX : u.sim.muY;
            const float* iss = isXr ? u.sim.isX : u.sim.isY;
            const float* hr = hbuf + (size_t)grow * kDp;
            float ss = 0.f;
            for (int c4 = 0; c4 < 16; ++c4) {
                int c = lane * 64 + c4 * 4;
                float4 v = *(const float4*)&hr[c];
                float p;
                p = fmaxf((v.x - mus[c+0]) * iss[c+0] * u.sim.ga[c+0] + u.sim.be[c+0], 0.f); ss += p * p;
                p = fmaxf((v.y - mus[c+1]) * iss[c+1] * u.sim.ga[c+1] + u.sim.be[c+1], 0.f); ss += p * p;
                p = fmaxf((v.z - mus[c+2]) * iss[c+2] * u.sim.ga[c+2] + u.sim.be[c+2], 0.f); ss += p * p;
                p = fmaxf((v.w - mus[c+3]) * iss[c+3] * u.sim.ga[c+3] + u.sim.be[c+3], 0.f); ss += p * p;
            }
            ss += __shfl_xor(ss, 1);
            ss += __shfl_xor(ss, 2);
            if (lane == 0) {
                float sc = 1.f / fmaxf(sqrtf(ss), 1e-12f);
                if (isXr) u.sim.scX[ri] = sc; else u.sim.scY[ri - 32] = sc;
            }
        }
        __syncthreads();
        const int row = t >> 3, kq = t & 7;
        const int ty = t >> 4, tx = t & 15;
        const float* Xp = hbuf + (size_t)(xrow0 + mt) * kDp;
        const float* Yp = hbuf + (size_t)(yrow0 + nt_) * kDp;
        float acc[2][2] = {};
        for (int k0 = 0; k0 < kDp; k0 += 32) {
            const int c = k0 + kq * 4;
            float4 xa = *(const float4*)(Xp + (size_t)row * kDp + c);
            float4 ya = *(const float4*)(Yp + (size_t)row * kDp + c);
            const float sx = u.sim.scX[row], sy = u.sim.scY[row];
            u.sim.Xs[kq*4+0][row] = fmaxf((xa.x - u.sim.muX[c+0]) * u.sim.isX[c+0] * u.sim.ga[c+0] + u.sim.be[c+0], 0.f) * sx;
            u.sim.Xs[kq*4+1][row] = fmaxf((xa.y - u.sim.muX[c+1]) * u.sim.isX[c+1] * u.sim.ga[c+1] + u.sim.be[c+1], 0.f) * sx;
            u.sim.Xs[kq*4+2][row] = fmaxf((xa.z - u.sim.muX[c+2]) * u.sim.isX[c+2] * u.sim.ga[c+2] + u.sim.be[c+2], 0.f) * sx;
            u.sim.Xs[kq*4+3][row] = fmaxf((xa.w - u.sim.muX[c+3]) * u.sim.isX[c+3] * u.sim.ga[c+3] + u.sim.be[c+3], 0.f) * sx;
            u.sim.Ys[kq*4+0][row] = fmaxf((ya.x - u.sim.muY[c+0]) * u.sim.isY[c+0] * u.sim.ga[c+0] + u.sim.be[c+0], 0.f) * sy;
            u.sim.Ys[kq*4+1][row] = fmaxf((ya.y - u.sim.muY[c+1]) * u.sim.isY[c+1] * u.sim.ga[c+1] + u.sim.be[c+1], 0.f) * sy;
            u.sim.Ys[kq*4+2][row] = fmaxf((ya.z - u.sim.muY[c+2]) * u.sim.isY[c+2] * u.sim.ga[c+2] + u.sim.be[c+2], 0.f) * sy;
            u.sim.Ys[kq*4+3][row] = fmaxf((ya.w - u.sim.muY[c+3]) * u.sim.isY[c+3] * u.sim.ga[c+3] + u.sim.be[c+3], 0.f) * sy;
            __syncthreads();
#pragma unroll
            for (int kk = 0; kk < 32; ++kk) {
                float2 xv = *(const float2*)&u.sim.Xs[kk][ty * 2];
                float2 yv = *(const float2*)&u.sim.Ys[kk][tx * 2];
                acc[0][0] += xv.x * yv.x; acc[0][1] += xv.x * yv.y;
                acc[1][0] += xv.y * yv.x; acc[1][1] += xv.y * yv.y;
            }
            __syncthreads();
        }
#pragma unroll
        for (int i = 0; i < 2; ++i)
#pragma unroll
            for (int j = 0; j < 2; ++j)
                __builtin_nontemporal_store(scale * acc[i][j],
                    &outp[(size_t)(mt + ty * 2 + i) * ldo + nt_ + tx * 2 + j]);
    } else {
        const int b = bid - 320;
        auto& C = u.csr;
        for (int i = t; i < 4096; i += 256) {
            C.km1[i] = 0x7fffffff; C.km2[i] = 0x7fffffff;
        }
        if (t < 64) { C.cnt1[t] = 0; C.cnt2[t] = 0; }
        for (int i = t; i < kE; i += 256) { C.ccnt1[i] = 0; C.ccnt2[i] = 0; }
        __syncthreads();
        if (t < kE) {
            int v1 = src1[b * kE + t], v2 = src2[b * kE + t];
            C.es1[t] = (short)v1; C.es2[t] = (short)v2;
            atomicAdd(&C.cnt1[v1], 1);
            atomicAdd(&C.cnt2[v2], 1);
            atomicMin(&C.km1[v1 * 64 + dst1[b * kE + t]], t);
            atomicMin(&C.km2[v2 * 64 + dst2[b * kE + t]], t);
        }
        __syncthreads();
        if (t < kE) {
            int r1 = C.km1[C.es1[t] * 64 + dst1[b * kE + t]];
            int r2 = C.km2[C.es2[t] * 64 + dst2[b * kE + t]];
            C.rp1[t] = (short)r1; C.rp2[t] = (short)r2;
            rep1g[b * kE + t] = r1; rep2g[b * kE + t] = r2;
            atomicAdd(&C.ccnt1[r1], 1);
            atomicAdd(&C.ccnt2[r2], 1);
        }
        __syncthreads();
        if (t == 0) {
            int a = 0, c = 0;
            for (int v = 0; v < 64; ++v) { C.pos1[v] = a; a += C.cnt1[v]; C.pos2[v] = c; c += C.cnt2[v]; }
            a = 0; c = 0;
            for (int v = 0; v < kE; ++v) { C.cpos1[v] = a; a += C.ccnt1[v]; C.cpos2[v] = c; c += C.ccnt2[v]; }
        }
        __syncthreads();
        if (t < 64) { off1[b * 65 + t] = C.pos1[t]; off2[b * 65 + t] = C.pos2[t]; }
        if (t == 0) { off1[b * 65 + 64] = kE; off2[b * 65 + 64] = kE; }
        if (t < kE) { coff1[b * 193 + t] = C.cpos1[t]; coff2[b * 193 + t] = C.cpos2[t]; }
        if (t == 0) { coff1[b * 193 + kE] = kE; coff2[b * 193 + kE] = kE; }
        __syncthreads();
        if (t < kE) {
            int p = atomicAdd(&C.pos1[C.es1[t]], 1); lst1[b * kE + p] = t;
            int q = atomicAdd(&C.pos2[C.es2[t]], 1); lst2[b * kE + q] = t;
            int cp = atomicAdd(&C.cpos1[C.rp1[t]], 1); clst1[b * kE + cp] = t;
            int cq = atomicAdd(&C.cpos2[C.rp2[t]], 1); clst2[b * kE + cq] = t;
        }
    }
}

// ===========================================================================
// K3: persistent 512 blocks — 3 GNN layers + final sinkhorns.
// x stride = 16 (ss channel is LDS-only). Gather stages dd2 row-groups in
// LDS (coalesced 8B coherent loads); stores are packed 8B; own-row via LDS.
// ===========================================================================
struct SmemLayer {
    float mat[64][68]; float fL[64], gL[64];
    float WL[17 * 16]; float bL[16], SL[16]; float c0v;
    int jd2[kE]; int il[kE]; float msgT[64][18];
    int co1L[kE + 1], co2L[kE + 1];
    short cl1L[kE], cl2L[kE];
    float xs[64][kXS];                       // staged dd2 row-group
};
struct SmemSink {
    float mat[65][68]; float fL[65], gL[65];
    float WcL[17]; float bcv, binvv; float wred[4];
};
struct __align__(16) SmemK3 {
    union { SmemLayer ly; SmemSink sk; } u;
    float xown[64][kXS];                     // own rows, persists across phases
};

// Local 64x64 sinkhorn from vbuf (coherent, 8B loads) into LDS.
__device__ void sink64_local(int b, int t, float (*mat)[68], float* fL, float* gL,
                             const float* __restrict__ vin)
{
    const ull* v8 = (const ull*)(vin + b * kNN);
    for (int i = t; i < 2048; i += 256) {
        ull v = cload8(v8 + i);
        int idx = i * 2;
        int q = idx >> 6, p = idx & 63;
        mat[p][q]     = __uint_as_float((unsigned)v) * kTauInv;
        mat[p + 1][q] = __uint_as_float((unsigned)(v >> 32)) * kTauInv;
    }
    if (t < 64) { fL[t] = 0.f; gL[t] = 0.f; }
    __syncthreads();
    const int r = t >> 2, s = t & 3;
    float tv[16];
    for (int it = 0; it < 10; ++it) {
        float mx = -1e30f;
#pragma unroll
        for (int k = 0; k < 16; ++k) {
            float v = mat[r][s + 4 * k] + gL[s + 4 * k];
            tv[k] = v; mx = fmaxf(mx, v);
        }
        mx = fmaxf(mx, __shfl_xor(mx, 1));
        mx = fmaxf(mx, __shfl_xor(mx, 2));
        float sum = 0.f;
#pragma unroll
        for (int k = 0; k < 16; ++k) sum += __expf(tv[k] - mx);
        sum += __shfl_xor(sum, 1);
        sum += __shfl_xor(sum, 2);
        if (s == 0) fL[r] = -(mx + __logf(sum));
        __syncthreads();
        mx = -1e30f;
#pragma unroll
        for (int k = 0; k < 16; ++k) {
            float v = mat[s + 4 * k][r] + fL[s + 4 * k];
            tv[k] = v; mx = fmaxf(mx, v);
        }
        mx = fmaxf(mx, __shfl_xor(mx, 1));
        mx = fmaxf(mx, __shfl_xor(mx, 2));
        sum = 0.f;
#pragma unroll
        for (int k = 0; k < 16; ++k) sum += __expf(tv[k] - mx);
        sum += __shfl_xor(sum, 1);
        sum += __shfl_xor(sum, 2);
        if (s == 0) gL[r] = -(mx + __logf(sum));
        __syncthreads();
    }
    const float fr = fL[r];
#pragma unroll
    for (int k = 0; k < 16; ++k) {
        int q = s + 4 * k;
        mat[r][q] = __expf(mat[r][q] + fr + gL[q]);
    }
    __syncthreads();
}

template <int C>
__device__ void layer_phase(int bid, int t, SmemK3& M,
    const int* off1, const int* lst1, const int* off2, const int* lst2,
    const int* d1, const int* d2,
    const int* rep1g, const int* rep2g,
    const int* coff1, const int* coff2,
    const int* clst1, const int* clst2,
    const float* Ke, const float* x, const float* Kp, int* degcnt,
    const float* W, const float* bb, const float* S, const float* c0,
    const float* vprev, float* xn, float* vout)
{
    SmemLayer& L = M.u.ly;
    const int r2 = bid & 63, b = bid >> 6;
    for (int k = t; k < C * 16; k += 256) L.WL[k] = W[k];
    if (t < 16) { L.bL[t] = bb[t]; L.SL[t] = S[t]; }
    if (t == 0) L.c0v = c0[0];
    const int j0 = off2[b * 65 + r2];
    const int n2 = off2[b * 65 + r2 + 1] - j0;
    for (int k = t; k < n2; k += 256) {
        int j = lst2[b * kE + j0 + k];
        int v = (j << 8) | d2[b * kE + j];
        if (C == 1 && rep2g[b * kE + j] == j) v |= 1 << 16;
        L.jd2[k] = v;
    }
    for (int k = t; k < kE; k += 256) {
        int i = lst1[b * kE + k];
        int v = (i << 8) | d1[b * kE + i];
        if (C == 1 && rep1g[b * kE + i] == i) v |= 1 << 16;
        L.il[k] = v;
    }
    if constexpr (C == 1) {
        for (int k = t; k < kE + 1; k += 256) {
            L.co1L[k] = coff1[b * 193 + k];
            L.co2L[k] = coff2[b * 193 + k];
        }
        for (int k = t; k < kE; k += 256) {
            L.cl1L[k] = (short)clst1[b * kE + k];
            L.cl2L[k] = (short)clst2[b * kE + k];
        }
    }
    if constexpr (C == 17) {
        sink64_local(b, t, L.mat, L.fL, L.gL, vprev);  // includes syncthreads
    } else {
        __syncthreads();
    }

    const int r1 = t >> 2, lane = t & 3;
    const int i0 = off1[b * 65 + r1], i1 = off1[b * 65 + r1 + 1];
    const float* Keb = Ke + (size_t)b * kE * kE;
    const float* KpB = Kp + (size_t)b * kNN;
    int degLocal = 0;

    if constexpr (C == 1) {
        float acc = 0.f;
        for (int k = 0; k < n2; ++k) {
            int pk = L.jd2[k], j = (pk >> 8) & 255, dd2 = pk & 255;
            for (int m = i0 + lane; m < i1; m += 4) {
                int pi = L.il[m], i = (pi >> 8) & 255, dd1 = pi & 255;
                if (dd2 == r2 && dd1 == r1) continue;
                acc += Keb[(size_t)i * kE + j] * KpB[dd1 * 64 + dd2];
            }
        }
        acc += __shfl_xor(acc, 1);
        acc += __shfl_xor(acc, 2);
        if (lane == 0) L.msgT[r1][0] = acc;
        for (int m = i0 + lane; m < i1; m += 4) {
            int pi = L.il[m];
            if (!(pi >> 16)) continue;
            int i = (pi >> 8) & 255, dd1 = pi & 255;
            for (int k = 0; k < n2; ++k) {
                int pk = L.jd2[k];
                if (!(pk >> 16)) continue;
                int j = (pk >> 8) & 255, dd2 = pk & 255;
                float sum = 0.f;
                for (int mm = L.co1L[i]; mm < L.co1L[i + 1]; ++mm) {
                    const float* kr = Keb + (size_t)L.cl1L[mm] * kE;
                    for (int nn = L.co2L[j]; nn < L.co2L[j + 1]; ++nn)
                        sum += kr[L.cl2L[nn]];
                }
                if ((r2 * 64 + r1) != (dd2 * 64 + dd1) && sum > 0.0f) ++degLocal;
            }
        }
        degLocal += __shfl_xor(degLocal, 1);
        degLocal += __shfl_xor(degLocal, 2);
    } else {
        const float* xb = x + (size_t)b * kNN * kXS;
        float acc[5];
#pragma unroll
        for (int cc = 0; cc < 5; ++cc) acc[cc] = 0.f;
        ull* xsu = (ull*)&L.xs[0][0];
        for (int k = 0; k < n2; ++k) {
            int pk = L.jd2[k], j = (pk >> 8) & 255, dd2 = pk & 255;
            // stage rows dd2*64..dd2*64+63 (16 ch each) into LDS, coalesced 8B
            __syncthreads();
            const ull* srcu = (const ull*)(xb + (size_t)(dd2 * 64) * kXS);
            xsu[t]       = cload8(srcu + t);
            xsu[t + 256] = cload8(srcu + t + 256);
            __syncthreads();
            for (int m = i0; m < i1; ++m) {
                int pi = L.il[m], dd1 = pi & 255;
                if (dd2 == r2 && dd1 == r1) continue;
                int i = (pi >> 8) & 255;
                float kv = Keb[(size_t)i * kE + j];
                const float* xc = &L.xs[dd1][0];
                acc[0] += kv * xc[lane];
                acc[1] += kv * xc[lane + 4];
                acc[2] += kv * xc[lane + 8];
                acc[3] += kv * xc[lane + 12];
                if (lane == 0) acc[4] += kv * L.mat[dd1][dd2];   // ss from LDS
            }
        }
#pragma unroll
        for (int cc = 0; cc < 5; ++cc) {
            int c = lane + cc * 4;
            if (c < C) L.msgT[r1][c] = acc[cc];
        }
    }
    __syncthreads();

    const int row = r2 * 64 + r1;
    const int idx = b * kNN + row;
    const float kd = KpB[r1 * 64 + r2];
    int degv;
    if constexpr (C == 1) {
        degv = degLocal;
        if (lane == 0) cstorei(&degcnt[idx], degLocal);
    } else {
        degv = cloadi(&degcnt[idx]);
    }
    const float dg = fmaxf((float)(degv + (kd > 0.f ? 1 : 0)), 1.f);
    float m[C];
    if constexpr (C == 1) {
        m[0] = (L.msgT[r1][0] + kd * kd) / dg;
    } else {
#pragma unroll
        for (int c = 0; c < 16; ++c)
            m[c] = (L.msgT[r1][c] + kd * M.xown[r1][c]) / dg;   // own row via LDS
        m[16] = (L.msgT[r1][16] + kd * L.mat[r1][r2]) / dg;     // own ss via LDS
    }
    float h[4];
    float vpart = 0.f;
#pragma unroll
    for (int ff = 0; ff < 4; ++ff) {
        int f = lane * 4 + ff;
        float a = L.bL[f];
#pragma unroll
        for (int c = 0; c < C; ++c) a += m[c] * L.WL[c * 16 + f];
        h[ff] = fmaxf(a, 0.f);
        vpart += h[ff] * L.SL[f];
    }
    // packed 8B coherent stores (row is 64B-aligned; lane offset 16B)
    {
        ull u0 = ((ull)__float_as_uint(h[1]) << 32) | __float_as_uint(h[0]);
        ull u1 = ((ull)__float_as_uint(h[3]) << 32) | __float_as_uint(h[2]);
        ull* dst = (ull*)(xn + (size_t)idx * kXS + lane * 4);
        cstore8(dst, u0);
        cstore8(dst + 1, u1);
    }
    __syncthreads();   // xown readers (above) are done; safe to overwrite
#pragma unroll
    for (int ff = 0; ff < 4; ++ff) M.xown[r1][lane * 4 + ff] = h[ff];
    vpart += __shfl_xor(vpart, 1);
    vpart += __shfl_xor(vpart, 2);
    if (lane == 0) cstore(&vout[idx], vpart + L.c0v);
}

__global__ __launch_bounds__(256, 2) void k_layers(
    const float* __restrict__ W0, const float* __restrict__ b0,
    const float* __restrict__ S0, const float* __restrict__ c0,
    const float* __restrict__ W1, const float* __restrict__ b1,
    const float* __restrict__ S1, const float* __restrict__ c1,
    const float* __restrict__ W2, const float* __restrict__ b2,
    const float* __restrict__ S2, const float* __restrict__ c2,
    const float* __restrict__ Wc, const float* __restrict__ bc,
    const float* __restrict__ binv,
    const int* __restrict__ dst1, const int* __restrict__ dst2,
    const float* __restrict__ Kp, const float* __restrict__ Ke,
    float* __restrict__ vA, float* __restrict__ vB,
    float* __restrict__ xA, float* __restrict__ xB,
    int* __restrict__ degcnt,
    const int* __restrict__ off1, const int* __restrict__ off2,
    const int* __restrict__ lst1, const int* __restrict__ lst2,
    const int* __restrict__ rep1g, const int* __restrict__ rep2g,
    const int* __restrict__ coff1, const int* __restrict__ coff2,
    const int* __restrict__ clst1, const int* __restrict__ clst2,
    int* __restrict__ bars, float* __restrict__ out)
{
    const int bid = blockIdx.x;
    const int t = threadIdx.x;
    __shared__ SmemK3 M;

    layer_phase<1>(bid, t, M, off1, lst1, off2, lst2, dst1, dst2,
                   rep1g, rep2g, coff1, coff2, clst1, clst2,
                   Ke, nullptr, Kp, degcnt, W0, b0, S0, c0, nullptr, xA, vA);
    gsync_nf(bars, 0);
    layer_phase<17>(bid, t, M, off1, lst1, off2, lst2, dst1, dst2,
                    rep1g, rep2g, coff1, coff2, clst1, clst2,
                    Ke, xA, Kp, degcnt, W1, b1, S1, c1, vA, xB, vB);
    gsync_nf(bars, 1);
    layer_phase<17>(bid, t, M, off1, lst1, off2, lst2, dst1, dst2,
                    rep1g, rep2g, coff1, coff2, clst1, clst2,
                    Ke, xB, Kp, degcnt, W2, b2, S2, c2, vB, xA, vA);
    gsync_nf(bars, 2);

    // ====== final: 8 blocks only — sink64 + sink65 + max + normalize =======
    if ((bid & 63) == 0) {
        const int b = bid >> 6;
        auto& S = M.u.sk;
        if (t < 17) S.WcL[t] = Wc[t];
        if (t == 17) S.bcv = bc[0];
        if (t == 18) S.binvv = binv[0];
        sink64_local(b, t, S.mat, S.fL, S.gL, vA);   // ss in mat[0..63][0..63]

        for (int idx = t; idx < 65 * 65; idx += 256) {
            int q = idx / 65, p = idx - q * 65;
            float v;
            if (p < 64 && q < 64) {
                const ull* xr = (const ull*)(xA + (size_t)(b * kNN + q * 64 + p) * kXS);
                v = S.bcv;
#pragma unroll
                for (int c8 = 0; c8 < 8; ++c8) {
                    ull uv = cload8(xr + c8);
                    v += __uint_as_float((unsigned)uv) * S.WcL[c8 * 2];
                    v += __uint_as_float((unsigned)(uv >> 32)) * S.WcL[c8 * 2 + 1];
                }
                v += S.mat[p][q] * S.WcL[16];
            } else v = S.binvv;
            S.mat[p][q] = v;
        }
        if (t < 65) { S.fL[t] = 0.f; S.gL[t] = 0.f; }
        __syncthreads();

        const int r = t >> 2, s = t & 3;
        for (int it = 0; it < 10; ++it) {
            for (int rr = r; rr < 65; rr += 64) {
                float tv[17];
                float mx = -1e30f;
#pragma unroll
                for (int k = 0; k < 17; ++k) {
                    int q = s + 4 * k;
                    float v = (q < 65) ? S.mat[rr][q] + S.gL[q] : -1e30f;
                    tv[k] = v; mx = fmaxf(mx, v);
                }
                mx = fmaxf(mx, __shfl_xor(mx, 1));
                mx = fmaxf(mx, __shfl_xor(mx, 2));
                float sum = 0.f;
#pragma unroll
                for (int k = 0; k < 17; ++k) sum += __expf(tv[k] - mx);
                sum += __shfl_xor(sum, 1);
                sum += __shfl_xor(sum, 2);
                if (s == 0) S.fL[rr] = -(mx + __logf(sum));
            }
            __syncthreads();
            for (int rr = r; rr < 65; rr += 64) {
                float tv[17];
                float mx = -1e30f;
#pragma unroll
                for (int k = 0; k < 17; ++k) {
                    int p = s + 4 * k;
                    float v = (p < 65) ? S.mat[p][rr] + S.fL[p] : -1e30f;
                    tv[k] = v; mx = fmaxf(mx, v);
                }
                mx = fmaxf(mx, __shfl_xor(mx, 1));
                mx = fmaxf(mx, __shfl_xor(mx, 2));
                float sum = 0.f;
#pragma unroll
                for (int k = 0; k < 17; ++k) sum += __expf(tv[k] - mx);
                sum += __shfl_xor(sum, 1);
                sum += __shfl_xor(sum, 2);
                if (s == 0) S.gL[rr] = -(mx + __logf(sum));
            }
            __syncthreads();
        }

        float ev[16];
        float lmax = 0.f;
        {
            const float fr = S.fL[r];
#pragma unroll
            for (int k = 0; k < 16; ++k) {
                int q = s + 4 * k;
                ev[k] = __expf(S.mat[r][q] + fr + S.gL[q]);
                lmax = fmaxf(lmax, ev[k]);
            }
        }
#pragma unroll
        for (int o = 32; o >= 1; o >>= 1) lmax = fmaxf(lmax, __shfl_xor(lmax, o));
        if ((t & 63) == 0) S.wred[t >> 6] = lmax;
        __syncthreads();
        int* mcnt = bars + 3584;
        int* gmax = bars + 3600;
        if (t == 0) {
            float mb = fmaxf(fmaxf(S.wred[0], S.wred[1]), fmaxf(S.wred[2], S.wred[3]));
            atomicMax(gmax, __float_as_int(mb));   // all values > 0
            asm volatile("s_waitcnt vmcnt(0)" ::: "memory");
            __hip_atomic_fetch_add(mcnt, 1, __ATOMIC_RELAXED, __HIP_MEMORY_SCOPE_AGENT);
            while (__hip_atomic_load(mcnt, __ATOMIC_RELAXED, __HIP_MEMORY_SCOPE_AGENT) < 8)
                __builtin_amdgcn_s_sleep(2);
        }
        __syncthreads();
        const float inv = 1.f / __int_as_float(
            __hip_atomic_load(gmax, __ATOMIC_RELAXED, __HIP_MEMORY_SCOPE_AGENT));
#pragma unroll
        for (int k = 0; k < 16; ++k) {
            int q = s + 4 * k;
            out[((size_t)b * kN + r) * kN + q] = ev[k] * inv;
        }
    }
}

// ---------------------------------------------------------------------------
extern "C" void kernel_launch(void* const* d_in, const int* in_sizes, int n_in,
                              void* d_out, int out_size, void* d_ws, size_t ws_size,
                              hipStream_t stream)
{
    (void)in_sizes; (void)n_in; (void)out_size; (void)ws_size;

    const float* x1    = (const float*)d_in[0];
    const float* x2    = (const float*)d_in[1];
    const float* e1    = (const float*)d_in[2];
    const float* e2    = (const float*)d_in[3];
    const float* Wp    = (const float*)d_in[4];
    const float* bp    = (const float*)d_in[5];
    const float* gamma = (const float*)d_in[6];
    const float* beta  = (const float*)d_in[7];
    const float* W0 = (const float*)d_in[8];
    const float* b0 = (const float*)d_in[9];
    const float* S0 = (const float*)d_in[10];
    const float* c0 = (const float*)d_in[11];
    const float* W1 = (const float*)d_in[12];
    const float* b1 = (const float*)d_in[13];
    const float* S1 = (const float*)d_in[14];
    const float* c1 = (const float*)d_in[15];
    const float* W2 = (const float*)d_in[16];
    const float* b2 = (const float*)d_in[17];
    const float* S2 = (const float*)d_in[18];
    const float* c2 = (const float*)d_in[19];
    const float* Wc = (const float*)d_in[20];
    const float* bc = (const float*)d_in[21];
    const float* binv = (const float*)d_in[22];
    const int* src1 = (const int*)d_in[23];
    const int* dst1 = (const int*)d_in[24];
    const int* src2 = (const int*)d_in[25];
    const int* dst2 = (const int*)d_in[26];

    float* out = (float*)d_out;
    float* wsf = (float*)d_ws;

    float* hbuf  = wsf;                    // 1,048,576
    float* Kp    = hbuf + 1048576;         // 32,768
    float* Ke    = Kp + 32768;             // 294,912
    float* vA    = Ke + 294912;            // 32,768
    float* vB    = vA + 32768;             // 32,768
    float* xA    = vB + 32768;             // 524,288 (stride 16)
    float* xB    = xA + 524288;            // 524,288
    int*   degcnt = (int*)(xB + 524288);   // 32,768
    int*   off1 = degcnt + 32768;          // 520
    int*   off2 = off1 + 520;              // 520
    int*   lst1 = off2 + 520;              // 1,536
    int*   lst2 = lst1 + 1536;             // 1,536
    int*   rep1g = lst2 + 1536;            // 1,536
    int*   rep2g = rep1g + 1536;           // 1,536
    int*   coff1 = rep2g + 1536;           // 1,544
    int*   coff2 = coff1 + 1544;           // 1,544
    int*   clst1 = coff2 + 1544;           // 1,536
    int*   clst2 = clst1 + 1536;           // 1,536
    float* stats = (float*)(clst2 + 1536); // 2,048   (zeroed by memset)
    int*   bars  = (int*)(stats + 2048);   // 4,096   (zeroed by memset)

    (void)hipMemsetAsync(stats, 0, (2048 + 4096) * sizeof(int), stream);
    k_proj<<<dim3(512), dim3(256), 0, stream>>>(x1, x2, e1, e2, Wp, bp, hbuf, stats);
    k_simcsr<<<dim3(328), dim3(256), 0, stream>>>(hbuf, stats, gamma, beta,
        src1, dst1, src2, dst2, Kp, Ke,
        off1, off2, lst1, lst2, rep1g, rep2g, coff1, coff2, clst1, clst2);
    k_layers<<<dim3(512), dim3(256), 0, stream>>>(
        W0, b0, S0, c0, W1, b1, S1, c1, W2, b2, S2, c2, Wc, bc, binv,
        dst1, dst2, Kp, Ke, vA, vB, xA, xB, degcnt,
        off1, off2, lst1, lst2, rep1g, rep2g, coff1, coff2, clst1, clst2,
        bars, out);
}

// Round 8
// 336.831 us; speedup vs baseline: 5.3817x; 1.0666x over previous
//
#include <hip/hip_runtime.h>

constexpr int kB   = 8;
constexpr int kN   = 64;
constexpr int kE   = 192;
constexpr int kDin = 1024;
constexpr int kDp  = 256;
constexpr int kNN  = 4096;
constexpr float kTauInv = 20.0f;
constexpr int kXS  = 16;     // x row stride (ss channel lives in LDS only)
constexpr int kXP  = 18;     // padded LDS stride for staged x rows

typedef float vfloat4 __attribute__((ext_vector_type(4)));

// ===========================================================================
// K1: projection GEMM (blocks 0..511) + CSR build (blocks 512..519).
// CSR depends only on src/dst inputs -> runs concurrently with the GEMM.
// ===========================================================================
struct SmemGemm {
    float As[2][16][36]; float Ws[2][16][68];
    float colS[64], colS2[64];
};
struct SmemCsr  {
    int km1[4096], km2[4096];
    short es1[kE], es2[kE], rp1[kE], rp2[kE];
    int cnt1[64], cnt2[64], pos1[64], pos2[64];
    int ccnt1[kE], ccnt2[kE], cpos1[kE], cpos2[kE];
};
union __align__(16) SmemK1 { SmemGemm g; SmemCsr csr; };

__global__ __launch_bounds__(256) void k_projcsr(
    const float* __restrict__ x1, const float* __restrict__ x2,
    const float* __restrict__ e1, const float* __restrict__ e2,
    const float* __restrict__ Wp, const float* __restrict__ bp,
    const int* __restrict__ src1, const int* __restrict__ dst1,
    const int* __restrict__ src2, const int* __restrict__ dst2,
    float* __restrict__ hbuf, float* __restrict__ stats,
    int* __restrict__ off1, int* __restrict__ off2,
    int* __restrict__ lst1, int* __restrict__ lst2,
    int* __restrict__ rep1g, int* __restrict__ rep2g,
    int* __restrict__ coff1, int* __restrict__ coff2,
    int* __restrict__ clst1, int* __restrict__ clst2)
{
    const int bid = blockIdx.x, t = threadIdx.x;
    __shared__ SmemK1 u;

    if (bid < 512) {
        const int rt = bid >> 2, ct = bid & 3;
        const int grow0 = rt * 32, col0 = ct * 64;
        const int seg = (rt < 16) ? 0 : (rt < 32 ? 1 : (rt < 80 ? 2 : 3));
        const float* src; int lrow0;
        if (rt < 16)      { src = x1; lrow0 = grow0; }
        else if (rt < 32) { src = x2; lrow0 = grow0 - 512; }
        else if (rt < 80) { src = e1; lrow0 = grow0 - 1024; }
        else              { src = e2; lrow0 = grow0 - 2560; }

        const int tx = t & 15, ty = t >> 4;
        const int arow = t >> 3, acol = (t & 7) * 2;
        const int wrow = t >> 4, wcol = (t & 15) * 4;
        if (t < 64) { u.g.colS[t] = 0.f; u.g.colS2[t] = 0.f; }

        const float* Abase = src + (size_t)(lrow0 + arow) * kDin + acol;
        const float* Wbase = Wp + (size_t)wrow * kDp + col0 + wcol;

        float2 a2 = *(const float2*)Abase;
        float4 w4 = *(const float4*)Wbase;
        float acc[2][4] = {};

        for (int c = 0; c < 64; ++c) {
            const int cur = c & 1;
            u.g.As[cur][acol + 0][arow] = a2.x;
            u.g.As[cur][acol + 1][arow] = a2.y;
            *(float4*)&u.g.Ws[cur][wrow][wcol] = w4;
            __syncthreads();
            if (c < 63) {
                a2 = *(const float2*)(Abase + (c + 1) * 16);
                w4 = *(const float4*)(Wbase + (size_t)(c + 1) * 16 * kDp);
            }
#pragma unroll
            for (int kk = 0; kk < 16; ++kk) {
                float2 av = *(const float2*)&u.g.As[cur][kk][ty * 2];
                float4 wv = *(const float4*)&u.g.Ws[cur][kk][tx * 4];
                acc[0][0] += av.x * wv.x; acc[0][1] += av.x * wv.y;
                acc[0][2] += av.x * wv.z; acc[0][3] += av.x * wv.w;
                acc[1][0] += av.y * wv.x; acc[1][1] += av.y * wv.y;
                acc[1][2] += av.y * wv.z; acc[1][3] += av.y * wv.w;
            }
        }
        const float4 bb4 = *(const float4*)&bp[col0 + tx * 4];
        float sC[4] = {0.f, 0.f, 0.f, 0.f}, qC[4] = {0.f, 0.f, 0.f, 0.f};
#pragma unroll
        for (int i = 0; i < 2; ++i) {
            const int row = grow0 + ty * 2 + i;
            vfloat4 v;
            v.x = acc[i][0] + bb4.x; v.y = acc[i][1] + bb4.y;
            v.z = acc[i][2] + bb4.z; v.w = acc[i][3] + bb4.w;
            __builtin_nontemporal_store(v, (vfloat4*)&hbuf[(size_t)row * kDp + col0 + tx * 4]);
            sC[0] += v.x; sC[1] += v.y; sC[2] += v.z; sC[3] += v.w;
            qC[0] += v.x * v.x; qC[1] += v.y * v.y;
            qC[2] += v.z * v.z; qC[3] += v.w * v.w;
        }
#pragma unroll
        for (int j = 0; j < 4; ++j) {
            atomicAdd(&u.g.colS[tx * 4 + j], sC[j]);
            atomicAdd(&u.g.colS2[tx * 4 + j], qC[j]);
        }
        __syncthreads();
        if (t < 64) {
            atomicAdd(&stats[seg * 512 + col0 + t], u.g.colS[t]);
            atomicAdd(&stats[seg * 512 + 256 + col0 + t], u.g.colS2[t]);
        }
    } else {
        const int b = bid - 512;
        auto& C = u.csr;
        for (int i = t; i < 4096; i += 256) {
            C.km1[i] = 0x7fffffff; C.km2[i] = 0x7fffffff;
        }
        if (t < 64) { C.cnt1[t] = 0; C.cnt2[t] = 0; }
        for (int i = t; i < kE; i += 256) { C.ccnt1[i] = 0; C.ccnt2[i] = 0; }
        __syncthreads();
        if (t < kE) {
            int v1 = src1[b * kE + t], v2 = src2[b * kE + t];
            C.es1[t] = (short)v1; C.es2[t] = (short)v2;
            atomicAdd(&C.cnt1[v1], 1);
            atomicAdd(&C.cnt2[v2], 1);
            atomicMin(&C.km1[v1 * 64 + dst1[b * kE + t]], t);
            atomicMin(&C.km2[v2 * 64 + dst2[b * kE + t]], t);
        }
        __syncthreads();
        if (t < kE) {
            int r1 = C.km1[C.es1[t] * 64 + dst1[b * kE + t]];
            int r2 = C.km2[C.es2[t] * 64 + dst2[b * kE + t]];
            C.rp1[t] = (short)r1; C.rp2[t] = (short)r2;
            rep1g[b * kE + t] = r1; rep2g[b * kE + t] = r2;
            atomicAdd(&C.ccnt1[r1], 1);
            atomicAdd(&C.ccnt2[r2], 1);
        }
        __syncthreads();
        if (t == 0) {
            int a = 0, c = 0;
            for (int v = 0; v < 64; ++v) { C.pos1[v] = a; a += C.cnt1[v]; C.pos2[v] = c; c += C.cnt2[v]; }
            a = 0; c = 0;
            for (int v = 0; v < kE; ++v) { C.cpos1[v] = a; a += C.ccnt1[v]; C.cpos2[v] = c; c += C.ccnt2[v]; }
        }
        __syncthreads();
        if (t < 64) { off1[b * 65 + t] = C.pos1[t]; off2[b * 65 + t] = C.pos2[t]; }
        if (t == 0) { off1[b * 65 + 64] = kE; off2[b * 65 + 64] = kE; }
        if (t < kE) { coff1[b * 193 + t] = C.cpos1[t]; coff2[b * 193 + t] = C.cpos2[t]; }
        if (t == 0) { coff1[b * 193 + kE] = kE; coff2[b * 193 + kE] = kE; }
        __syncthreads();
        if (t < kE) {
            int p = atomicAdd(&C.pos1[C.es1[t]], 1); lst1[b * kE + p] = t;
            int q = atomicAdd(&C.pos2[C.es2[t]], 1); lst2[b * kE + q] = t;
            int cp = atomicAdd(&C.cpos1[C.rp1[t]], 1); clst1[b * kE + cp] = t;
            int cq = atomicAdd(&C.cpos2[C.rp2[t]], 1); clst2[b * kE + cq] = t;
        }
    }
}

// ===========================================================================
// K2: similarity GEMMs with inline BN+ReLU+L2.  320 blocks.
// ===========================================================================
struct __align__(16) SmemSim  {
    float Xs[32][36]; float Ys[32][36];
    float muX[256], isX[256], muY[256], isY[256];
    float ga[256], be[256];
    float scX[32], scY[32];
};

__global__ __launch_bounds__(256) void k_sim(
    const float* __restrict__ hbuf, const float* __restrict__ stats,
    const float* __restrict__ gamma, const float* __restrict__ beta,
    float* __restrict__ Kp, float* __restrict__ Ke)
{
    const int bid = blockIdx.x, t = threadIdx.x;
    __shared__ SmemSim u;

    const int id = bid % 40, b = bid / 40;
    int mt, nt_, ldo, segX, segY, xrow0, yrow0; float* outp; float scale;
    if (id < 4) {
        mt = (id >> 1) * 32; nt_ = (id & 1) * 32; ldo = 64;
        xrow0 = b * 64; yrow0 = 512 + b * 64;
        segX = 0; segY = 1;
        outp = Kp + (size_t)b * 4096; scale = 1.0f;
    } else {
        int e = id - 4;
        mt = (e / 6) * 32; nt_ = (e % 6) * 32; ldo = 192;
        xrow0 = 1024 + b * 192; yrow0 = 2560 + b * 192;
        segX = 2; segY = 3;
        outp = Ke + (size_t)b * 36864; scale = 0.5f;
    }
    {
        const float n = (segX < 2) ? 512.f : 1536.f;
        float mu = stats[segX * 512 + t] / n;
        float var = stats[segX * 512 + 256 + t] / n - mu * mu;
        u.muX[t] = mu; u.isX[t] = rsqrtf(var + 1e-5f);
        mu = stats[segY * 512 + t] / n;
        var = stats[segY * 512 + 256 + t] / n - mu * mu;
        u.muY[t] = mu; u.isY[t] = rsqrtf(var + 1e-5f);
        u.ga[t] = gamma[t]; u.be[t] = beta[t];
    }
    __syncthreads();
    {
        const int ri = t >> 2, lane = t & 3;
        const bool isXr = ri < 32;
        const int grow = isXr ? (xrow0 + mt + ri) : (yrow0 + nt_ + (ri - 32));
        const float* mus = isXr ? u.muX : u.muY;
        const float* iss = isXr ? u.isX : u.isY;
        const float* hr = hbuf + (size_t)grow * kDp;
        float ss = 0.f;
        for (int c4 = 0; c4 < 16; ++c4) {
            int c = lane * 64 + c4 * 4;
            float4 v = *(const float4*)&hr[c];
            float p;
            p = fmaxf((v.x - mus[c+0]) * iss[c+0] * u.ga[c+0] + u.be[c+0], 0.f); ss += p * p;
            p = fmaxf((v.y - mus[c+1]) * iss[c+1] * u.ga[c+1] + u.be[c+1], 0.f); ss += p * p;
            p = fmaxf((v.z - mus[c+2]) * iss[c+2] * u.ga[c+2] + u.be[c+2], 0.f); ss += p * p;
            p = fmaxf((v.w - mus[c+3]) * iss[c+3] * u.ga[c+3] + u.be[c+3], 0.f); ss += p * p;
        }
        ss += __shfl_xor(ss, 1);
        ss += __shfl_xor(ss, 2);
        if (lane == 0) {
            float sc = 1.f / fmaxf(sqrtf(ss), 1e-12f);
            if (isXr) u.scX[ri] = sc; else u.scY[ri - 32] = sc;
        }
    }
    __syncthreads();
    const int row = t >> 3, kq = t & 7;
    const int ty = t >> 4, tx = t & 15;
    const float* Xp = hbuf + (size_t)(xrow0 + mt) * kDp;
    const float* Yp = hbuf + (size_t)(yrow0 + nt_) * kDp;
    float acc[2][2] = {};
    for (int k0 = 0; k0 < kDp; k0 += 32) {
        const int c = k0 + kq * 4;
        float4 xa = *(const float4*)(Xp + (size_t)row * kDp + c);
        float4 ya = *(const float4*)(Yp + (size_t)row * kDp + c);
        const float sx = u.scX[row], sy = u.scY[row];
        u.Xs[kq*4+0][row] = fmaxf((xa.x - u.muX[c+0]) * u.isX[c+0] * u.ga[c+0] + u.be[c+0], 0.f) * sx;
        u.Xs[kq*4+1][row] = fmaxf((xa.y - u.muX[c+1]) * u.isX[c+1] * u.ga[c+1] + u.be[c+1], 0.f) * sx;
        u.Xs[kq*4+2][row] = fmaxf((xa.z - u.muX[c+2]) * u.isX[c+2] * u.ga[c+2] + u.be[c+2], 0.f) * sx;
        u.Xs[kq*4+3][row] = fmaxf((xa.w - u.muX[c+3]) * u.isX[c+3] * u.ga[c+3] + u.be[c+3], 0.f) * sx;
        u.Ys[kq*4+0][row] = fmaxf((ya.x - u.muY[c+0]) * u.isY[c+0] * u.ga[c+0] + u.be[c+0], 0.f) * sy;
        u.Ys[kq*4+1][row] = fmaxf((ya.y - u.muY[c+1]) * u.isY[c+1] * u.ga[c+1] + u.be[c+1], 0.f) * sy;
        u.Ys[kq*4+2][row] = fmaxf((ya.z - u.muY[c+2]) * u.isY[c+2] * u.ga[c+2] + u.be[c+2], 0.f) * sy;
        u.Ys[kq*4+3][row] = fmaxf((ya.w - u.muY[c+3]) * u.isY[c+3] * u.ga[c+3] + u.be[c+3], 0.f) * sy;
        __syncthreads();
#pragma unroll
        for (int kk = 0; kk < 32; ++kk) {
            float2 xv = *(const float2*)&u.Xs[kk][ty * 2];
            float2 yv = *(const float2*)&u.Ys[kk][tx * 2];
            acc[0][0] += xv.x * yv.x; acc[0][1] += xv.x * yv.y;
            acc[1][0] += xv.y * yv.x; acc[1][1] += xv.y * yv.y;
        }
        __syncthreads();
    }
#pragma unroll
    for (int i = 0; i < 2; ++i)
#pragma unroll
        for (int j = 0; j < 2; ++j)
            __builtin_nontemporal_store(scale * acc[i][j],
                &outp[(size_t)(mt + ty * 2 + i) * ldo + nt_ + tx * 2 + j]);
}

// ===========================================================================
// K3a/b/c: one GNN layer per kernel (512 blocks each), normal cached loads,
// nontemporal stores.  k_l2 additionally fuses the Wc projection (vc).
// ===========================================================================
struct __align__(16) SmemLayer {
    float mat[64][68]; float fL[64], gL[64];
    float WL[17 * 16]; float bL[16], SL[16]; float c0v;
    float WcL[17]; 
    int jd2[kE]; int il[kE]; float msgT[64][18];
    int co1L[kE + 1], co2L[kE + 1];
    short cl1L[kE], cl2L[kE];
    float xs[64][kXP];
};

// Local per-block 64x64 sinkhorn from vin into LDS mat (prob values).
__device__ void sink64_local(int b, int t, float (*mat)[68], float* fL, float* gL,
                             const float* __restrict__ vin)
{
    const float4* v4 = (const float4*)(vin + b * kNN);
    for (int i = t; i < 1024; i += 256) {
        float4 v = v4[i];
        int idx = i * 4;
        int q = idx >> 6, p = idx & 63;
        mat[p][q]     = v.x * kTauInv;
        mat[p + 1][q] = v.y * kTauInv;
        mat[p + 2][q] = v.z * kTauInv;
        mat[p + 3][q] = v.w * kTauInv;
    }
    if (t < 64) { fL[t] = 0.f; gL[t] = 0.f; }
    __syncthreads();
    const int r = t >> 2, s = t & 3;
    float tv[16];
    for (int it = 0; it < 10; ++it) {
        float mx = -1e30f;
#pragma unroll
        for (int k = 0; k < 16; ++k) {
            float v = mat[r][s + 4 * k] + gL[s + 4 * k];
            tv[k] = v; mx = fmaxf(mx, v);
        }
        mx = fmaxf(mx, __shfl_xor(mx, 1));
        mx = fmaxf(mx, __shfl_xor(mx, 2));
        float sum = 0.f;
#pragma unroll
        for (int k = 0; k < 16; ++k) sum += __expf(tv[k] - mx);
        sum += __shfl_xor(sum, 1);
        sum += __shfl_xor(sum, 2);
        if (s == 0) fL[r] = -(mx + __logf(sum));
        __syncthreads();
        mx = -1e30f;
#pragma unroll
        for (int k = 0; k < 16; ++k) {
            float v = mat[s + 4 * k][r] + fL[s + 4 * k];
            tv[k] = v; mx = fmaxf(mx, v);
        }
        mx = fmaxf(mx, __shfl_xor(mx, 1));
        mx = fmaxf(mx, __shfl_xor(mx, 2));
        sum = 0.f;
#pragma unroll
        for (int k = 0; k < 16; ++k) sum += __expf(tv[k] - mx);
        sum += __shfl_xor(sum, 1);
        sum += __shfl_xor(sum, 2);
        if (s == 0) gL[r] = -(mx + __logf(sum));
        __syncthreads();
    }
    const float fr = fL[r];
#pragma unroll
    for (int k = 0; k < 16; ++k) {
        int q = s + 4 * k;
        mat[r][q] = __expf(mat[r][q] + fr + gL[q]);
    }
    __syncthreads();
}

template <int C, bool LASTP>
__device__ void layer_body(int bid, int t, SmemLayer& L,
    const int* __restrict__ off1, const int* __restrict__ lst1,
    const int* __restrict__ off2, const int* __restrict__ lst2,
    const int* __restrict__ d1, const int* __restrict__ d2,
    const int* __restrict__ rep1g, const int* __restrict__ rep2g,
    const int* __restrict__ coff1, const int* __restrict__ coff2,
    const int* __restrict__ clst1, const int* __restrict__ clst2,
    const float* __restrict__ Ke, const float* __restrict__ x,
    const float* __restrict__ Kp, int* __restrict__ degcnt,
    const float* __restrict__ W, const float* __restrict__ bb,
    const float* __restrict__ S, const float* __restrict__ c0,
    const float* __restrict__ Wc,
    const float* __restrict__ vprev, float* __restrict__ xn,
    float* __restrict__ vcbuf, float* __restrict__ vout)
{
    const int r2 = bid & 63, b = bid >> 6;
    for (int k = t; k < C * 16; k += 256) L.WL[k] = W[k];
    if (t < 16) { L.bL[t] = bb[t]; L.SL[t] = S[t]; }
    if (t == 0) L.c0v = c0[0];
    if (LASTP && t < 17) L.WcL[t] = Wc[t];
    const int j0 = off2[b * 65 + r2];
    const int n2 = off2[b * 65 + r2 + 1] - j0;
    for (int k = t; k < n2; k += 256) {
        int j = lst2[b * kE + j0 + k];
        int v = (j << 8) | d2[b * kE + j];
        if (C == 1 && rep2g[b * kE + j] == j) v |= 1 << 16;
        L.jd2[k] = v;
    }
    for (int k = t; k < kE; k += 256) {
        int i = lst1[b * kE + k];
        int v = (i << 8) | d1[b * kE + i];
        if (C == 1 && rep1g[b * kE + i] == i) v |= 1 << 16;
        L.il[k] = v;
    }
    if constexpr (C == 1) {
        for (int k = t; k < kE + 1; k += 256) {
            L.co1L[k] = coff1[b * 193 + k];
            L.co2L[k] = coff2[b * 193 + k];
        }
        for (int k = t; k < kE; k += 256) {
            L.cl1L[k] = (short)clst1[b * kE + k];
            L.cl2L[k] = (short)clst2[b * kE + k];
        }
    }
    if constexpr (C == 17) {
        sink64_local(b, t, L.mat, L.fL, L.gL, vprev);  // includes syncthreads
    } else {
        __syncthreads();
    }

    const int r1 = t >> 2, lane = t & 3;
    const int i0 = off1[b * 65 + r1], i1 = off1[b * 65 + r1 + 1];
    const float* Keb = Ke + (size_t)b * kE * kE;
    const float* KpB = Kp + (size_t)b * kNN;
    int degLocal = 0;

    if constexpr (C == 1) {
        float acc = 0.f;
        for (int k = 0; k < n2; ++k) {
            int pk = L.jd2[k], j = (pk >> 8) & 255, dd2 = pk & 255;
            for (int m = i0 + lane; m < i1; m += 4) {
                int pi = L.il[m], i = (pi >> 8) & 255, dd1 = pi & 255;
                if (dd2 == r2 && dd1 == r1) continue;
                acc += Keb[(size_t)i * kE + j] * KpB[dd1 * 64 + dd2];
            }
        }
        acc += __shfl_xor(acc, 1);
        acc += __shfl_xor(acc, 2);
        if (lane == 0) L.msgT[r1][0] = acc;
        for (int m = i0 + lane; m < i1; m += 4) {
            int pi = L.il[m];
            if (!(pi >> 16)) continue;
            int i = (pi >> 8) & 255, dd1 = pi & 255;
            for (int k = 0; k < n2; ++k) {
                int pk = L.jd2[k];
                if (!(pk >> 16)) continue;
                int j = (pk >> 8) & 255, dd2 = pk & 255;
                float sum = 0.f;
                for (int mm = L.co1L[i]; mm < L.co1L[i + 1]; ++mm) {
                    const float* kr = Keb + (size_t)L.cl1L[mm] * kE;
                    for (int nn = L.co2L[j]; nn < L.co2L[j + 1]; ++nn)
                        sum += kr[L.cl2L[nn]];
                }
                if ((r2 * 64 + r1) != (dd2 * 64 + dd1) && sum > 0.0f) ++degLocal;
            }
        }
        degLocal += __shfl_xor(degLocal, 1);
        degLocal += __shfl_xor(degLocal, 2);
    } else {
        const float* xb = x + (size_t)b * kNN * kXS;
        float acc[5];
#pragma unroll
        for (int cc = 0; cc < 5; ++cc) acc[cc] = 0.f;
        for (int k = 0; k < n2; ++k) {
            int pk = L.jd2[k], j = (pk >> 8) & 255, dd2 = pk & 255;
            // stage rows dd2*64..+63 (16 ch) into padded LDS, coalesced 16B
            __syncthreads();
            {
                const float4* src4 = (const float4*)(xb + (size_t)(dd2 * 64) * kXS);
                float4 vv = src4[t];
                const int row = t >> 2, c4 = (t & 3) * 4;
                L.xs[row][c4 + 0] = vv.x; L.xs[row][c4 + 1] = vv.y;
                L.xs[row][c4 + 2] = vv.z; L.xs[row][c4 + 3] = vv.w;
            }
            __syncthreads();
            for (int m = i0; m < i1; ++m) {
                int pi = L.il[m], dd1 = pi & 255;
                if (dd2 == r2 && dd1 == r1) continue;
                int i = (pi >> 8) & 255;
                float kv = Keb[(size_t)i * kE + j];
                const float* xc = &L.xs[dd1][0];
                acc[0] += kv * xc[lane];
                acc[1] += kv * xc[lane + 4];
                acc[2] += kv * xc[lane + 8];
                acc[3] += kv * xc[lane + 12];
                if (lane == 0) acc[4] += kv * L.mat[dd1][dd2];   // ss from LDS
            }
        }
#pragma unroll
        for (int cc = 0; cc < 5; ++cc) {
            int c = lane + cc * 4;
            if (c < C) L.msgT[r1][c] = acc[cc];
        }
    }
    __syncthreads();

    const int row = r2 * 64 + r1;
    const int idx = b * kNN + row;
    const float kd = KpB[r1 * 64 + r2];
    int degv;
    if constexpr (C == 1) {
        degv = degLocal;
        if (lane == 0) __builtin_nontemporal_store(degLocal, &degcnt[idx]);
    } else {
        degv = degcnt[idx];
    }
    const float dg = fmaxf((float)(degv + (kd > 0.f ? 1 : 0)), 1.f);
    float m[C];
    if constexpr (C == 1) {
        m[0] = (L.msgT[r1][0] + kd * kd) / dg;
    } else {
        const float4* xr4 = (const float4*)(x + (size_t)idx * kXS + lane * 4);
        // own-row term: coalesced float4 covering this lane's 4 channels
        float4 xo = *xr4;
        // gather full own row via msgT-style LDS? channels are lane-split:
        // m[c] only needed for c handled... but W multiply needs ALL c.
        // So read the full row (4 float4s, coalesced across lanes).
        float4 xa = *(const float4*)(x + (size_t)idx * kXS + 0);
        float4 xb4 = *(const float4*)(x + (size_t)idx * kXS + 4);
        float4 xc4 = *(const float4*)(x + (size_t)idx * kXS + 8);
        float4 xd4 = *(const float4*)(x + (size_t)idx * kXS + 12);
        (void)xo;
        m[0]  = (L.msgT[r1][0]  + kd * xa.x) / dg;
        m[1]  = (L.msgT[r1][1]  + kd * xa.y) / dg;
        m[2]  = (L.msgT[r1][2]  + kd * xa.z) / dg;
        m[3]  = (L.msgT[r1][3]  + kd * xa.w) / dg;
        m[4]  = (L.msgT[r1][4]  + kd * xb4.x) / dg;
        m[5]  = (L.msgT[r1][5]  + kd * xb4.y) / dg;
        m[6]  = (L.msgT[r1][6]  + kd * xb4.z) / dg;
        m[7]  = (L.msgT[r1][7]  + kd * xb4.w) / dg;
        m[8]  = (L.msgT[r1][8]  + kd * xc4.x) / dg;
        m[9]  = (L.msgT[r1][9]  + kd * xc4.y) / dg;
        m[10] = (L.msgT[r1][10] + kd * xc4.z) / dg;
        m[11] = (L.msgT[r1][11] + kd * xc4.w) / dg;
        m[12] = (L.msgT[r1][12] + kd * xd4.x) / dg;
        m[13] = (L.msgT[r1][13] + kd * xd4.y) / dg;
        m[14] = (L.msgT[r1][14] + kd * xd4.z) / dg;
        m[15] = (L.msgT[r1][15] + kd * xd4.w) / dg;
        m[16] = (L.msgT[r1][16] + kd * L.mat[r1][r2]) / dg;   // own ss via LDS
    }
    float h[4];
    float vpart = 0.f;
#pragma unroll
    for (int ff = 0; ff < 4; ++ff) {
        int f = lane * 4 + ff;
        float a = L.bL[f];
#pragma unroll
        for (int c = 0; c < C; ++c) a += m[c] * L.WL[c * 16 + f];
        h[ff] = fmaxf(a, 0.f);
        vpart += h[ff] * L.SL[f];
    }
    if constexpr (!LASTP) {
        vfloat4 hv; hv.x = h[0]; hv.y = h[1]; hv.z = h[2]; hv.w = h[3];
        __builtin_nontemporal_store(hv, (vfloat4*)(xn + (size_t)idx * kXS + lane * 4));
    } else {
        float vcp = h[0] * L.WcL[lane * 4 + 0] + h[1] * L.WcL[lane * 4 + 1]
                  + h[2] * L.WcL[lane * 4 + 2] + h[3] * L.WcL[lane * 4 + 3];
        vcp += __shfl_xor(vcp, 1);
        vcp += __shfl_xor(vcp, 2);
        if (lane == 0) __builtin_nontemporal_store(vcp, &vcbuf[idx]);
    }
    vpart += __shfl_xor(vpart, 1);
    vpart += __shfl_xor(vpart, 2);
    if (lane == 0) __builtin_nontemporal_store(vpart + L.c0v, &vout[idx]);
}

__global__ __launch_bounds__(256) void k_l0(
    const int* __restrict__ off1, const int* __restrict__ lst1,
    const int* __restrict__ off2, const int* __restrict__ lst2,
    const int* __restrict__ dst1, const int* __restrict__ dst2,
    const int* __restrict__ rep1g, const int* __restrict__ rep2g,
    const int* __restrict__ coff1, const int* __restrict__ coff2,
    const int* __restrict__ clst1, const int* __restrict__ clst2,
    const float* __restrict__ Ke, const float* __restrict__ Kp,
    int* __restrict__ degcnt,
    const float* __restrict__ W0, const float* __restrict__ b0,
    const float* __restrict__ S0, const float* __restrict__ c0,
    float* __restrict__ xA, float* __restrict__ vA)
{
    __shared__ SmemLayer L;
    layer_body<1, false>(blockIdx.x, threadIdx.x, L,
        off1, lst1, off2, lst2, dst1, dst2, rep1g, rep2g,
        coff1, coff2, clst1, clst2, Ke, nullptr, Kp, degcnt,
        W0, b0, S0, c0, nullptr, nullptr, xA, nullptr, vA);
}

__global__ __launch_bounds__(256) void k_l1(
    const int* __restrict__ off1, const int* __restrict__ lst1,
    const int* __restrict__ off2, const int* __restrict__ lst2,
    const int* __restrict__ dst1, const int* __restrict__ dst2,
    const float* __restrict__ Ke, const float* __restrict__ Kp,
    int* __restrict__ degcnt,
    const float* __restrict__ W1, const float* __restrict__ b1,
    const float* __restrict__ S1, const float* __restrict__ c1,
    const float* __restrict__ xA, const float* __restrict__ vA,
    float* __restrict__ xB, float* __restrict__ vB)
{
    __shared__ SmemLayer L;
    layer_body<17, false>(blockIdx.x, threadIdx.x, L,
        off1, lst1, off2, lst2, dst1, dst2, nullptr, nullptr,
        nullptr, nullptr, nullptr, nullptr, Ke, xA, Kp, degcnt,
        W1, b1, S1, c1, nullptr, vA, xB, nullptr, vB);
}

__global__ __launch_bounds__(256) void k_l2(
    const int* __restrict__ off1, const int* __restrict__ lst1,
    const int* __restrict__ off2, const int* __restrict__ lst2,
    const int* __restrict__ dst1, const int* __restrict__ dst2,
    const float* __restrict__ Ke, const float* __restrict__ Kp,
    int* __restrict__ degcnt,
    const float* __restrict__ W2, const float* __restrict__ b2,
    const float* __restrict__ S2, const float* __restrict__ c2,
    const float* __restrict__ Wc,
    const float* __restrict__ xB, const float* __restrict__ vB,
    float* __restrict__ vcbuf, float* __restrict__ vA)
{
    __shared__ SmemLayer L;
    layer_body<17, true>(blockIdx.x, threadIdx.x, L,
        off1, lst1, off2, lst2, dst1, dst2, nullptr, nullptr,
        nullptr, nullptr, nullptr, nullptr, Ke, xB, Kp, degcnt,
        W2, b2, S2, c2, Wc, vB, nullptr, vcbuf, vA);
}

// ===========================================================================
// K4: final — 8 blocks: ss = sinkhorn(v2); 65x65 bin sinkhorn from vc + ss;
// global max via atomicMax + 8-block mini-barrier; normalize; write out.
// ===========================================================================
struct __align__(16) SmemSink {
    float mat[65][68]; float fL[65], gL[65];
    float wred[4];
};

__global__ __launch_bounds__(256) void k_final(
    const float* __restrict__ vA, const float* __restrict__ vcbuf,
    const float* __restrict__ Wc, const float* __restrict__ bc,
    const float* __restrict__ binv,
    int* __restrict__ bars, float* __restrict__ out)
{
    const int b = blockIdx.x, t = threadIdx.x;
    __shared__ SmemSink S;

    sink64_local(b, t, S.mat, S.fL, S.gL, vA);   // ss in mat[0..63][0..63]

    const float Wc16 = Wc[16], bcv = bc[0], binvv = binv[0];
    const float* vcb = vcbuf + (size_t)b * kNN;
    for (int idx = t; idx < 65 * 65; idx += 256) {
        int q = idx / 65, p = idx - q * 65;
        float v;
        if (p < 64 && q < 64)
            v = vcb[q * 64 + p] + S.mat[p][q] * Wc16 + bcv;
        else v = binvv;
        S.mat[p][q] = v;
    }
    if (t < 65) { S.fL[t] = 0.f; S.gL[t] = 0.f; }
    __syncthreads();

    const int r = t >> 2, s = t & 3;
    for (int it = 0; it < 10; ++it) {
        for (int rr = r; rr < 65; rr += 64) {
            float tv[17];
            float mx = -1e30f;
#pragma unroll
            for (int k = 0; k < 17; ++k) {
                int q = s + 4 * k;
                float v = (q < 65) ? S.mat[rr][q] + S.gL[q] : -1e30f;
                tv[k] = v; mx = fmaxf(mx, v);
            }
            mx = fmaxf(mx, __shfl_xor(mx, 1));
            mx = fmaxf(mx, __shfl_xor(mx, 2));
            float sum = 0.f;
#pragma unroll
            for (int k = 0; k < 17; ++k) sum += __expf(tv[k] - mx);
            sum += __shfl_xor(sum, 1);
            sum += __shfl_xor(sum, 2);
            if (s == 0) S.fL[rr] = -(mx + __logf(sum));
        }
        __syncthreads();
        for (int rr = r; rr < 65; rr += 64) {
            float tv[17];
            float mx = -1e30f;
#pragma unroll
            for (int k = 0; k < 17; ++k) {
                int p = s + 4 * k;
                float v = (p < 65) ? S.mat[p][rr] + S.fL[p] : -1e30f;
                tv[k] = v; mx = fmaxf(mx, v);
            }
            mx = fmaxf(mx, __shfl_xor(mx, 1));
            mx = fmaxf(mx, __shfl_xor(mx, 2));
            float sum = 0.f;
#pragma unroll
            for (int k = 0; k < 17; ++k) sum += __expf(tv[k] - mx);
            sum += __shfl_xor(sum, 1);
            sum += __shfl_xor(sum, 2);
            if (s == 0) S.gL[rr] = -(mx + __logf(sum));
        }
        __syncthreads();
    }

    float ev[16];
    float lmax = 0.f;
    {
        const float fr = S.fL[r];
#pragma unroll
        for (int k = 0; k < 16; ++k) {
            int q = s + 4 * k;
            ev[k] = __expf(S.mat[r][q] + fr + S.gL[q]);
            lmax = fmaxf(lmax, ev[k]);
        }
    }
#pragma unroll
    for (int o = 32; o >= 1; o >>= 1) lmax = fmaxf(lmax, __shfl_xor(lmax, o));
    if ((t & 63) == 0) S.wred[t >> 6] = lmax;
    __syncthreads();
    int* mcnt = bars + 3584;
    int* gmax = bars + 3600;
    if (t == 0) {
        float mb = fmaxf(fmaxf(S.wred[0], S.wred[1]), fmaxf(S.wred[2], S.wred[3]));
        atomicMax(gmax, __float_as_int(mb));   // all values > 0
        asm volatile("s_waitcnt vmcnt(0)" ::: "memory");
        __hip_atomic_fetch_add(mcnt, 1, __ATOMIC_RELAXED, __HIP_MEMORY_SCOPE_AGENT);
        while (__hip_atomic_load(mcnt, __ATOMIC_RELAXED, __HIP_MEMORY_SCOPE_AGENT) < 8)
            __builtin_amdgcn_s_sleep(2);
    }
    __syncthreads();
    const float inv = 1.f / __int_as_float(
        __hip_atomic_load(gmax, __ATOMIC_RELAXED, __HIP_MEMORY_SCOPE_AGENT));
#pragma unroll
    for (int k = 0; k < 16; ++k) {
        int q = s + 4 * k;
        out[((size_t)b * kN + r) * kN + q] = ev[k] * inv;
    }
}

// ---------------------------------------------------------------------------
extern "C" void kernel_launch(void* const* d_in, const int* in_sizes, int n_in,
                              void* d_out, int out_size, void* d_ws, size_t ws_size,
                              hipStream_t stream)
{
    (void)in_sizes; (void)n_in; (void)out_size; (void)ws_size;

    const float* x1    = (const float*)d_in[0];
    const float* x2    = (const float*)d_in[1];
    const float* e1    = (const float*)d_in[2];
    const float* e2    = (const float*)d_in[3];
    const float* Wp    = (const float*)d_in[4];
    const float* bp    = (const float*)d_in[5];
    const float* gamma = (const float*)d_in[6];
    const float* beta  = (const float*)d_in[7];
    const float* W0 = (const float*)d_in[8];
    const float* b0 = (const float*)d_in[9];
    const float* S0 = (const float*)d_in[10];
    const float* c0 = (const float*)d_in[11];
    const float* W1 = (const float*)d_in[12];
    const float* b1 = (const float*)d_in[13];
    const float* S1 = (const float*)d_in[14];
    const float* c1 = (const float*)d_in[15];
    const float* W2 = (const float*)d_in[16];
    const float* b2 = (const float*)d_in[17];
    const float* S2 = (const float*)d_in[18];
    const float* c2 = (const float*)d_in[19];
    const float* Wc = (const float*)d_in[20];
    const float* bc = (const float*)d_in[21];
    const float* binv = (const float*)d_in[22];
    const int* src1 = (const int*)d_in[23];
    const int* dst1 = (const int*)d_in[24];
    const int* src2 = (const int*)d_in[25];
    const int* dst2 = (const int*)d_in[26];

    float* out = (float*)d_out;
    float* wsf = (float*)d_ws;

    float* hbuf  = wsf;                    // 1,048,576
    float* Kp    = hbuf + 1048576;         // 32,768
    float* Ke    = Kp + 32768;             // 294,912
    float* vA    = Ke + 294912;            // 32,768
    float* vB    = vA + 32768;             // 32,768
    float* xA    = vB + 32768;             // 524,288 (stride 16)
    float* xB    = xA + 524288;            // 524,288
    float* vcbuf = xB + 524288;            // 32,768
    int*   degcnt = (int*)(vcbuf + 32768); // 32,768
    int*   off1 = degcnt + 32768;          // 520
    int*   off2 = off1 + 520;              // 520
    int*   lst1 = off2 + 520;              // 1,536
    int*   lst2 = lst1 + 1536;             // 1,536
    int*   rep1g = lst2 + 1536;            // 1,536
    int*   rep2g = rep1g + 1536;           // 1,536
    int*   coff1 = rep2g + 1536;           // 1,544
    int*   coff2 = coff1 + 1544;           // 1,544
    int*   clst1 = coff2 + 1544;           // 1,536
    int*   clst2 = clst1 + 1536;           // 1,536
    float* stats = (float*)(clst2 + 1536); // 2,048   (zeroed by memset)
    int*   bars  = (int*)(stats + 2048);   // 4,096   (zeroed by memset)

    (void)hipMemsetAsync(stats, 0, (2048 + 4096) * sizeof(int), stream);
    k_projcsr<<<dim3(520), dim3(256), 0, stream>>>(
        x1, x2, e1, e2, Wp, bp, src1, dst1, src2, dst2, hbuf, stats,
        off1, off2, lst1, lst2, rep1g, rep2g, coff1, coff2, clst1, clst2);
    k_sim<<<dim3(320), dim3(256), 0, stream>>>(hbuf, stats, gamma, beta, Kp, Ke);
    k_l0<<<dim3(512), dim3(256), 0, stream>>>(
        off1, lst1, off2, lst2, dst1, dst2, rep1g, rep2g,
        coff1, coff2, clst1, clst2, Ke, Kp, degcnt,
        W0, b0, S0, c0, xA, vA);
    k_l1<<<dim3(512), dim3(256), 0, stream>>>(
        off1, lst1, off2, lst2, dst1, dst2, Ke, Kp, degcnt,
        W1, b1, S1, c1, xA, vA, xB, vB);
    k_l2<<<dim3(512), dim3(256), 0, stream>>>(
        off1, lst1, off2, lst2, dst1, dst2, Ke, Kp, degcnt,
        W2, b2, S2, c2, Wc, xB, vB, vcbuf, vA);
    k_final<<<dim3(8), dim3(256), 0, stream>>>(vA, vcbuf, Wc, bc, binv, bars, out);
}

// Round 9
// 323.497 us; speedup vs baseline: 5.6036x; 1.0412x over previous
//
#include <hip/hip_runtime.h>

constexpr int kB   = 8;
constexpr int kN   = 64;
constexpr int kE   = 192;
constexpr int kDin = 1024;
constexpr int kDp  = 256;
constexpr int kNN  = 4096;
constexpr float kTauInv = 20.0f;
constexpr int kXS  = 16;     // x row stride (ss channel lives in LDS only)
constexpr int kXP  = 18;     // padded LDS stride for staged x rows

typedef float vfloat4 __attribute__((ext_vector_type(4)));

// ===========================================================================
// K1: projection GEMM 64x64 tiles, 4x4 acc/thread (blocks 0..255)
//     + CSR build (blocks 256..263).
// R8: 32x64/2x4 ran 62us at VALUBusy 24% (8 FMA per 1.5 ds_read).
// 4x4 acc doubles FMA:ds_read ratio and ILP.
// ===========================================================================
struct SmemGemm {
    float As[2][16][68]; float Ws[2][16][68];
    float colS[64], colS2[64];
};
struct SmemCsr  {
    int km1[4096], km2[4096];
    short es1[kE], es2[kE], rp1[kE], rp2[kE];
    int cnt1[64], cnt2[64], pos1[64], pos2[64];
    int ccnt1[kE], ccnt2[kE], cpos1[kE], cpos2[kE];
};
union __align__(16) SmemK1 { SmemGemm g; SmemCsr csr; };

__global__ __launch_bounds__(256) void k_projcsr(
    const float* __restrict__ x1, const float* __restrict__ x2,
    const float* __restrict__ e1, const float* __restrict__ e2,
    const float* __restrict__ Wp, const float* __restrict__ bp,
    const int* __restrict__ src1, const int* __restrict__ dst1,
    const int* __restrict__ src2, const int* __restrict__ dst2,
    float* __restrict__ hbuf, float* __restrict__ stats,
    int* __restrict__ off1, int* __restrict__ off2,
    int* __restrict__ lst1, int* __restrict__ lst2,
    int* __restrict__ rep1g, int* __restrict__ rep2g,
    int* __restrict__ coff1, int* __restrict__ coff2,
    int* __restrict__ clst1, int* __restrict__ clst2)
{
    const int bid = blockIdx.x, t = threadIdx.x;
    __shared__ SmemK1 u;

    if (bid < 256) {
        const int rt = bid >> 2, ct = bid & 3;
        const int grow0 = rt * 64, col0 = ct * 64;
        const int seg = (rt < 8) ? 0 : (rt < 16 ? 1 : (rt < 40 ? 2 : 3));
        const float* src; int lrow0;
        if (rt < 8)       { src = x1; lrow0 = grow0; }
        else if (rt < 16) { src = x2; lrow0 = grow0 - 512; }
        else if (rt < 40) { src = e1; lrow0 = grow0 - 1024; }
        else              { src = e2; lrow0 = grow0 - 2560; }

        const int tx = t & 15, ty = t >> 4;
        const int arow = t >> 2, acol = (t & 3) * 4;
        const int wrow = t >> 4, wcol = (t & 15) * 4;
        if (t < 64) { u.g.colS[t] = 0.f; u.g.colS2[t] = 0.f; }

        const float* Abase = src + (size_t)(lrow0 + arow) * kDin + acol;
        const float* Wbase = Wp + (size_t)wrow * kDp + col0 + wcol;

        float4 a4 = *(const float4*)Abase;
        float4 w4 = *(const float4*)Wbase;
        float acc[4][4] = {};

        for (int c = 0; c < 64; ++c) {
            const int cur = c & 1;
            u.g.As[cur][acol + 0][arow] = a4.x;
            u.g.As[cur][acol + 1][arow] = a4.y;
            u.g.As[cur][acol + 2][arow] = a4.z;
            u.g.As[cur][acol + 3][arow] = a4.w;
            *(float4*)&u.g.Ws[cur][wrow][wcol] = w4;
            __syncthreads();
            if (c < 63) {
                a4 = *(const float4*)(Abase + (c + 1) * 16);
                w4 = *(const float4*)(Wbase + (size_t)(c + 1) * 16 * kDp);
            }
#pragma unroll
            for (int kk = 0; kk < 16; ++kk) {
                float4 av = *(const float4*)&u.g.As[cur][kk][ty * 4];
                float4 wv = *(const float4*)&u.g.Ws[cur][kk][tx * 4];
                float a[4] = {av.x, av.y, av.z, av.w};
                float w[4] = {wv.x, wv.y, wv.z, wv.w};
#pragma unroll
                for (int i = 0; i < 4; ++i)
#pragma unroll
                    for (int j = 0; j < 4; ++j)
                        acc[i][j] += a[i] * w[j];
            }
        }
        const float4 bb4 = *(const float4*)&bp[col0 + tx * 4];
        float sC[4] = {0.f, 0.f, 0.f, 0.f}, qC[4] = {0.f, 0.f, 0.f, 0.f};
#pragma unroll
        for (int i = 0; i < 4; ++i) {
            const int row = grow0 + ty * 4 + i;
            vfloat4 v;
            v.x = acc[i][0] + bb4.x; v.y = acc[i][1] + bb4.y;
            v.z = acc[i][2] + bb4.z; v.w = acc[i][3] + bb4.w;
            __builtin_nontemporal_store(v, (vfloat4*)&hbuf[(size_t)row * kDp + col0 + tx * 4]);
            sC[0] += v.x; sC[1] += v.y; sC[2] += v.z; sC[3] += v.w;
            qC[0] += v.x * v.x; qC[1] += v.y * v.y;
            qC[2] += v.z * v.z; qC[3] += v.w * v.w;
        }
#pragma unroll
        for (int j = 0; j < 4; ++j) {
            atomicAdd(&u.g.colS[tx * 4 + j], sC[j]);
            atomicAdd(&u.g.colS2[tx * 4 + j], qC[j]);
        }
        __syncthreads();
        if (t < 64) {
            atomicAdd(&stats[seg * 512 + col0 + t], u.g.colS[t]);
            atomicAdd(&stats[seg * 512 + 256 + col0 + t], u.g.colS2[t]);
        }
    } else {
        const int b = bid - 256;
        auto& C = u.csr;
        for (int i = t; i < 4096; i += 256) {
            C.km1[i] = 0x7fffffff; C.km2[i] = 0x7fffffff;
        }
        if (t < 64) { C.cnt1[t] = 0; C.cnt2[t] = 0; }
        for (int i = t; i < kE; i += 256) { C.ccnt1[i] = 0; C.ccnt2[i] = 0; }
        __syncthreads();
        if (t < kE) {
            int v1 = src1[b * kE + t], v2 = src2[b * kE + t];
            C.es1[t] = (short)v1; C.es2[t] = (short)v2;
            atomicAdd(&C.cnt1[v1], 1);
            atomicAdd(&C.cnt2[v2], 1);
            atomicMin(&C.km1[v1 * 64 + dst1[b * kE + t]], t);
            atomicMin(&C.km2[v2 * 64 + dst2[b * kE + t]], t);
        }
        __syncthreads();
        if (t < kE) {
            int r1 = C.km1[C.es1[t] * 64 + dst1[b * kE + t]];
            int r2 = C.km2[C.es2[t] * 64 + dst2[b * kE + t]];
            C.rp1[t] = (short)r1; C.rp2[t] = (short)r2;
            rep1g[b * kE + t] = r1; rep2g[b * kE + t] = r2;
            atomicAdd(&C.ccnt1[r1], 1);
            atomicAdd(&C.ccnt2[r2], 1);
        }
        __syncthreads();
        if (t == 0) {
            int a = 0, c = 0;
            for (int v = 0; v < 64; ++v) { C.pos1[v] = a; a += C.cnt1[v]; C.pos2[v] = c; c += C.cnt2[v]; }
            a = 0; c = 0;
            for (int v = 0; v < kE; ++v) { C.cpos1[v] = a; a += C.ccnt1[v]; C.cpos2[v] = c; c += C.ccnt2[v]; }
        }
        __syncthreads();
        if (t < 64) { off1[b * 65 + t] = C.pos1[t]; off2[b * 65 + t] = C.pos2[t]; }
        if (t == 0) { off1[b * 65 + 64] = kE; off2[b * 65 + 64] = kE; }
        if (t < kE) { coff1[b * 193 + t] = C.cpos1[t]; coff2[b * 193 + t] = C.cpos2[t]; }
        if (t == 0) { coff1[b * 193 + kE] = kE; coff2[b * 193 + kE] = kE; }
        __syncthreads();
        if (t < kE) {
            int p = atomicAdd(&C.pos1[C.es1[t]], 1); lst1[b * kE + p] = t;
            int q = atomicAdd(&C.pos2[C.es2[t]], 1); lst2[b * kE + q] = t;
            int cp = atomicAdd(&C.cpos1[C.rp1[t]], 1); clst1[b * kE + cp] = t;
            int cq = atomicAdd(&C.cpos2[C.rp2[t]], 1); clst2[b * kE + cq] = t;
        }
    }
}

// ===========================================================================
// K2: similarity GEMMs with inline BN+ReLU+L2.  320 blocks.
// ===========================================================================
struct __align__(16) SmemSim  {
    float Xs[32][36]; float Ys[32][36];
    float muX[256], isX[256], muY[256], isY[256];
    float ga[256], be[256];
    float scX[32], scY[32];
};

__global__ __launch_bounds__(256) void k_sim(
    const float* __restrict__ hbuf, const float* __restrict__ stats,
    const float* __restrict__ gamma, const float* __restrict__ beta,
    float* __restrict__ Kp, float* __restrict__ Ke)
{
    const int bid = blockIdx.x, t = threadIdx.x;
    __shared__ SmemSim u;

    const int id = bid % 40, b = bid / 40;
    int mt, nt_, ldo, segX, segY, xrow0, yrow0; float* outp; float scale;
    if (id < 4) {
        mt = (id >> 1) * 32; nt_ = (id & 1) * 32; ldo = 64;
        xrow0 = b * 64; yrow0 = 512 + b * 64;
        segX = 0; segY = 1;
        outp = Kp + (size_t)b * 4096; scale = 1.0f;
    } else {
        int e = id - 4;
        mt = (e / 6) * 32; nt_ = (e % 6) * 32; ldo = 192;
        xrow0 = 1024 + b * 192; yrow0 = 2560 + b * 192;
        segX = 2; segY = 3;
        outp = Ke + (size_t)b * 36864; scale = 0.5f;
    }
    {
        const float n = (segX < 2) ? 512.f : 1536.f;
        float mu = stats[segX * 512 + t] / n;
        float var = stats[segX * 512 + 256 + t] / n - mu * mu;
        u.muX[t] = mu; u.isX[t] = rsqrtf(var + 1e-5f);
        mu = stats[segY * 512 + t] / n;
        var = stats[segY * 512 + 256 + t] / n - mu * mu;
        u.muY[t] = mu; u.isY[t] = rsqrtf(var + 1e-5f);
        u.ga[t] = gamma[t]; u.be[t] = beta[t];
    }
    __syncthreads();
    {
        const int ri = t >> 2, lane = t & 3;
        const bool isXr = ri < 32;
        const int grow = isXr ? (xrow0 + mt + ri) : (yrow0 + nt_ + (ri - 32));
        const float* mus = isXr ? u.muX : u.muY;
        const float* iss = isXr ? u.isX : u.isY;
        const float* hr = hbuf + (size_t)grow * kDp;
        float ss = 0.f;
        for (int c4 = 0; c4 < 16; ++c4) {
            int c = lane * 64 + c4 * 4;
            float4 v = *(const float4*)&hr[c];
            float p;
            p = fmaxf((v.x - mus[c+0]) * iss[c+0] * u.ga[c+0] + u.be[c+0], 0.f); ss += p * p;
            p = fmaxf((v.y - mus[c+1]) * iss[c+1] * u.ga[c+1] + u.be[c+1], 0.f); ss += p * p;
            p = fmaxf((v.z - mus[c+2]) * iss[c+2] * u.ga[c+2] + u.be[c+2], 0.f); ss += p * p;
            p = fmaxf((v.w - mus[c+3]) * iss[c+3] * u.ga[c+3] + u.be[c+3], 0.f); ss += p * p;
        }
        ss += __shfl_xor(ss, 1);
        ss += __shfl_xor(ss, 2);
        if (lane == 0) {
            float sc = 1.f / fmaxf(sqrtf(ss), 1e-12f);
            if (isXr) u.scX[ri] = sc; else u.scY[ri - 32] = sc;
        }
    }
    __syncthreads();
    const int row = t >> 3, kq = t & 7;
    const int ty = t >> 4, tx = t & 15;
    const float* Xp = hbuf + (size_t)(xrow0 + mt) * kDp;
    const float* Yp = hbuf + (size_t)(yrow0 + nt_) * kDp;
    float acc[2][2] = {};
    for (int k0 = 0; k0 < kDp; k0 += 32) {
        const int c = k0 + kq * 4;
        float4 xa = *(const float4*)(Xp + (size_t)row * kDp + c);
        float4 ya = *(const float4*)(Yp + (size_t)row * kDp + c);
        const float sx = u.scX[row], sy = u.scY[row];
        u.Xs[kq*4+0][row] = fmaxf((xa.x - u.muX[c+0]) * u.isX[c+0] * u.ga[c+0] + u.be[c+0], 0.f) * sx;
        u.Xs[kq*4+1][row] = fmaxf((xa.y - u.muX[c+1]) * u.isX[c+1] * u.ga[c+1] + u.be[c+1], 0.f) * sx;
        u.Xs[kq*4+2][row] = fmaxf((xa.z - u.muX[c+2]) * u.isX[c+2] * u.ga[c+2] + u.be[c+2], 0.f) * sx;
        u.Xs[kq*4+3][row] = fmaxf((xa.w - u.muX[c+3]) * u.isX[c+3] * u.ga[c+3] + u.be[c+3], 0.f) * sx;
        u.Ys[kq*4+0][row] = fmaxf((ya.x - u.muY[c+0]) * u.isY[c+0] * u.ga[c+0] + u.be[c+0], 0.f) * sy;
        u.Ys[kq*4+1][row] = fmaxf((ya.y - u.muY[c+1]) * u.isY[c+1] * u.ga[c+1] + u.be[c+1], 0.f) * sy;
        u.Ys[kq*4+2][row] = fmaxf((ya.z - u.muY[c+2]) * u.isY[c+2] * u.ga[c+2] + u.be[c+2], 0.f) * sy;
        u.Ys[kq*4+3][row] = fmaxf((ya.w - u.muY[c+3]) * u.isY[c+3] * u.ga[c+3] + u.be[c+3], 0.f) * sy;
        __syncthreads();
#pragma unroll
        for (int kk = 0; kk < 32; ++kk) {
            float2 xv = *(const float2*)&u.Xs[kk][ty * 2];
            float2 yv = *(const float2*)&u.Ys[kk][tx * 2];
            acc[0][0] += xv.x * yv.x; acc[0][1] += xv.x * yv.y;
            acc[1][0] += xv.y * yv.x; acc[1][1] += xv.y * yv.y;
        }
        __syncthreads();
    }
#pragma unroll
    for (int i = 0; i < 2; ++i)
#pragma unroll
        for (int j = 0; j < 2; ++j)
            __builtin_nontemporal_store(scale * acc[i][j],
                &outp[(size_t)(mt + ty * 2 + i) * ldo + nt_ + tx * 2 + j]);
}

// ===========================================================================
// K3a/b/c: one GNN layer per kernel (512 blocks each), normal cached loads,
// nontemporal stores.  k_l2 additionally fuses the Wc projection (vc).
// ===========================================================================
struct __align__(16) SmemLayer {
    float mat[64][68]; float fL[64], gL[64];
    float WL[17 * 16]; float bL[16], SL[16]; float c0v;
    float WcL[17];
    int jd2[kE]; int il[kE]; float msgT[64][18];
    int co1L[kE + 1], co2L[kE + 1];
    short cl1L[kE], cl2L[kE];
    float xs[64][kXP];
};

// Local per-block 64x64 sinkhorn from vin into LDS mat (prob values).
__device__ void sink64_local(int b, int t, float (*mat)[68], float* fL, float* gL,
                             const float* __restrict__ vin)
{
    const float4* v4 = (const float4*)(vin + b * kNN);
    for (int i = t; i < 1024; i += 256) {
        float4 v = v4[i];
        int idx = i * 4;
        int q = idx >> 6, p = idx & 63;
        mat[p][q]     = v.x * kTauInv;
        mat[p + 1][q] = v.y * kTauInv;
        mat[p + 2][q] = v.z * kTauInv;
        mat[p + 3][q] = v.w * kTauInv;
    }
    if (t < 64) { fL[t] = 0.f; gL[t] = 0.f; }
    __syncthreads();
    const int r = t >> 2, s = t & 3;
    float tv[16];
    for (int it = 0; it < 10; ++it) {
        float mx = -1e30f;
#pragma unroll
        for (int k = 0; k < 16; ++k) {
            float v = mat[r][s + 4 * k] + gL[s + 4 * k];
            tv[k] = v; mx = fmaxf(mx, v);
        }
        mx = fmaxf(mx, __shfl_xor(mx, 1));
        mx = fmaxf(mx, __shfl_xor(mx, 2));
        float sum = 0.f;
#pragma unroll
        for (int k = 0; k < 16; ++k) sum += __expf(tv[k] - mx);
        sum += __shfl_xor(sum, 1);
        sum += __shfl_xor(sum, 2);
        if (s == 0) fL[r] = -(mx + __logf(sum));
        __syncthreads();
        mx = -1e30f;
#pragma unroll
        for (int k = 0; k < 16; ++k) {
            float v = mat[s + 4 * k][r] + fL[s + 4 * k];
            tv[k] = v; mx = fmaxf(mx, v);
        }
        mx = fmaxf(mx, __shfl_xor(mx, 1));
        mx = fmaxf(mx, __shfl_xor(mx, 2));
        sum = 0.f;
#pragma unroll
        for (int k = 0; k < 16; ++k) sum += __expf(tv[k] - mx);
        sum += __shfl_xor(sum, 1);
        sum += __shfl_xor(sum, 2);
        if (s == 0) gL[r] = -(mx + __logf(sum));
        __syncthreads();
    }
    const float fr = fL[r];
#pragma unroll
    for (int k = 0; k < 16; ++k) {
        int q = s + 4 * k;
        mat[r][q] = __expf(mat[r][q] + fr + gL[q]);
    }
    __syncthreads();
}

template <int C, bool LASTP>
__device__ void layer_body(int bid, int t, SmemLayer& L,
    const int* __restrict__ off1, const int* __restrict__ lst1,
    const int* __restrict__ off2, const int* __restrict__ lst2,
    const int* __restrict__ d1, const int* __restrict__ d2,
    const int* __restrict__ rep1g, const int* __restrict__ rep2g,
    const int* __restrict__ coff1, const int* __restrict__ coff2,
    const int* __restrict__ clst1, const int* __restrict__ clst2,
    const float* __restrict__ Ke, const float* __restrict__ x,
    const float* __restrict__ Kp, int* __restrict__ degcnt,
    const float* __restrict__ W, const float* __restrict__ bb,
    const float* __restrict__ S, const float* __restrict__ c0,
    const float* __restrict__ Wc,
    const float* __restrict__ vprev, float* __restrict__ xn,
    float* __restrict__ vcbuf, float* __restrict__ vout)
{
    const int r2 = bid & 63, b = bid >> 6;
    for (int k = t; k < C * 16; k += 256) L.WL[k] = W[k];
    if (t < 16) { L.bL[t] = bb[t]; L.SL[t] = S[t]; }
    if (t == 0) L.c0v = c0[0];
    if (LASTP && t < 17) L.WcL[t] = Wc[t];
    const int j0 = off2[b * 65 + r2];
    const int n2 = off2[b * 65 + r2 + 1] - j0;
    for (int k = t; k < n2; k += 256) {
        int j = lst2[b * kE + j0 + k];
        int v = (j << 8) | d2[b * kE + j];
        if (C == 1 && rep2g[b * kE + j] == j) v |= 1 << 16;
        L.jd2[k] = v;
    }
    for (int k = t; k < kE; k += 256) {
        int i = lst1[b * kE + k];
        int v = (i << 8) | d1[b * kE + i];
        if (C == 1 && rep1g[b * kE + i] == i) v |= 1 << 16;
        L.il[k] = v;
    }
    if constexpr (C == 1) {
        for (int k = t; k < kE + 1; k += 256) {
            L.co1L[k] = coff1[b * 193 + k];
            L.co2L[k] = coff2[b * 193 + k];
        }
        for (int k = t; k < kE; k += 256) {
            L.cl1L[k] = (short)clst1[b * kE + k];
            L.cl2L[k] = (short)clst2[b * kE + k];
        }
    }
    if constexpr (C == 17) {
        sink64_local(b, t, L.mat, L.fL, L.gL, vprev);  // includes syncthreads
    } else {
        __syncthreads();
    }

    const int r1 = t >> 2, lane = t & 3;
    const int i0 = off1[b * 65 + r1], i1 = off1[b * 65 + r1 + 1];
    const float* Keb = Ke + (size_t)b * kE * kE;
    const float* KpB = Kp + (size_t)b * kNN;
    int degLocal = 0;

    if constexpr (C == 1) {
        float acc = 0.f;
        for (int k = 0; k < n2; ++k) {
            int pk = L.jd2[k], j = (pk >> 8) & 255, dd2 = pk & 255;
            for (int m = i0 + lane; m < i1; m += 4) {
                int pi = L.il[m], i = (pi >> 8) & 255, dd1 = pi & 255;
                if (dd2 == r2 && dd1 == r1) continue;
                acc += Keb[(size_t)i * kE + j] * KpB[dd1 * 64 + dd2];
            }
        }
        acc += __shfl_xor(acc, 1);
        acc += __shfl_xor(acc, 2);
        if (lane == 0) L.msgT[r1][0] = acc;
        for (int m = i0 + lane; m < i1; m += 4) {
            int pi = L.il[m];
            if (!(pi >> 16)) continue;
            int i = (pi >> 8) & 255, dd1 = pi & 255;
            for (int k = 0; k < n2; ++k) {
                int pk = L.jd2[k];
                if (!(pk >> 16)) continue;
                int j = (pk >> 8) & 255, dd2 = pk & 255;
                float sum = 0.f;
                for (int mm = L.co1L[i]; mm < L.co1L[i + 1]; ++mm) {
                    const float* kr = Keb + (size_t)L.cl1L[mm] * kE;
                    for (int nn = L.co2L[j]; nn < L.co2L[j + 1]; ++nn)
                        sum += kr[L.cl2L[nn]];
                }
                if ((r2 * 64 + r1) != (dd2 * 64 + dd1) && sum > 0.0f) ++degLocal;
            }
        }
        degLocal += __shfl_xor(degLocal, 1);
        degLocal += __shfl_xor(degLocal, 2);
    } else {
        const float* xb = x + (size_t)b * kNN * kXS;
        float acc[5];
#pragma unroll
        for (int cc = 0; cc < 5; ++cc) acc[cc] = 0.f;
        for (int k = 0; k < n2; ++k) {
            int pk = L.jd2[k], j = (pk >> 8) & 255, dd2 = pk & 255;
            // stage rows dd2*64..+63 (16 ch) into padded LDS, coalesced 16B
            __syncthreads();
            {
                const float4* src4 = (const float4*)(xb + (size_t)(dd2 * 64) * kXS);
                float4 vv = src4[t];
                const int row = t >> 2, c4 = (t & 3) * 4;
                L.xs[row][c4 + 0] = vv.x; L.xs[row][c4 + 1] = vv.y;
                L.xs[row][c4 + 2] = vv.z; L.xs[row][c4 + 3] = vv.w;
            }
            __syncthreads();
            for (int m = i0; m < i1; ++m) {
                int pi = L.il[m], dd1 = pi & 255;
                if (dd2 == r2 && dd1 == r1) continue;
                int i = (pi >> 8) & 255;
                float kv = Keb[(size_t)i * kE + j];
                const float* xc = &L.xs[dd1][0];
                acc[0] += kv * xc[lane];
                acc[1] += kv * xc[lane + 4];
                acc[2] += kv * xc[lane + 8];
                acc[3] += kv * xc[lane + 12];
                if (lane == 0) acc[4] += kv * L.mat[dd1][dd2];   // ss from LDS
            }
        }
#pragma unroll
        for (int cc = 0; cc < 5; ++cc) {
            int c = lane + cc * 4;
            if (c < C) L.msgT[r1][c] = acc[cc];
        }
    }
    __syncthreads();

    const int row = r2 * 64 + r1;
    const int idx = b * kNN + row;
    const float kd = KpB[r1 * 64 + r2];
    int degv;
    if constexpr (C == 1) {
        degv = degLocal;
        if (lane == 0) __builtin_nontemporal_store(degLocal, &degcnt[idx]);
    } else {
        degv = degcnt[idx];
    }
    const float dg = fmaxf((float)(degv + (kd > 0.f ? 1 : 0)), 1.f);
    float m[C];
    if constexpr (C == 1) {
        m[0] = (L.msgT[r1][0] + kd * kd) / dg;
    } else {
        float4 xa  = *(const float4*)(x + (size_t)idx * kXS + 0);
        float4 xb4 = *(const float4*)(x + (size_t)idx * kXS + 4);
        float4 xc4 = *(const float4*)(x + (size_t)idx * kXS + 8);
        float4 xd4 = *(const float4*)(x + (size_t)idx * kXS + 12);
        m[0]  = (L.msgT[r1][0]  + kd * xa.x) / dg;
        m[1]  = (L.msgT[r1][1]  + kd * xa.y) / dg;
        m[2]  = (L.msgT[r1][2]  + kd * xa.z) / dg;
        m[3]  = (L.msgT[r1][3]  + kd * xa.w) / dg;
        m[4]  = (L.msgT[r1][4]  + kd * xb4.x) / dg;
        m[5]  = (L.msgT[r1][5]  + kd * xb4.y) / dg;
        m[6]  = (L.msgT[r1][6]  + kd * xb4.z) / dg;
        m[7]  = (L.msgT[r1][7]  + kd * xb4.w) / dg;
        m[8]  = (L.msgT[r1][8]  + kd * xc4.x) / dg;
        m[9]  = (L.msgT[r1][9]  + kd * xc4.y) / dg;
        m[10] = (L.msgT[r1][10] + kd * xc4.z) / dg;
        m[11] = (L.msgT[r1][11] + kd * xc4.w) / dg;
        m[12] = (L.msgT[r1][12] + kd * xd4.x) / dg;
        m[13] = (L.msgT[r1][13] + kd * xd4.y) / dg;
        m[14] = (L.msgT[r1][14] + kd * xd4.z) / dg;
        m[15] = (L.msgT[r1][15] + kd * xd4.w) / dg;
        m[16] = (L.msgT[r1][16] + kd * L.mat[r1][r2]) / dg;   // own ss via LDS
    }
    float h[4];
    float vpart = 0.f;
#pragma unroll
    for (int ff = 0; ff < 4; ++ff) {
        int f = lane * 4 + ff;
        float a = L.bL[f];
#pragma unroll
        for (int c = 0; c < C; ++c) a += m[c] * L.WL[c * 16 + f];
        h[ff] = fmaxf(a, 0.f);
        vpart += h[ff] * L.SL[f];
    }
    if constexpr (!LASTP) {
        vfloat4 hv; hv.x = h[0]; hv.y = h[1]; hv.z = h[2]; hv.w = h[3];
        __builtin_nontemporal_store(hv, (vfloat4*)(xn + (size_t)idx * kXS + lane * 4));
    } else {
        float vcp = h[0] * L.WcL[lane * 4 + 0] + h[1] * L.WcL[lane * 4 + 1]
                  + h[2] * L.WcL[lane * 4 + 2] + h[3] * L.WcL[lane * 4 + 3];
        vcp += __shfl_xor(vcp, 1);
        vcp += __shfl_xor(vcp, 2);
        if (lane == 0) __builtin_nontemporal_store(vcp, &vcbuf[idx]);
    }
    vpart += __shfl_xor(vpart, 1);
    vpart += __shfl_xor(vpart, 2);
    if (lane == 0) __builtin_nontemporal_store(vpart + L.c0v, &vout[idx]);
}

__global__ __launch_bounds__(256) void k_l0(
    const int* __restrict__ off1, const int* __restrict__ lst1,
    const int* __restrict__ off2, const int* __restrict__ lst2,
    const int* __restrict__ dst1, const int* __restrict__ dst2,
    const int* __restrict__ rep1g, const int* __restrict__ rep2g,
    const int* __restrict__ coff1, const int* __restrict__ coff2,
    const int* __restrict__ clst1, const int* __restrict__ clst2,
    const float* __restrict__ Ke, const float* __restrict__ Kp,
    int* __restrict__ degcnt,
    const float* __restrict__ W0, const float* __restrict__ b0,
    const float* __restrict__ S0, const float* __restrict__ c0,
    float* __restrict__ xA, float* __restrict__ vA)
{
    __shared__ SmemLayer L;
    layer_body<1, false>(blockIdx.x, threadIdx.x, L,
        off1, lst1, off2, lst2, dst1, dst2, rep1g, rep2g,
        coff1, coff2, clst1, clst2, Ke, nullptr, Kp, degcnt,
        W0, b0, S0, c0, nullptr, nullptr, xA, nullptr, vA);
}

__global__ __launch_bounds__(256) void k_l1(
    const int* __restrict__ off1, const int* __restrict__ lst1,
    const int* __restrict__ off2, const int* __restrict__ lst2,
    const int* __restrict__ dst1, const int* __restrict__ dst2,
    const float* __restrict__ Ke, const float* __restrict__ Kp,
    int* __restrict__ degcnt,
    const float* __restrict__ W1, const float* __restrict__ b1,
    const float* __restrict__ S1, const float* __restrict__ c1,
    const float* __restrict__ xA, const float* __restrict__ vA,
    float* __restrict__ xB, float* __restrict__ vB)
{
    __shared__ SmemLayer L;
    layer_body<17, false>(blockIdx.x, threadIdx.x, L,
        off1, lst1, off2, lst2, dst1, dst2, nullptr, nullptr,
        nullptr, nullptr, nullptr, nullptr, Ke, xA, Kp, degcnt,
        W1, b1, S1, c1, nullptr, vA, xB, nullptr, vB);
}

__global__ __launch_bounds__(256) void k_l2(
    const int* __restrict__ off1, const int* __restrict__ lst1,
    const int* __restrict__ off2, const int* __restrict__ lst2,
    const int* __restrict__ dst1, const int* __restrict__ dst2,
    const float* __restrict__ Ke, const float* __restrict__ Kp,
    int* __restrict__ degcnt,
    const float* __restrict__ W2, const float* __restrict__ b2,
    const float* __restrict__ S2, const float* __restrict__ c2,
    const float* __restrict__ Wc,
    const float* __restrict__ xB, const float* __restrict__ vB,
    float* __restrict__ vcbuf, float* __restrict__ vA)
{
    __shared__ SmemLayer L;
    layer_body<17, true>(blockIdx.x, threadIdx.x, L,
        off1, lst1, off2, lst2, dst1, dst2, nullptr, nullptr,
        nullptr, nullptr, nullptr, nullptr, Ke, xB, Kp, degcnt,
        W2, b2, S2, c2, Wc, vB, nullptr, vcbuf, vA);
}

// ===========================================================================
// K4: final — 8 blocks: ss = sinkhorn(v2); 65x65 bin sinkhorn from vc + ss;
// global max via atomicMax + 8-block mini-barrier; normalize; write out.
// ===========================================================================
struct __align__(16) SmemSink {
    float mat[65][68]; float fL[65], gL[65];
    float wred[4];
};

__global__ __launch_bounds__(256) void k_final(
    const float* __restrict__ vA, const float* __restrict__ vcbuf,
    const float* __restrict__ Wc, const float* __restrict__ bc,
    const float* __restrict__ binv,
    int* __restrict__ bars, float* __restrict__ out)
{
    const int b = blockIdx.x, t = threadIdx.x;
    __shared__ SmemSink S;

    sink64_local(b, t, S.mat, S.fL, S.gL, vA);   // ss in mat[0..63][0..63]

    const float Wc16 = Wc[16], bcv = bc[0], binvv = binv[0];
    const float* vcb = vcbuf + (size_t)b * kNN;
    for (int idx = t; idx < 65 * 65; idx += 256) {
        int q = idx / 65, p = idx - q * 65;
        float v;
        if (p < 64 && q < 64)
            v = vcb[q * 64 + p] + S.mat[p][q] * Wc16 + bcv;
        else v = binvv;
        S.mat[p][q] = v;
    }
    if (t < 65) { S.fL[t] = 0.f; S.gL[t] = 0.f; }
    __syncthreads();

    const int r = t >> 2, s = t & 3;
    for (int it = 0; it < 10; ++it) {
        for (int rr = r; rr < 65; rr += 64) {
            float tv[17];
            float mx = -1e30f;
#pragma unroll
            for (int k = 0; k < 17; ++k) {
                int q = s + 4 * k;
                float v = (q < 65) ? S.mat[rr][q] + S.gL[q] : -1e30f;
                tv[k] = v; mx = fmaxf(mx, v);
            }
            mx = fmaxf(mx, __shfl_xor(mx, 1));
            mx = fmaxf(mx, __shfl_xor(mx, 2));
            float sum = 0.f;
#pragma unroll
            for (int k = 0; k < 17; ++k) sum += __expf(tv[k] - mx);
            sum += __shfl_xor(sum, 1);
            sum += __shfl_xor(sum, 2);
            if (s == 0) S.fL[rr] = -(mx + __logf(sum));
        }
        __syncthreads();
        for (int rr = r; rr < 65; rr += 64) {
            float tv[17];
            float mx = -1e30f;
#pragma unroll
            for (int k = 0; k < 17; ++k) {
                int p = s + 4 * k;
                float v = (p < 65) ? S.mat[p][rr] + S.fL[p] : -1e30f;
                tv[k] = v; mx = fmaxf(mx, v);
            }
            mx = fmaxf(mx, __shfl_xor(mx, 1));
            mx = fmaxf(mx, __shfl_xor(mx, 2));
            float sum = 0.f;
#pragma unroll
            for (int k = 0; k < 17; ++k) sum += __expf(tv[k] - mx);
            sum += __shfl_xor(sum, 1);
            sum += __shfl_xor(sum, 2);
            if (s == 0) S.gL[rr] = -(mx + __logf(sum));
        }
        __syncthreads();
    }

    float ev[16];
    float lmax = 0.f;
    {
        const float fr = S.fL[r];
#pragma unroll
        for (int k = 0; k < 16; ++k) {
            int q = s + 4 * k;
            ev[k] = __expf(S.mat[r][q] + fr + S.gL[q]);
            lmax = fmaxf(lmax, ev[k]);
        }
    }
#pragma unroll
    for (int o = 32; o >= 1; o >>= 1) lmax = fmaxf(lmax, __shfl_xor(lmax, o));
    if ((t & 63) == 0) S.wred[t >> 6] = lmax;
    __syncthreads();
    int* mcnt = bars + 3584;
    int* gmax = bars + 3600;
    if (t == 0) {
        float mb = fmaxf(fmaxf(S.wred[0], S.wred[1]), fmaxf(S.wred[2], S.wred[3]));
        atomicMax(gmax, __float_as_int(mb));   // all values > 0
        asm volatile("s_waitcnt vmcnt(0)" ::: "memory");
        __hip_atomic_fetch_add(mcnt, 1, __ATOMIC_RELAXED, __HIP_MEMORY_SCOPE_AGENT);
        while (__hip_atomic_load(mcnt, __ATOMIC_RELAXED, __HIP_MEMORY_SCOPE_AGENT) < 8)
            __builtin_amdgcn_s_sleep(2);
    }
    __syncthreads();
    const float inv = 1.f / __int_as_float(
        __hip_atomic_load(gmax, __ATOMIC_RELAXED, __HIP_MEMORY_SCOPE_AGENT));
#pragma unroll
    for (int k = 0; k < 16; ++k) {
        int q = s + 4 * k;
        out[((size_t)b * kN + r) * kN + q] = ev[k] * inv;
    }
}

// ---------------------------------------------------------------------------
extern "C" void kernel_launch(void* const* d_in, const int* in_sizes, int n_in,
                              void* d_out, int out_size, void* d_ws, size_t ws_size,
                              hipStream_t stream)
{
    (void)in_sizes; (void)n_in; (void)out_size; (void)ws_size;

    const float* x1    = (const float*)d_in[0];
    const float* x2    = (const float*)d_in[1];
    const float* e1    = (const float*)d_in[2];
    const float* e2    = (const float*)d_in[3];
    const float* Wp    = (const float*)d_in[4];
    const float* bp    = (const float*)d_in[5];
    const float* gamma = (const float*)d_in[6];
    const float* beta  = (const float*)d_in[7];
    const float* W0 = (const float*)d_in[8];
    const float* b0 = (const float*)d_in[9];
    const float* S0 = (const float*)d_in[10];
    const float* c0 = (const float*)d_in[11];
    const float* W1 = (const float*)d_in[12];
    const float* b1 = (const float*)d_in[13];
    const float* S1 = (const float*)d_in[14];
    const float* c1 = (const float*)d_in[15];
    const float* W2 = (const float*)d_in[16];
    const float* b2 = (const float*)d_in[17];
    const float* S2 = (const float*)d_in[18];
    const float* c2 = (const float*)d_in[19];
    const float* Wc = (const float*)d_in[20];
    const float* bc = (const float*)d_in[21];
    const float* binv = (const float*)d_in[22];
    const int* src1 = (const int*)d_in[23];
    const int* dst1 = (const int*)d_in[24];
    const int* src2 = (const int*)d_in[25];
    const int* dst2 = (const int*)d_in[26];

    float* out = (float*)d_out;
    float* wsf = (float*)d_ws;

    float* hbuf  = wsf;                    // 1,048,576
    float* Kp    = hbuf + 1048576;         // 32,768
    float* Ke    = Kp + 32768;             // 294,912
    float* vA    = Ke + 294912;            // 32,768
    float* vB    = vA + 32768;             // 32,768
    float* xA    = vB + 32768;             // 524,288 (stride 16)
    float* xB    = xA + 524288;            // 524,288
    float* vcbuf = xB + 524288;            // 32,768
    int*   degcnt = (int*)(vcbuf + 32768); // 32,768
    int*   off1 = degcnt + 32768;          // 520
    int*   off2 = off1 + 520;              // 520
    int*   lst1 = off2 + 520;              // 1,536
    int*   lst2 = lst1 + 1536;             // 1,536
    int*   rep1g = lst2 + 1536;            // 1,536
    int*   rep2g = rep1g + 1536;           // 1,536
    int*   coff1 = rep2g + 1536;           // 1,544
    int*   coff2 = coff1 + 1544;           // 1,544
    int*   clst1 = coff2 + 1544;           // 1,536
    int*   clst2 = clst1 + 1536;           // 1,536
    float* stats = (float*)(clst2 + 1536); // 2,048   (zeroed by memset)
    int*   bars  = (int*)(stats + 2048);   // 4,096   (zeroed by memset)

    (void)hipMemsetAsync(stats, 0, (2048 + 4096) * sizeof(int), stream);
    k_projcsr<<<dim3(264), dim3(256), 0, stream>>>(
        x1, x2, e1, e2, Wp, bp, src1, dst1, src2, dst2, hbuf, stats,
        off1, off2, lst1, lst2, rep1g, rep2g, coff1, coff2, clst1, clst2);
    k_sim<<<dim3(320), dim3(256), 0, stream>>>(hbuf, stats, gamma, beta, Kp, Ke);
    k_l0<<<dim3(512), dim3(256), 0, stream>>>(
        off1, lst1, off2, lst2, dst1, dst2, rep1g, rep2g,
        coff1, coff2, clst1, clst2, Ke, Kp, degcnt,
        W0, b0, S0, c0, xA, vA);
    k_l1<<<dim3(512), dim3(256), 0, stream>>>(
        off1, lst1, off2, lst2, dst1, dst2, Ke, Kp, degcnt,
        W1, b1, S1, c1, xA, vA, xB, vB);
    k_l2<<<dim3(512), dim3(256), 0, stream>>>(
        off1, lst1, off2, lst2, dst1, dst2, Ke, Kp, degcnt,
        W2, b2, S2, c2, Wc, xB, vB, vcbuf, vA);
    k_final<<<dim3(8), dim3(256), 0, stream>>>(vA, vcbuf, Wc, bc, binv, bars, out);
}